// Round 5
// baseline (849.012 us; speedup 1.0000x reference)
//
#include <hip/hip_runtime.h>
#include <math.h>
#include <stdint.h>

// ---------------------------------------------------------------------------
// GroundingModule — round 5: split-bf16 GEMMs on the 8-phase schedule (T3+T4+T5).
// Virtual-K formulation: 3-term split (AhBh + AlBh + AhBl) = GEMM with
// K=2304 (36 K-tiles of 64), segment-selected source pointers.
// Per phase: {ds_read quadrant ∥ stage 1 unit} -> barrier -> lgkmcnt(0) ->
// MFMA(setprio) -> barrier.  vmcnt(4) at phases 3/7 (never drains mid-loop).
// ---------------------------------------------------------------------------

#define DEV __device__ __forceinline__

typedef __attribute__((ext_vector_type(8))) short short8v;   // 8 bf16
typedef __attribute__((ext_vector_type(4))) float f32x4;

constexpr int KDIM  = 768;
constexpr int CHUNK = 32768;
constexpr int NTILE = 36;          // virtual K tiles of 64 (3 x 768/64)

// output offsets (floats) in return order
constexpr int OFF_KG   = 0;
constexpr int OFF_MI   = 65536;
constexpr int OFF_ST   = 69632;
constexpr int OFF_ET   = 71680;
constexpr int OFF_MASK = 73728;
constexpr int OFF_ORI  = 139264;

DEV float gelu_erf(float x) { return 0.5f * x * (1.0f + erff(x * 0.70710678118654752f)); }
DEV float wave_sum(float v) { for (int o = 32; o; o >>= 1) v += __shfl_xor(v, o); return v; }
DEV float wave_max(float v) { for (int o = 32; o; o >>= 1) v = fmaxf(v, __shfl_xor(v, o)); return v; }

DEV short f2bf(float x) {                       // f32 -> bf16 (RNE)
    uint32_t u = __builtin_bit_cast(uint32_t, x);
    u = u + 0x7fffu + ((u >> 16) & 1u);
    return (short)(u >> 16);
}
DEV float bf2f(short b) {
    uint32_t u = ((uint32_t)(uint16_t)b) << 16;
    return __builtin_bit_cast(float, u);
}

DEV void gl_lds16(const void* g, void* l) {     // async 16B/lane global->LDS
    __builtin_amdgcn_global_load_lds(
        (const __attribute__((address_space(1))) uint32_t*)g,
        (__attribute__((address_space(3))) uint32_t*)l, 16, 0, 0);
}

// ---------------------------------------------------------------------------
// prep_A1: fused rowstats + LN-affine + hi/lo split.  One wave per row.
__global__ __launch_bounds__(256)
void prep_A1(const float* __restrict__ X, const float* __restrict__ g,
             const float* __restrict__ b, short* __restrict__ Ah, short* __restrict__ Al)
{
    int w = threadIdx.x >> 6, lane = threadIdx.x & 63;
    int row = blockIdx.x * 4 + w;
    const float4* xr = (const float4*)(X + (size_t)row * KDIM);
    float4 xv[3]; float s = 0.f, ss = 0.f;
#pragma unroll
    for (int i = 0; i < 3; ++i) {
        xv[i] = xr[lane + i * 64];
        s  += xv[i].x + xv[i].y + xv[i].z + xv[i].w;
        ss += xv[i].x * xv[i].x + xv[i].y * xv[i].y + xv[i].z * xv[i].z + xv[i].w * xv[i].w;
    }
    s = wave_sum(s); ss = wave_sum(ss);
    float m = s * (1.f / 768.f), var = ss * (1.f / 768.f) - m * m;
    float sa = rsqrtf(var + 1e-5f), ta = -m * sa;
#pragma unroll
    for (int i = 0; i < 3; ++i) {
        int idx = lane + i * 64;
        float4 gv = ((const float4*)g)[idx];
        float4 bv = ((const float4*)b)[idx];
        float a0 = fmaf(fmaf(xv[i].x, sa, ta), gv.x, bv.x);
        float a1 = fmaf(fmaf(xv[i].y, sa, ta), gv.y, bv.y);
        float a2 = fmaf(fmaf(xv[i].z, sa, ta), gv.z, bv.z);
        float a3 = fmaf(fmaf(xv[i].w, sa, ta), gv.w, bv.w);
        short h0 = f2bf(a0), h1 = f2bf(a1), h2 = f2bf(a2), h3 = f2bf(a3);
        ushort4 hv, lv;
        hv.x = (uint16_t)h0; hv.y = (uint16_t)h1; hv.z = (uint16_t)h2; hv.w = (uint16_t)h3;
        lv.x = (uint16_t)f2bf(a0 - bf2f(h0)); lv.y = (uint16_t)f2bf(a1 - bf2f(h1));
        lv.z = (uint16_t)f2bf(a2 - bf2f(h2)); lv.w = (uint16_t)f2bf(a3 - bf2f(h3));
        ((ushort4*)(Ah + (size_t)row * KDIM))[idx] = hv;
        ((ushort4*)(Al + (size_t)row * KDIM))[idx] = lv;
    }
}

// ---------------------------------------------------------------------------
// prep_A2: gate(tanh dot) + LN2 stats + affine + split. vp packed (hi|lo<<16).
__global__ __launch_bounds__(256)
void prep_A2(const uint32_t* __restrict__ vp_hl, const float* __restrict__ qa_p,
             const float* __restrict__ g, const float* __restrict__ b,
             short* __restrict__ Ah, short* __restrict__ Al, int chunk_off)
{
    int w = threadIdx.x >> 6, lane = threadIdx.x & 63;
    int row = blockIdx.x * 4 + w;
    int bidx = (chunk_off + row) >> 5;
    const uint4*  hr = (const uint4*)(vp_hl + (size_t)row * KDIM);
    const float4* qr = (const float4*)(qa_p + (size_t)bidx * KDIM);
    float vp[12]; float s = 0.f, ss = 0.f, d = 0.f;
#pragma unroll
    for (int i = 0; i < 3; ++i) {
        uint4  uv = hr[lane + i * 64];
        float4 qv = qr[lane + i * 64];
        float v0 = bf2f((short)(uv.x & 0xffff)) + bf2f((short)(uv.x >> 16));
        float v1 = bf2f((short)(uv.y & 0xffff)) + bf2f((short)(uv.y >> 16));
        float v2 = bf2f((short)(uv.z & 0xffff)) + bf2f((short)(uv.z >> 16));
        float v3 = bf2f((short)(uv.w & 0xffff)) + bf2f((short)(uv.w >> 16));
        vp[i * 4 + 0] = v0; vp[i * 4 + 1] = v1; vp[i * 4 + 2] = v2; vp[i * 4 + 3] = v3;
        s  += v0 + v1 + v2 + v3;
        ss += v0 * v0 + v1 * v1 + v2 * v2 + v3 * v3;
        d  += v0 * qv.x + v1 * qv.y + v2 * qv.z + v3 * qv.w;
    }
    s = wave_sum(s); ss = wave_sum(ss); d = wave_sum(d);
    float gate = tanhf(d);
    float m = s * (1.f / 768.f), var = ss * (1.f / 768.f) - m * m;
    float den = rsqrtf(gate * gate * var + 1e-5f);
    float sa = gate * den, ta = -gate * m * den;
#pragma unroll
    for (int i = 0; i < 3; ++i) {
        int idx = lane + i * 64;
        float4 gv = ((const float4*)g)[idx];
        float4 bv = ((const float4*)b)[idx];
        float a0 = fmaf(fmaf(vp[i * 4 + 0], sa, ta), gv.x, bv.x);
        float a1 = fmaf(fmaf(vp[i * 4 + 1], sa, ta), gv.y, bv.y);
        float a2 = fmaf(fmaf(vp[i * 4 + 2], sa, ta), gv.z, bv.z);
        float a3 = fmaf(fmaf(vp[i * 4 + 3], sa, ta), gv.w, bv.w);
        short h0 = f2bf(a0), h1 = f2bf(a1), h2 = f2bf(a2), h3 = f2bf(a3);
        ushort4 hv, lv;
        hv.x = (uint16_t)h0; hv.y = (uint16_t)h1; hv.z = (uint16_t)h2; hv.w = (uint16_t)h3;
        lv.x = (uint16_t)f2bf(a0 - bf2f(h0)); lv.y = (uint16_t)f2bf(a1 - bf2f(h1));
        lv.z = (uint16_t)f2bf(a2 - bf2f(h2)); lv.w = (uint16_t)f2bf(a3 - bf2f(h3));
        ((ushort4*)(Ah + (size_t)row * KDIM))[idx] = hv;
        ((ushort4*)(Al + (size_t)row * KDIM))[idx] = lv;
    }
}

// ---------------------------------------------------------------------------
// prep_W: transpose + hi/lo split.  W[k][n] f32 -> Bh/Bl[n][k] bf16.
__global__ __launch_bounds__(256)
void prep_W(const float* __restrict__ W, short* __restrict__ Bh, short* __restrict__ Bl, int N)
{
    __shared__ float t[32][33];
    int bx = blockIdx.x, by = blockIdx.y;
    int lx = threadIdx.x & 31, ly = threadIdx.x >> 5;
#pragma unroll
    for (int r = 0; r < 32; r += 8)
        t[ly + r][lx] = W[(size_t)(by * 32 + ly + r) * N + bx * 32 + lx];
    __syncthreads();
#pragma unroll
    for (int r = 0; r < 32; r += 8) {
        float v = t[lx][ly + r];
        short hi = f2bf(v);
        size_t o = (size_t)(bx * 32 + ly + r) * KDIM + by * 32 + lx;
        Bh[o] = hi;
        Bl[o] = f2bf(v - bf2f(hi));
    }
}

// ---------------------------------------------------------------------------
// 8-phase split-bf16 MFMA GEMM.  512 thr / 8 waves (2M x 4N).
//   MODE 0: BM=256 BN=256, out = gelu(.) packed (hi|lo<<16) u32.
//   MODE 1: BM=128 BN=384, partial row-dot with w2 -> partials[wn][row].
#define VM4  asm volatile("s_waitcnt vmcnt(4)" ::: "memory")
#define VM0  asm volatile("s_waitcnt vmcnt(0)" ::: "memory")

#define STAGE(U, TT) do {                                                     \
    const int sT_ = (TT);                                                     \
    const int seg_ = (sT_ >= 24) ? 2 : ((sT_ >= 12) ? 1 : 0);                 \
    const int kp_ = (sT_ - seg_ * 12) << 6;                                   \
    const short* sb_ = ((U) < 2) ? ((seg_ == 1) ? APl : APh)                  \
                                 : ((seg_ == 2) ? BPl : BPh);                 \
    char* db_ = lds + ((sT_) & 1) * BUFSZ;                                    \
    _Pragma("unroll")                                                         \
    for (int j_ = 0; j_ < UL_[(U)]; ++j_)                                     \
        gl_lds16(sb_ + goff[(U)][j_] + kp_, db_ + ldso[(U)][j_]);             \
} while (0)

#define PHASE(P, VMSTMT, ...) do {                                            \
    constexpr int mh_ = ((P) >> 1) & 1, nh_ = (P) & 1;                        \
    const char* Ab_ = lds + (((P) >> 2) & 1) * BUFSZ;                         \
    const char* Bb_ = Ab_ + BREG;                                             \
    short8v av[QM][2], bv[QN][2];                                             \
    _Pragma("unroll")                                                         \
    for (int nf = 0; nf < QN; ++nf) {                                         \
        int sB = nh_ * (BN / 2) + wn * (BN / 8) + nf * 16 + lr;               \
        int so = (lh ^ ((sB >> 1) & 3)) << 4;                                 \
        bv[nf][0] = *(const short8v*)(Bb_ + sB * 128 + so);                   \
        bv[nf][1] = *(const short8v*)(Bb_ + sB * 128 + 64 + so);              \
    }                                                                         \
    _Pragma("unroll")                                                         \
    for (int mf = 0; mf < QM; ++mf) {                                         \
        int sA = mh_ * (BM / 2) + wm * (BM / 4) + mf * 16 + lr;               \
        int so = (lh ^ ((sA >> 1) & 3)) << 4;                                 \
        av[mf][0] = *(const short8v*)(Ab_ + sA * 128 + so);                   \
        av[mf][1] = *(const short8v*)(Ab_ + sA * 128 + 64 + so);              \
    }                                                                         \
    __VA_ARGS__;                                                              \
    VMSTMT;                                                                   \
    __builtin_amdgcn_sched_barrier(0);                                        \
    __builtin_amdgcn_s_barrier();                                             \
    asm volatile("s_waitcnt lgkmcnt(0)" ::: "memory");                        \
    __builtin_amdgcn_sched_barrier(0);                                        \
    __builtin_amdgcn_s_setprio(1);                                            \
    _Pragma("unroll")                                                         \
    for (int mf = 0; mf < QM; ++mf)                                           \
        _Pragma("unroll")                                                     \
        for (int nf = 0; nf < QN; ++nf) {                                     \
            acc[mh_ * QM + mf][nh_ * QN + nf] =                               \
                __builtin_amdgcn_mfma_f32_16x16x32_bf16(av[mf][0], bv[nf][0], \
                    acc[mh_ * QM + mf][nh_ * QN + nf], 0, 0, 0);              \
            acc[mh_ * QM + mf][nh_ * QN + nf] =                               \
                __builtin_amdgcn_mfma_f32_16x16x32_bf16(av[mf][1], bv[nf][1], \
                    acc[mh_ * QM + mf][nh_ * QN + nf], 0, 0, 0);              \
        }                                                                     \
    __builtin_amdgcn_s_setprio(0);                                            \
    __builtin_amdgcn_sched_barrier(0);                                        \
    __builtin_amdgcn_s_barrier();                                             \
} while (0)

template<int MODE>
__global__ __launch_bounds__(512, 1)
void gemm8(const short* __restrict__ Ah_g, const short* __restrict__ Al_g,
           const short* __restrict__ Bh_g, const short* __restrict__ Bl_g,
           const float* __restrict__ bias, uint32_t* __restrict__ O_hl,
           const float* __restrict__ w2, float* __restrict__ partials,
           int chunk_off)
{
    constexpr int BM = MODE ? 128 : 256;
    constexpr int BN = MODE ? 384 : 256;
    constexpr int QM = MODE ? 2 : 4;          // M frags per quadrant
    constexpr int QN = MODE ? 3 : 2;          // N frags per quadrant
    constexpr int MFR = 2 * QM, NFR = 2 * QN;
    constexpr int BREG  = BM * 128;           // B region byte offset
    constexpr int BUFSZ = (BM + BN) * 128;    // 64 KB per buf
    constexpr int US0[4] = { 0, BM / 2, 0, BN / 2 };      // unit storage row 0
    constexpr int UL_[4] = { BM / 128, BM / 128, BN / 128, BN / 128 };  // loads/unit
    extern __shared__ __align__(16) char lds[];

    const int t = threadIdx.x;
    const int w = t >> 6, lane = t & 63;
    const int lr = lane & 15, lh = lane >> 4;
    const int wm = w >> 2, wn = w & 3;        // 2 x 4 wave grid

    const int gx = gridDim.x, nwg = gx * gridDim.y;
    int bidx = blockIdx.y * gx + blockIdx.x;
    int wid = (bidx & 7) * (nwg >> 3) + (bidx >> 3);
    const int bx = wid % gx, by = wid / gx;
    const int row0 = by * BM, col0 = bx * BN;

    const short* APh = Ah_g + (size_t)row0 * KDIM;
    const short* APl = Al_g + (size_t)row0 * KDIM;
    const short* BPh = Bh_g + (size_t)col0 * KDIM;
    const short* BPl = Bl_g + (size_t)col0 * KDIM;

    // per-thread stage source offsets (elements) + LDS dest offsets (bytes)
    size_t goff[4][3];
    int    ldso[4][3];
#pragma unroll
    for (int u = 0; u < 4; ++u)
#pragma unroll
        for (int j = 0; j < 3; ++j) {
            if (j >= UL_[u]) continue;
            int p  = j * 512 + t;
            int sr = US0[u] + (p >> 3);       // storage row
            int c  = t & 7;                   // 16B chunk in 128B row
            int kloc = ((c >> 2) << 5) + (((c & 3) ^ ((sr >> 1) & 3)) << 3);
            int g;
            if (u < 2)
                g = MODE ? (((sr >> 5) & 1) * 64 + (sr >> 6) * 32 + (sr & 31))
                         : (((sr >> 6) & 1) * 128 + (sr >> 7) * 64 + (sr & 63));
            else
                g = MODE ? (((sr % 192) / 48) * 96 + (sr / 192) * 48 + (sr % 48))
                         : (((sr >> 5) & 3) * 64 + (sr >> 7) * 32 + (sr & 31));
            goff[u][j] = (size_t)g * KDIM + kloc;
            ldso[u][j] = (u < 2 ? 0 : BREG) + US0[u] * 128 + (j * 512 + (t & ~63)) * 16;
        }

    f32x4 acc[MFR][NFR] = {};

    // prologue: t0 {A0,B0,A1,B1} + t1 {A0,B0}; drain t0 (8 loads) -> vmcnt(4)
    STAGE(0, 0); STAGE(2, 0); STAGE(1, 0); STAGE(3, 0);
    STAGE(0, 1); STAGE(2, 1);
    VM4;
    __builtin_amdgcn_s_barrier();

    for (int i = 0; i < NTILE / 2; ++i) {
        const int  T1 = 2 * i + 1, T2 = 2 * i + 2, T3 = 2 * i + 3;
        const bool nl = (i < NTILE / 2 - 1);
        PHASE(0, (void)0,            STAGE(1, T1));
        PHASE(1, (void)0,            STAGE(3, T1));
        PHASE(2, (void)0,            if (nl) STAGE(0, T2));
        PHASE(3, if (nl) VM4; else VM0, if (nl) STAGE(2, T2));
        PHASE(4, (void)0,            if (nl) STAGE(1, T2));
        PHASE(5, (void)0,            if (nl) STAGE(3, T2));
        PHASE(6, (void)0,            if (nl) STAGE(0, T3));
        PHASE(7, VM4,                if (nl) STAGE(2, T3));
    }

    if (MODE == 0) {
#pragma unroll
        for (int im = 0; im < MFR; ++im)
#pragma unroll
            for (int in = 0; in < NFR; ++in) {
                int n = col0 + wn * 64 + (in >> 1) * 32 + (in & 1) * 16 + lr;
                float bvs = bias[n];
#pragma unroll
                for (int q = 0; q < 4; ++q) {
                    int m = row0 + wm * 128 + (im >> 2) * 64 + (im & 3) * 16 + lh * 4 + q;
                    float gv = gelu_erf(acc[im][in][q] + bvs);
                    short hi = f2bf(gv);
                    short lo = f2bf(gv - bf2f(hi));
                    O_hl[(size_t)m * 768 + n] =
                        (uint32_t)(uint16_t)hi | ((uint32_t)(uint16_t)lo << 16);
                }
            }
    } else {
        float rs[MFR][4] = {};
#pragma unroll
        for (int im = 0; im < MFR; ++im)
#pragma unroll
            for (int in = 0; in < NFR; ++in) {
                int n = wn * 96 + (in / 3) * 48 + (in % 3) * 16 + lr;
                float bvs = bias[n], wv = w2[n];
#pragma unroll
                for (int q = 0; q < 4; ++q)
                    rs[im][q] += gelu_erf(acc[im][in][q] + bvs) * wv;
            }
#pragma unroll
        for (int im = 0; im < MFR; ++im)
#pragma unroll
            for (int q = 0; q < 4; ++q) {
                float vv = rs[im][q];
                vv += __shfl_xor(vv, 1); vv += __shfl_xor(vv, 2);
                vv += __shfl_xor(vv, 4); vv += __shfl_xor(vv, 8);
                if (lr == 0) {
                    int m = chunk_off + row0 + wm * 64 + (im >> 1) * 32 + (im & 1) * 16 + lh * 4 + q;
                    partials[(size_t)wn * 65536 + m] = vv;
                }
            }
    }
}

// ---------------------------------------------------------------------------
// f32 fallback GEMM for the small qa projection.
constexpr int BKF = 16;
__global__ __launch_bounds__(256)
void rowstats(const float* __restrict__ X, float2* __restrict__ st, int M)
{
    int wave = threadIdx.x >> 6, lane = threadIdx.x & 63;
    int row = blockIdx.x * 4 + wave;
    if (row >= M) return;
    const float4* xr = reinterpret_cast<const float4*>(X + (size_t)row * KDIM);
    float s = 0.f, ss = 0.f;
#pragma unroll
    for (int i = 0; i < 3; ++i) {
        float4 v = xr[lane + i * 64];
        s  += v.x + v.y + v.z + v.w;
        ss += v.x * v.x + v.y * v.y + v.z * v.z + v.w * v.w;
    }
    s = wave_sum(s); ss = wave_sum(ss);
    if (lane == 0) {
        float m = s * (1.0f / 768.0f);
        float var = ss * (1.0f / 768.0f) - m * m;
        float rstd = rsqrtf(var + 1e-5f);
        st[row] = make_float2(rstd, -m * rstd);
    }
}

template<int BM, int BN, int TM, int TN>
__global__ __launch_bounds__(256)
void gemm_fused(const float* __restrict__ X, const float2* __restrict__ st,
                const float* __restrict__ gw, const float* __restrict__ gb,
                const float* __restrict__ W, const float* __restrict__ bias,
                float* __restrict__ out, int M, int N)
{
    static_assert((BM / TM) * (BN / TN) == 256, "256 threads");
    __shared__ float As[BKF][BM];
    __shared__ float Bs[BKF][BN];
    const int t = threadIdx.x;
    constexpr int TXN = BN / TN;
    const int tx = t % TXN;
    const int ty = t / TXN;
    const int row0 = blockIdx.y * BM;
    const int col0 = blockIdx.x * BN;
    float acc[TM][TN] = {};
    constexpr int A_IT = BM * BKF / 4 / 256;
    constexpr int B_IT = BKF * BN / 4 / 256;
    for (int k0 = 0; k0 < KDIM; k0 += BKF) {
#pragma unroll
        for (int i = 0; i < A_IT; ++i) {
            int idx = t + i * 256;
            int r = idx >> 2;
            int c = (idx & 3) << 2;
            float4 xv = *reinterpret_cast<const float4*>(X + (size_t)(row0 + r) * KDIM + k0 + c);
            float2 s = st[row0 + r];
            float4 gv = *reinterpret_cast<const float4*>(gw + k0 + c);
            float4 bv = *reinterpret_cast<const float4*>(gb + k0 + c);
            As[c + 0][r] = fmaf(fmaf(xv.x, s.x, s.y), gv.x, bv.x);
            As[c + 1][r] = fmaf(fmaf(xv.y, s.x, s.y), gv.y, bv.y);
            As[c + 2][r] = fmaf(fmaf(xv.z, s.x, s.y), gv.z, bv.z);
            As[c + 3][r] = fmaf(fmaf(xv.w, s.x, s.y), gv.w, bv.w);
        }
#pragma unroll
        for (int i = 0; i < B_IT; ++i) {
            int idx = t + i * 256;
            int r = idx / (BN / 4);
            int c = (idx % (BN / 4)) << 2;
            *reinterpret_cast<float4*>(&Bs[r][c]) =
                *reinterpret_cast<const float4*>(W + (size_t)(k0 + r) * N + col0 + c);
        }
        __syncthreads();
#pragma unroll
        for (int kk = 0; kk < BKF; ++kk) {
            float a[TM], b[TN];
#pragma unroll
            for (int i = 0; i < TM; i += 4)
                *reinterpret_cast<float4*>(&a[i]) = *reinterpret_cast<const float4*>(&As[kk][ty * TM + i]);
#pragma unroll
            for (int j = 0; j < TN; j += 4)
                *reinterpret_cast<float4*>(&b[j]) = *reinterpret_cast<const float4*>(&Bs[kk][tx * TN + j]);
#pragma unroll
            for (int i = 0; i < TM; ++i)
#pragma unroll
                for (int j = 0; j < TN; ++j)
                    acc[i][j] = fmaf(a[i], b[j], acc[i][j]);
        }
        __syncthreads();
    }
#pragma unroll
    for (int i = 0; i < TM; ++i) {
        size_t row = row0 + ty * TM + i;
#pragma unroll
        for (int j = 0; j < TN; j += 4) {
            int col = col0 + tx * TN + j;
            float4 o;
            o.x = gelu_erf(acc[i][j + 0] + bias[col + 0]);
            o.y = gelu_erf(acc[i][j + 1] + bias[col + 1]);
            o.z = gelu_erf(acc[i][j + 2] + bias[col + 2]);
            o.w = gelu_erf(acc[i][j + 3] + bias[col + 3]);
            *reinterpret_cast<float4*>(out + row * N + col) = o;
        }
    }
}

// ---------------------------------------------------------------------------
// head: logits = sum(4 partials)+b2 -> softmax -> smooth -> softmax -> decode.
__global__ __launch_bounds__(64)
void head_kernel(const float* __restrict__ partials, const float* __restrict__ b2,
                 const float* __restrict__ sigma_p, float* __restrict__ out)
{
    int b = blockIdx.x, lane = threadIdx.x;
    __shared__ float ok[36];
    __shared__ float kg[32];
    __shared__ int sel[2];

    if (lane < 36) ok[lane] = 0.f;
    __syncthreads();

    float x = -3.4e38f;
    if (lane < 32) {
        int row = b * 32 + lane;
        x = b2[0];
#pragma unroll
        for (int p = 0; p < 4; ++p) x += partials[(size_t)p * 65536 + row];
    }
    float mx = wave_max(x);
    float e = (lane < 32) ? expf(x - mx) : 0.f;
    float sum = wave_sum(e);
    float ori = e / sum;
    if (lane < 32) {
        out[OFF_ORI + b * 32 + lane] = ori;
        ok[lane + 2] = ori;
    }
    __syncthreads();

    float sg = sigma_p[0];
    float kern[5]; float ks = 0.f;
#pragma unroll
    for (int k = 0; k < 5; ++k) { float xx = (float)(k - 2) / sg; kern[k] = expf(-0.5f * xx * xx); ks += kern[k]; }
    float sm = -3.4e38f;
    if (lane < 32) {
        sm = 0.f;
#pragma unroll
        for (int k = 0; k < 5; ++k) sm += (kern[k] / ks) * ok[lane + k];
    }
    float mx2 = wave_max(sm);
    float e2 = (lane < 32) ? expf(sm - mx2) : 0.f;
    float sum2 = wave_sum(e2);
    float kgv = e2 / sum2;
    if (lane < 32) {
        out[OFF_KG + b * 32 + lane] = kgv;
        kg[lane] = kgv;
    }
    __syncthreads();

    if (lane == 0) {
        int pm = 0; float bv = kg[0];
        for (int i = 1; i < 32; ++i) if (kg[i] > bv) { bv = kg[i]; pm = i; }
        float cum[33]; cum[0] = 0.f;
        for (int i = 0; i < 32; ++i) cum[i + 1] = cum[i] + kg[i];
        float bs = -3.4e38f; int bst = 0, ben = 0;
        const int wsz[3] = {1, 3, 5};
        for (int wi = 0; wi < 3; ++wi) {
            int w = wsz[wi];
            for (int s = 0; s + w <= 32; ++s) {
                if (pm >= s && pm < s + w) {
                    float sc = cum[s + w] - cum[s];
                    if (sc > bs) { bs = sc; bst = s; ben = s + w; }
                }
            }
        }
        out[OFF_MI + b * 2 + 0] = (float)bst;
        out[OFF_MI + b * 2 + 1] = (float)ben;
        out[OFF_ST + b] = (float)bst / 31.0f;
        out[OFF_ET + b] = (float)ben / 31.0f;
        sel[0] = bst; sel[1] = ben;
    }
    __syncthreads();
    if (lane < 32)
        out[OFF_MASK + b * 32 + lane] = (lane >= sel[0] && lane <= sel[1]) ? 1.0f : 0.0f;
}

// ---------------------------------------------------------------------------
extern "C" void kernel_launch(void* const* d_in, const int* in_sizes, int n_in,
                              void* d_out, int out_size, void* d_ws, size_t ws_size,
                              hipStream_t stream)
{
    const float* v      = (const float*)d_in[0];
    const float* qa     = (const float*)d_in[1];
    const float* vp_lng = (const float*)d_in[2];
    const float* vp_lnb = (const float*)d_in[3];
    const float* vp_w   = (const float*)d_in[4];
    const float* vp_b   = (const float*)d_in[5];
    const float* qp_lng = (const float*)d_in[6];
    const float* qp_lnb = (const float*)d_in[7];
    const float* qp_w   = (const float*)d_in[8];
    const float* qp_b   = (const float*)d_in[9];
    const float* g_lng  = (const float*)d_in[10];
    const float* g_lnb  = (const float*)d_in[11];
    const float* g_w1   = (const float*)d_in[12];
    const float* g_b1   = (const float*)d_in[13];
    const float* g_w2   = (const float*)d_in[14];
    const float* g_b2   = (const float*)d_in[15];
    const float* sigma  = (const float*)d_in[16];
    float* outf = (float*)d_out;

    // workspace layout (~213 MB)
    short* A1h = (short*)d_ws;                           // CHUNK*768
    short* A1l = A1h + (size_t)CHUNK * KDIM;
    uint32_t* vp_hl = (uint32_t*)(A1l + (size_t)CHUNK * KDIM);   // CHUNK*768 u32
    short* B1h = (short*)(vp_hl + (size_t)CHUNK * KDIM); // 768*768
    short* B1l = B1h + 768 * KDIM;
    short* B2h = B1l + 768 * KDIM;                       // 384*768
    short* B2l = B2h + 384 * KDIM;
    float* qa_p = (float*)(B2l + 384 * KDIM);            // 2048*768
    float* st_qa = qa_p + 2048 * KDIM;                   // 2048*2
    float* partials = st_qa + 4096;                      // 4*65536

    // qa path (small, f32 vector GEMM)
    rowstats<<<512, 256, 0, stream>>>(qa, (float2*)st_qa, 2048);
    gemm_fused<64, 64, 4, 4><<<dim3(12, 32), 256, 0, stream>>>(
        qa, (const float2*)st_qa, qp_lng, qp_lnb, qp_w, qp_b, qa_p, 2048, 768);

    // weight transpose + split
    prep_W<<<dim3(24, 24), 256, 0, stream>>>(vp_w, B1h, B1l, 768);
    prep_W<<<dim3(12, 24), 256, 0, stream>>>(g_w1, B2h, B2l, 384);

    constexpr int LDS8 = 131072;   // 2 bufs x 64 KB (both modes)

    for (int c = 0; c < 65536; c += CHUNK) {
        prep_A1<<<CHUNK / 4, 256, 0, stream>>>(v + (size_t)c * KDIM, vp_lng, vp_lnb, A1h, A1l);
        // v_p = gelu(A1 @ vp_w^T + vp_b): 256x256 tile, grid (3,128)
        gemm8<0><<<dim3(3, CHUNK / 256), 512, LDS8, stream>>>(
            A1h, A1l, B1h, B1l, vp_b, vp_hl, nullptr, nullptr, 0);
        prep_A2<<<CHUNK / 4, 256, 0, stream>>>(vp_hl, qa_p, g_lng, g_lnb, A1h, A1l, c);
        // fused h@g_w1+gelu+dot(g_w2): 128x384 tile, grid (1,256)
        gemm8<1><<<dim3(1, CHUNK / 128), 512, LDS8, stream>>>(
            A1h, A1l, B2h, B2l, g_b1, nullptr, g_w2, partials, c);
    }

    head_kernel<<<2048, 64, 0, stream>>>(partials, g_b2, sigma, outf);
}

// Round 6
// 758.330 us; speedup vs baseline: 1.1196x; 1.1196x over previous
//
#include <hip/hip_runtime.h>
#include <math.h>
#include <stdint.h>

// ---------------------------------------------------------------------------
// GroundingModule — round 6: 8-phase split-bf16 GEMMs with full (row&7) XOR
// LDS swizzle (banks 0-31 spread; round 5's 2-bit swizzle only hit banks 0-15).
// Identity storage rows; epilogue derived from the read mapping.
// Virtual K = 2304 (AhBh | AlBh | AhBl), 36 K-tiles of 64, 2 tiles/iter.
// ---------------------------------------------------------------------------

#define DEV __device__ __forceinline__

typedef __attribute__((ext_vector_type(8))) short short8v;   // 8 bf16
typedef __attribute__((ext_vector_type(4))) float f32x4;

constexpr int KDIM  = 768;
constexpr int CHUNK = 32768;
constexpr int NTILE = 36;          // virtual K tiles of 64

// output offsets (floats) in return order
constexpr int OFF_KG   = 0;
constexpr int OFF_MI   = 65536;
constexpr int OFF_ST   = 69632;
constexpr int OFF_ET   = 71680;
constexpr int OFF_MASK = 73728;
constexpr int OFF_ORI  = 139264;

DEV float gelu_erf(float x) { return 0.5f * x * (1.0f + erff(x * 0.70710678118654752f)); }
DEV float wave_sum(float v) { for (int o = 32; o; o >>= 1) v += __shfl_xor(v, o); return v; }
DEV float wave_max(float v) { for (int o = 32; o; o >>= 1) v = fmaxf(v, __shfl_xor(v, o)); return v; }

DEV short f2bf(float x) {                       // f32 -> bf16 (RNE)
    uint32_t u = __builtin_bit_cast(uint32_t, x);
    u = u + 0x7fffu + ((u >> 16) & 1u);
    return (short)(u >> 16);
}
DEV float bf2f(short b) {
    uint32_t u = ((uint32_t)(uint16_t)b) << 16;
    return __builtin_bit_cast(float, u);
}

DEV void gl_lds16(const void* g, void* l) {     // async 16B/lane global->LDS
    __builtin_amdgcn_global_load_lds(
        (const __attribute__((address_space(1))) uint32_t*)g,
        (__attribute__((address_space(3))) uint32_t*)l, 16, 0, 0);
}

// ---------------------------------------------------------------------------
// prep_A1: fused rowstats + LN-affine + hi/lo split.  One wave per row.
__global__ __launch_bounds__(256)
void prep_A1(const float* __restrict__ X, const float* __restrict__ g,
             const float* __restrict__ b, short* __restrict__ Ah, short* __restrict__ Al)
{
    int w = threadIdx.x >> 6, lane = threadIdx.x & 63;
    int row = blockIdx.x * 4 + w;
    const float4* xr = (const float4*)(X + (size_t)row * KDIM);
    float4 xv[3]; float s = 0.f, ss = 0.f;
#pragma unroll
    for (int i = 0; i < 3; ++i) {
        xv[i] = xr[lane + i * 64];
        s  += xv[i].x + xv[i].y + xv[i].z + xv[i].w;
        ss += xv[i].x * xv[i].x + xv[i].y * xv[i].y + xv[i].z * xv[i].z + xv[i].w * xv[i].w;
    }
    s = wave_sum(s); ss = wave_sum(ss);
    float m = s * (1.f / 768.f), var = ss * (1.f / 768.f) - m * m;
    float sa = rsqrtf(var + 1e-5f), ta = -m * sa;
#pragma unroll
    for (int i = 0; i < 3; ++i) {
        int idx = lane + i * 64;
        float4 gv = ((const float4*)g)[idx];
        float4 bv = ((const float4*)b)[idx];
        float a0 = fmaf(fmaf(xv[i].x, sa, ta), gv.x, bv.x);
        float a1 = fmaf(fmaf(xv[i].y, sa, ta), gv.y, bv.y);
        float a2 = fmaf(fmaf(xv[i].z, sa, ta), gv.z, bv.z);
        float a3 = fmaf(fmaf(xv[i].w, sa, ta), gv.w, bv.w);
        short h0 = f2bf(a0), h1 = f2bf(a1), h2 = f2bf(a2), h3 = f2bf(a3);
        ushort4 hv, lv;
        hv.x = (uint16_t)h0; hv.y = (uint16_t)h1; hv.z = (uint16_t)h2; hv.w = (uint16_t)h3;
        lv.x = (uint16_t)f2bf(a0 - bf2f(h0)); lv.y = (uint16_t)f2bf(a1 - bf2f(h1));
        lv.z = (uint16_t)f2bf(a2 - bf2f(h2)); lv.w = (uint16_t)f2bf(a3 - bf2f(h3));
        ((ushort4*)(Ah + (size_t)row * KDIM))[idx] = hv;
        ((ushort4*)(Al + (size_t)row * KDIM))[idx] = lv;
    }
}

// ---------------------------------------------------------------------------
// prep_A2: gate(tanh dot) + LN2 stats + affine + split. vp packed (hi|lo<<16).
__global__ __launch_bounds__(256)
void prep_A2(const uint32_t* __restrict__ vp_hl, const float* __restrict__ qa_p,
             const float* __restrict__ g, const float* __restrict__ b,
             short* __restrict__ Ah, short* __restrict__ Al, int chunk_off)
{
    int w = threadIdx.x >> 6, lane = threadIdx.x & 63;
    int row = blockIdx.x * 4 + w;
    int bidx = (chunk_off + row) >> 5;
    const uint4*  hr = (const uint4*)(vp_hl + (size_t)row * KDIM);
    const float4* qr = (const float4*)(qa_p + (size_t)bidx * KDIM);
    float vp[12]; float s = 0.f, ss = 0.f, d = 0.f;
#pragma unroll
    for (int i = 0; i < 3; ++i) {
        uint4  uv = hr[lane + i * 64];
        float4 qv = qr[lane + i * 64];
        float v0 = bf2f((short)(uv.x & 0xffff)) + bf2f((short)(uv.x >> 16));
        float v1 = bf2f((short)(uv.y & 0xffff)) + bf2f((short)(uv.y >> 16));
        float v2 = bf2f((short)(uv.z & 0xffff)) + bf2f((short)(uv.z >> 16));
        float v3 = bf2f((short)(uv.w & 0xffff)) + bf2f((short)(uv.w >> 16));
        vp[i * 4 + 0] = v0; vp[i * 4 + 1] = v1; vp[i * 4 + 2] = v2; vp[i * 4 + 3] = v3;
        s  += v0 + v1 + v2 + v3;
        ss += v0 * v0 + v1 * v1 + v2 * v2 + v3 * v3;
        d  += v0 * qv.x + v1 * qv.y + v2 * qv.z + v3 * qv.w;
    }
    s = wave_sum(s); ss = wave_sum(ss); d = wave_sum(d);
    float gate = tanhf(d);
    float m = s * (1.f / 768.f), var = ss * (1.f / 768.f) - m * m;
    float den = rsqrtf(gate * gate * var + 1e-5f);
    float sa = gate * den, ta = -gate * m * den;
#pragma unroll
    for (int i = 0; i < 3; ++i) {
        int idx = lane + i * 64;
        float4 gv = ((const float4*)g)[idx];
        float4 bv = ((const float4*)b)[idx];
        float a0 = fmaf(fmaf(vp[i * 4 + 0], sa, ta), gv.x, bv.x);
        float a1 = fmaf(fmaf(vp[i * 4 + 1], sa, ta), gv.y, bv.y);
        float a2 = fmaf(fmaf(vp[i * 4 + 2], sa, ta), gv.z, bv.z);
        float a3 = fmaf(fmaf(vp[i * 4 + 3], sa, ta), gv.w, bv.w);
        short h0 = f2bf(a0), h1 = f2bf(a1), h2 = f2bf(a2), h3 = f2bf(a3);
        ushort4 hv, lv;
        hv.x = (uint16_t)h0; hv.y = (uint16_t)h1; hv.z = (uint16_t)h2; hv.w = (uint16_t)h3;
        lv.x = (uint16_t)f2bf(a0 - bf2f(h0)); lv.y = (uint16_t)f2bf(a1 - bf2f(h1));
        lv.z = (uint16_t)f2bf(a2 - bf2f(h2)); lv.w = (uint16_t)f2bf(a3 - bf2f(h3));
        ((ushort4*)(Ah + (size_t)row * KDIM))[idx] = hv;
        ((ushort4*)(Al + (size_t)row * KDIM))[idx] = lv;
    }
}

// ---------------------------------------------------------------------------
// prep_W: transpose + hi/lo split.  W[k][n] f32 -> Bh/Bl[n][k] bf16.
__global__ __launch_bounds__(256)
void prep_W(const float* __restrict__ W, short* __restrict__ Bh, short* __restrict__ Bl, int N)
{
    __shared__ float t[32][33];
    int bx = blockIdx.x, by = blockIdx.y;
    int lx = threadIdx.x & 31, ly = threadIdx.x >> 5;
#pragma unroll
    for (int r = 0; r < 32; r += 8)
        t[ly + r][lx] = W[(size_t)(by * 32 + ly + r) * N + bx * 32 + lx];
    __syncthreads();
#pragma unroll
    for (int r = 0; r < 32; r += 8) {
        float v = t[lx][ly + r];
        short hi = f2bf(v);
        size_t o = (size_t)(bx * 32 + ly + r) * KDIM + by * 32 + lx;
        Bh[o] = hi;
        Bl[o] = f2bf(v - bf2f(hi));
    }
}

// ---------------------------------------------------------------------------
// 8-phase split-bf16 MFMA GEMM.  512 thr / 8 waves (2M x 4N).
// LDS rows = 128B (K-tile 64); chunk position c ^= (row & 7)  <=>
// byte ^= (row&7)<<4  — spreads every row across all 32 banks.
//   MODE 0: BM=256 BN=256, out = gelu(.) packed (hi|lo<<16) u32.
//   MODE 1: BM=128 BN=384, partial row-dot with w2 -> partials[wn][row].
#define VM4  asm volatile("s_waitcnt vmcnt(4)" ::: "memory")
#define VM0  asm volatile("s_waitcnt vmcnt(0)" ::: "memory")

#define STAGE(U, TT) do {                                                     \
    const int sT_ = (TT);                                                     \
    const int seg_ = (sT_ >= 24) ? 2 : ((sT_ >= 12) ? 1 : 0);                 \
    const int kp_ = (sT_ - seg_ * 12) << 6;                                   \
    const short* sb_ = ((U) < 2) ? ((seg_ == 1) ? APl : APh)                  \
                                 : ((seg_ == 2) ? BPl : BPh);                 \
    char* db_ = lds + ((sT_) & 1) * BUFSZ;                                    \
    _Pragma("unroll")                                                         \
    for (int j_ = 0; j_ < UL_[(U)]; ++j_)                                     \
        gl_lds16(sb_ + goff[(U)][j_] + kp_, db_ + ldso[(U)][j_]);             \
} while (0)

#define PHASE(P, VMSTMT, ...) do {                                            \
    constexpr int mh_ = ((P) >> 1) & 1, nh_ = (P) & 1;                        \
    const char* Ab_ = lds + (((P) >> 2) & 1) * BUFSZ;                         \
    const char* Bb_ = Ab_ + BREG;                                             \
    short8v av[QM][2], bv[QN][2];                                             \
    _Pragma("unroll")                                                         \
    for (int nf = 0; nf < QN; ++nf) {                                         \
        int sB = nh_ * (BN / 2) + wn * (BN / 8) + nf * 16 + lr;               \
        int so = (lh ^ (sB & 7)) << 4;                                        \
        bv[nf][0] = *(const short8v*)(Bb_ + sB * 128 + so);                   \
        bv[nf][1] = *(const short8v*)(Bb_ + sB * 128 + (so ^ 64));            \
    }                                                                         \
    _Pragma("unroll")                                                         \
    for (int mf = 0; mf < QM; ++mf) {                                         \
        int sA = mh_ * (BM / 2) + wm * (BM / 4) + mf * 16 + lr;               \
        int so = (lh ^ (sA & 7)) << 4;                                        \
        av[mf][0] = *(const short8v*)(Ab_ + sA * 128 + so);                   \
        av[mf][1] = *(const short8v*)(Ab_ + sA * 128 + (so ^ 64));            \
    }                                                                         \
    __VA_ARGS__;                                                              \
    VMSTMT;                                                                   \
    __builtin_amdgcn_sched_barrier(0);                                        \
    __builtin_amdgcn_s_barrier();                                             \
    asm volatile("s_waitcnt lgkmcnt(0)" ::: "memory");                        \
    __builtin_amdgcn_sched_barrier(0);                                        \
    __builtin_amdgcn_s_setprio(1);                                            \
    _Pragma("unroll")                                                         \
    for (int mf = 0; mf < QM; ++mf)                                           \
        _Pragma("unroll")                                                     \
        for (int nf = 0; nf < QN; ++nf) {                                     \
            acc[mh_ * QM + mf][nh_ * QN + nf] =                               \
                __builtin_amdgcn_mfma_f32_16x16x32_bf16(av[mf][0], bv[nf][0], \
                    acc[mh_ * QM + mf][nh_ * QN + nf], 0, 0, 0);              \
            acc[mh_ * QM + mf][nh_ * QN + nf] =                               \
                __builtin_amdgcn_mfma_f32_16x16x32_bf16(av[mf][1], bv[nf][1], \
                    acc[mh_ * QM + mf][nh_ * QN + nf], 0, 0, 0);              \
        }                                                                     \
    __builtin_amdgcn_s_setprio(0);                                            \
    __builtin_amdgcn_sched_barrier(0);                                        \
    __builtin_amdgcn_s_barrier();                                             \
} while (0)

template<int MODE>
__global__ __launch_bounds__(512, 1)
void gemm8(const short* __restrict__ Ah_g, const short* __restrict__ Al_g,
           const short* __restrict__ Bh_g, const short* __restrict__ Bl_g,
           const float* __restrict__ bias, uint32_t* __restrict__ O_hl,
           const float* __restrict__ w2, float* __restrict__ partials,
           int chunk_off)
{
    constexpr int BM = MODE ? 128 : 256;
    constexpr int BN = MODE ? 384 : 256;
    constexpr int QM = MODE ? 2 : 4;          // M frags per quadrant
    constexpr int QN = MODE ? 3 : 2;          // N frags per quadrant
    constexpr int MFR = 2 * QM, NFR = 2 * QN;
    constexpr int BREG  = BM * 128;           // B region byte offset
    constexpr int BUFSZ = (BM + BN) * 128;    // 64 KB per buf
    constexpr int US0[4] = { 0, BM / 2, 0, BN / 2 };      // unit start row
    constexpr int UL_[4] = { BM / 128, BM / 128, BN / 128, BN / 128 };
    extern __shared__ __align__(16) char lds[];

    const int t = threadIdx.x;
    const int w = t >> 6, lane = t & 63;
    const int lr = lane & 15, lh = lane >> 4;
    const int wm = w >> 2, wn = w & 3;        // 2 x 4 wave grid

    const int gx = gridDim.x, nwg = gx * gridDim.y;
    int bidx = blockIdx.y * gx + blockIdx.x;
    int wid = (bidx & 7) * (nwg >> 3) + (bidx >> 3);
    const int bx = wid % gx, by = wid / gx;
    const int row0 = by * BM, col0 = bx * BN;

    const short* APh = Ah_g + (size_t)row0 * KDIM;
    const short* APl = Al_g + (size_t)row0 * KDIM;
    const short* BPh = Bh_g + (size_t)col0 * KDIM;
    const short* BPl = Bl_g + (size_t)col0 * KDIM;

    // stage precompute: identity storage rows; source column pre-swizzled
    // (chunk c holds global k-chunk c ^ (row&7)); LDS dest stays linear.
    size_t goff[4][3];
    int    ldso[4][3];
#pragma unroll
    for (int u = 0; u < 4; ++u)
#pragma unroll
        for (int j = 0; j < 3; ++j) {
            if (j >= UL_[u]) continue;
            int p  = j * 512 + t;
            int sr = US0[u] + (p >> 3);       // storage row (= tile row)
            int c  = p & 7;                   // 16B chunk slot in 128B row
            goff[u][j] = (size_t)sr * KDIM + ((c ^ (sr & 7)) << 3);
            ldso[u][j] = (u < 2 ? 0 : BREG) + US0[u] * 128 + (j * 512 + (t & ~63)) * 16;
        }

    f32x4 acc[MFR][NFR] = {};

    // prologue: t0 {A0,B0,A1,B1} + t1 {A0,B0}; vmcnt(4) -> t0 landed
    STAGE(0, 0); STAGE(2, 0); STAGE(1, 0); STAGE(3, 0);
    STAGE(0, 1); STAGE(2, 1);
    VM4;
    __builtin_amdgcn_s_barrier();

    for (int i = 0; i < NTILE / 2; ++i) {
        const int  T1 = 2 * i + 1, T2 = 2 * i + 2, T3 = 2 * i + 3;
        const bool nl = (i < NTILE / 2 - 1);
        PHASE(0, (void)0,            STAGE(1, T1));
        PHASE(1, (void)0,            STAGE(3, T1));
        PHASE(2, (void)0,            if (nl) STAGE(0, T2));
        PHASE(3, if (nl) VM4; else VM0, if (nl) STAGE(2, T2));
        PHASE(4, (void)0,            if (nl) STAGE(1, T2));
        PHASE(5, (void)0,            if (nl) STAGE(3, T2));
        PHASE(6, (void)0,            if (nl) STAGE(0, T3));
        PHASE(7, VM4,                if (nl) STAGE(2, T3));
    }

    if (MODE == 0) {
#pragma unroll
        for (int im = 0; im < MFR; ++im)
#pragma unroll
            for (int in = 0; in < NFR; ++in) {
                int n = col0 + (in >> 1) * 128 + wn * 32 + (in & 1) * 16 + lr;
                float bvs = bias[n];
#pragma unroll
                for (int q = 0; q < 4; ++q) {
                    int m = row0 + (im >> 2) * 128 + wm * 64 + (im & 3) * 16 + lh * 4 + q;
                    float gv = gelu_erf(acc[im][in][q] + bvs);
                    short hi = f2bf(gv);
                    short lo = f2bf(gv - bf2f(hi));
                    O_hl[(size_t)m * 768 + n] =
                        (uint32_t)(uint16_t)hi | ((uint32_t)(uint16_t)lo << 16);
                }
            }
    } else {
        float rs[MFR][4] = {};
#pragma unroll
        for (int im = 0; im < MFR; ++im)
#pragma unroll
            for (int in = 0; in < NFR; ++in) {
                int n = (in / 3) * 192 + wn * 48 + (in % 3) * 16 + lr;
                float bvs = bias[n], wv = w2[n];
#pragma unroll
                for (int q = 0; q < 4; ++q)
                    rs[im][q] += gelu_erf(acc[im][in][q] + bvs) * wv;
            }
#pragma unroll
        for (int im = 0; im < MFR; ++im)
#pragma unroll
            for (int q = 0; q < 4; ++q) {
                float vv = rs[im][q];
                vv += __shfl_xor(vv, 1); vv += __shfl_xor(vv, 2);
                vv += __shfl_xor(vv, 4); vv += __shfl_xor(vv, 8);
                if (lr == 0) {
                    int m = chunk_off + row0 + (im >> 1) * 64 + wm * 32 + (im & 1) * 16 + lh * 4 + q;
                    partials[(size_t)wn * 65536 + m] = vv;
                }
            }
    }
}

// ---------------------------------------------------------------------------
// f32 fallback GEMM for the small qa projection.
constexpr int BKF = 16;
__global__ __launch_bounds__(256)
void rowstats(const float* __restrict__ X, float2* __restrict__ st, int M)
{
    int wave = threadIdx.x >> 6, lane = threadIdx.x & 63;
    int row = blockIdx.x * 4 + wave;
    if (row >= M) return;
    const float4* xr = reinterpret_cast<const float4*>(X + (size_t)row * KDIM);
    float s = 0.f, ss = 0.f;
#pragma unroll
    for (int i = 0; i < 3; ++i) {
        float4 v = xr[lane + i * 64];
        s  += v.x + v.y + v.z + v.w;
        ss += v.x * v.x + v.y * v.y + v.z * v.z + v.w * v.w;
    }
    s = wave_sum(s); ss = wave_sum(ss);
    if (lane == 0) {
        float m = s * (1.0f / 768.0f);
        float var = ss * (1.0f / 768.0f) - m * m;
        float rstd = rsqrtf(var + 1e-5f);
        st[row] = make_float2(rstd, -m * rstd);
    }
}

template<int BM, int BN, int TM, int TN>
__global__ __launch_bounds__(256)
void gemm_fused(const float* __restrict__ X, const float2* __restrict__ st,
                const float* __restrict__ gw, const float* __restrict__ gb,
                const float* __restrict__ W, const float* __restrict__ bias,
                float* __restrict__ out, int M, int N)
{
    static_assert((BM / TM) * (BN / TN) == 256, "256 threads");
    __shared__ float As[BKF][BM];
    __shared__ float Bs[BKF][BN];
    const int t = threadIdx.x;
    constexpr int TXN = BN / TN;
    const int tx = t % TXN;
    const int ty = t / TXN;
    const int row0 = blockIdx.y * BM;
    const int col0 = blockIdx.x * BN;
    float acc[TM][TN] = {};
    constexpr int A_IT = BM * BKF / 4 / 256;
    constexpr int B_IT = BKF * BN / 4 / 256;
    for (int k0 = 0; k0 < KDIM; k0 += BKF) {
#pragma unroll
        for (int i = 0; i < A_IT; ++i) {
            int idx = t + i * 256;
            int r = idx >> 2;
            int c = (idx & 3) << 2;
            float4 xv = *reinterpret_cast<const float4*>(X + (size_t)(row0 + r) * KDIM + k0 + c);
            float2 s = st[row0 + r];
            float4 gv = *reinterpret_cast<const float4*>(gw + k0 + c);
            float4 bv = *reinterpret_cast<const float4*>(gb + k0 + c);
            As[c + 0][r] = fmaf(fmaf(xv.x, s.x, s.y), gv.x, bv.x);
            As[c + 1][r] = fmaf(fmaf(xv.y, s.x, s.y), gv.y, bv.y);
            As[c + 2][r] = fmaf(fmaf(xv.z, s.x, s.y), gv.z, bv.z);
            As[c + 3][r] = fmaf(fmaf(xv.w, s.x, s.y), gv.w, bv.w);
        }
#pragma unroll
        for (int i = 0; i < B_IT; ++i) {
            int idx = t + i * 256;
            int r = idx / (BN / 4);
            int c = (idx % (BN / 4)) << 2;
            *reinterpret_cast<float4*>(&Bs[r][c]) =
                *reinterpret_cast<const float4*>(W + (size_t)(k0 + r) * N + col0 + c);
        }
        __syncthreads();
#pragma unroll
        for (int kk = 0; kk < BKF; ++kk) {
            float a[TM], b[TN];
#pragma unroll
            for (int i = 0; i < TM; i += 4)
                *reinterpret_cast<float4*>(&a[i]) = *reinterpret_cast<const float4*>(&As[kk][ty * TM + i]);
#pragma unroll
            for (int j = 0; j < TN; j += 4)
                *reinterpret_cast<float4*>(&b[j]) = *reinterpret_cast<const float4*>(&Bs[kk][tx * TN + j]);
#pragma unroll
            for (int i = 0; i < TM; ++i)
#pragma unroll
                for (int j = 0; j < TN; ++j)
                    acc[i][j] = fmaf(a[i], b[j], acc[i][j]);
        }
        __syncthreads();
    }
#pragma unroll
    for (int i = 0; i < TM; ++i) {
        size_t row = row0 + ty * TM + i;
#pragma unroll
        for (int j = 0; j < TN; j += 4) {
            int col = col0 + tx * TN + j;
            float4 o;
            o.x = gelu_erf(acc[i][j + 0] + bias[col + 0]);
            o.y = gelu_erf(acc[i][j + 1] + bias[col + 1]);
            o.z = gelu_erf(acc[i][j + 2] + bias[col + 2]);
            o.w = gelu_erf(acc[i][j + 3] + bias[col + 3]);
            *reinterpret_cast<float4*>(out + row * N + col) = o;
        }
    }
}

// ---------------------------------------------------------------------------
// head: logits = sum(4 partials)+b2 -> softmax -> smooth -> softmax -> decode.
__global__ __launch_bounds__(64)
void head_kernel(const float* __restrict__ partials, const float* __restrict__ b2,
                 const float* __restrict__ sigma_p, float* __restrict__ out)
{
    int b = blockIdx.x, lane = threadIdx.x;
    __shared__ float ok[36];
    __shared__ float kg[32];
    __shared__ int sel[2];

    if (lane < 36) ok[lane] = 0.f;
    __syncthreads();

    float x = -3.4e38f;
    if (lane < 32) {
        int row = b * 32 + lane;
        x = b2[0];
#pragma unroll
        for (int p = 0; p < 4; ++p) x += partials[(size_t)p * 65536 + row];
    }
    float mx = wave_max(x);
    float e = (lane < 32) ? expf(x - mx) : 0.f;
    float sum = wave_sum(e);
    float ori = e / sum;
    if (lane < 32) {
        out[OFF_ORI + b * 32 + lane] = ori;
        ok[lane + 2] = ori;
    }
    __syncthreads();

    float sg = sigma_p[0];
    float kern[5]; float ks = 0.f;
#pragma unroll
    for (int k = 0; k < 5; ++k) { float xx = (float)(k - 2) / sg; kern[k] = expf(-0.5f * xx * xx); ks += kern[k]; }
    float sm = -3.4e38f;
    if (lane < 32) {
        sm = 0.f;
#pragma unroll
        for (int k = 0; k < 5; ++k) sm += (kern[k] / ks) * ok[lane + k];
    }
    float mx2 = wave_max(sm);
    float e2 = (lane < 32) ? expf(sm - mx2) : 0.f;
    float sum2 = wave_sum(e2);
    float kgv = e2 / sum2;
    if (lane < 32) {
        out[OFF_KG + b * 32 + lane] = kgv;
        kg[lane] = kgv;
    }
    __syncthreads();

    if (lane == 0) {
        int pm = 0; float bv = kg[0];
        for (int i = 1; i < 32; ++i) if (kg[i] > bv) { bv = kg[i]; pm = i; }
        float cum[33]; cum[0] = 0.f;
        for (int i = 0; i < 32; ++i) cum[i + 1] = cum[i] + kg[i];
        float bs = -3.4e38f; int bst = 0, ben = 0;
        const int wsz[3] = {1, 3, 5};
        for (int wi = 0; wi < 3; ++wi) {
            int w = wsz[wi];
            for (int s = 0; s + w <= 32; ++s) {
                if (pm >= s && pm < s + w) {
                    float sc = cum[s + w] - cum[s];
                    if (sc > bs) { bs = sc; bst = s; ben = s + w; }
                }
            }
        }
        out[OFF_MI + b * 2 + 0] = (float)bst;
        out[OFF_MI + b * 2 + 1] = (float)ben;
        out[OFF_ST + b] = (float)bst / 31.0f;
        out[OFF_ET + b] = (float)ben / 31.0f;
        sel[0] = bst; sel[1] = ben;
    }
    __syncthreads();
    if (lane < 32)
        out[OFF_MASK + b * 32 + lane] = (lane >= sel[0] && lane <= sel[1]) ? 1.0f : 0.0f;
}

// ---------------------------------------------------------------------------
extern "C" void kernel_launch(void* const* d_in, const int* in_sizes, int n_in,
                              void* d_out, int out_size, void* d_ws, size_t ws_size,
                              hipStream_t stream)
{
    const float* v      = (const float*)d_in[0];
    const float* qa     = (const float*)d_in[1];
    const float* vp_lng = (const float*)d_in[2];
    const float* vp_lnb = (const float*)d_in[3];
    const float* vp_w   = (const float*)d_in[4];
    const float* vp_b   = (const float*)d_in[5];
    const float* qp_lng = (const float*)d_in[6];
    const float* qp_lnb = (const float*)d_in[7];
    const float* qp_w   = (const float*)d_in[8];
    const float* qp_b   = (const float*)d_in[9];
    const float* g_lng  = (const float*)d_in[10];
    const float* g_lnb  = (const float*)d_in[11];
    const float* g_w1   = (const float*)d_in[12];
    const float* g_b1   = (const float*)d_in[13];
    const float* g_w2   = (const float*)d_in[14];
    const float* g_b2   = (const float*)d_in[15];
    const float* sigma  = (const float*)d_in[16];
    float* outf = (float*)d_out;

    // workspace layout (~213 MB)
    short* A1h = (short*)d_ws;                           // CHUNK*768
    short* A1l = A1h + (size_t)CHUNK * KDIM;
    uint32_t* vp_hl = (uint32_t*)(A1l + (size_t)CHUNK * KDIM);   // CHUNK*768 u32
    short* B1h = (short*)(vp_hl + (size_t)CHUNK * KDIM); // 768*768
    short* B1l = B1h + 768 * KDIM;
    short* B2h = B1l + 768 * KDIM;                       // 384*768
    short* B2l = B2h + 384 * KDIM;
    float* qa_p = (float*)(B2l + 384 * KDIM);            // 2048*768
    float* st_qa = qa_p + 2048 * KDIM;                   // 2048*2
    float* partials = st_qa + 4096;                      // 4*65536

    // qa path (small, f32 vector GEMM)
    rowstats<<<512, 256, 0, stream>>>(qa, (float2*)st_qa, 2048);
    gemm_fused<64, 64, 4, 4><<<dim3(12, 32), 256, 0, stream>>>(
        qa, (const float2*)st_qa, qp_lng, qp_lnb, qp_w, qp_b, qa_p, 2048, 768);

    // weight transpose + split
    prep_W<<<dim3(24, 24), 256, 0, stream>>>(vp_w, B1h, B1l, 768);
    prep_W<<<dim3(12, 24), 256, 0, stream>>>(g_w1, B2h, B2l, 384);

    constexpr int LDS8 = 131072;   // 2 bufs x 64 KB (both modes)

    for (int c = 0; c < 65536; c += CHUNK) {
        prep_A1<<<CHUNK / 4, 256, 0, stream>>>(v + (size_t)c * KDIM, vp_lng, vp_lnb, A1h, A1l);
        // v_p = gelu(A1 @ vp_w^T + vp_b): 256x256 tile, grid (3,128)
        gemm8<0><<<dim3(3, CHUNK / 256), 512, LDS8, stream>>>(
            A1h, A1l, B1h, B1l, vp_b, vp_hl, nullptr, nullptr, 0);
        prep_A2<<<CHUNK / 4, 256, 0, stream>>>(vp_hl, qa_p, g_lng, g_lnb, A1h, A1l, c);
        // fused h@g_w1+gelu+dot(g_w2): 128x384 tile, grid (1,256)
        gemm8<1><<<dim3(1, CHUNK / 128), 512, LDS8, stream>>>(
            A1h, A1l, B2h, B2l, g_b1, nullptr, g_w2, partials, c);
    }

    head_kernel<<<2048, 64, 0, stream>>>(partials, g_b2, sigma, outf);
}

// Round 7
// 715.250 us; speedup vs baseline: 1.1870x; 1.0602x over previous
//
#include <hip/hip_runtime.h>
#include <math.h>
#include <stdint.h>

// ---------------------------------------------------------------------------
// GroundingModule — round 7: 8-phase split-bf16 GEMMs, gray-code quadrant
// order with register-resident operands: 24 ds_read_b128 per K-tile per wave
// (round 6 re-read both operands every phase = 48).  Swizzle + stage schedule
// + vmcnt points unchanged from round 6 (verified conflict-free & race-free).
// Virtual K = 2304 (AhBh | AlBh | AhBl), 36 K-tiles of 64, 2 tiles/iter.
// ---------------------------------------------------------------------------

#define DEV __device__ __forceinline__

typedef __attribute__((ext_vector_type(8))) short short8v;   // 8 bf16
typedef __attribute__((ext_vector_type(4))) float f32x4;

constexpr int KDIM  = 768;
constexpr int CHUNK = 32768;
constexpr int NTILE = 36;          // virtual K tiles of 64

// output offsets (floats) in return order
constexpr int OFF_KG   = 0;
constexpr int OFF_MI   = 65536;
constexpr int OFF_ST   = 69632;
constexpr int OFF_ET   = 71680;
constexpr int OFF_MASK = 73728;
constexpr int OFF_ORI  = 139264;

DEV float gelu_erf(float x) { return 0.5f * x * (1.0f + erff(x * 0.70710678118654752f)); }
DEV float wave_sum(float v) { for (int o = 32; o; o >>= 1) v += __shfl_xor(v, o); return v; }
DEV float wave_max(float v) { for (int o = 32; o; o >>= 1) v = fmaxf(v, __shfl_xor(v, o)); return v; }

DEV short f2bf(float x) {                       // f32 -> bf16 (RNE)
    uint32_t u = __builtin_bit_cast(uint32_t, x);
    u = u + 0x7fffu + ((u >> 16) & 1u);
    return (short)(u >> 16);
}
DEV float bf2f(short b) {
    uint32_t u = ((uint32_t)(uint16_t)b) << 16;
    return __builtin_bit_cast(float, u);
}

DEV void gl_lds16(const void* g, void* l) {     // async 16B/lane global->LDS
    __builtin_amdgcn_global_load_lds(
        (const __attribute__((address_space(1))) uint32_t*)g,
        (__attribute__((address_space(3))) uint32_t*)l, 16, 0, 0);
}

// ---------------------------------------------------------------------------
// prep_A1: fused rowstats + LN-affine + hi/lo split.  One wave per row.
__global__ __launch_bounds__(256)
void prep_A1(const float* __restrict__ X, const float* __restrict__ g,
             const float* __restrict__ b, short* __restrict__ Ah, short* __restrict__ Al)
{
    int w = threadIdx.x >> 6, lane = threadIdx.x & 63;
    int row = blockIdx.x * 4 + w;
    const float4* xr = (const float4*)(X + (size_t)row * KDIM);
    float4 xv[3]; float s = 0.f, ss = 0.f;
#pragma unroll
    for (int i = 0; i < 3; ++i) {
        xv[i] = xr[lane + i * 64];
        s  += xv[i].x + xv[i].y + xv[i].z + xv[i].w;
        ss += xv[i].x * xv[i].x + xv[i].y * xv[i].y + xv[i].z * xv[i].z + xv[i].w * xv[i].w;
    }
    s = wave_sum(s); ss = wave_sum(ss);
    float m = s * (1.f / 768.f), var = ss * (1.f / 768.f) - m * m;
    float sa = rsqrtf(var + 1e-5f), ta = -m * sa;
#pragma unroll
    for (int i = 0; i < 3; ++i) {
        int idx = lane + i * 64;
        float4 gv = ((const float4*)g)[idx];
        float4 bv = ((const float4*)b)[idx];
        float a0 = fmaf(fmaf(xv[i].x, sa, ta), gv.x, bv.x);
        float a1 = fmaf(fmaf(xv[i].y, sa, ta), gv.y, bv.y);
        float a2 = fmaf(fmaf(xv[i].z, sa, ta), gv.z, bv.z);
        float a3 = fmaf(fmaf(xv[i].w, sa, ta), gv.w, bv.w);
        short h0 = f2bf(a0), h1 = f2bf(a1), h2 = f2bf(a2), h3 = f2bf(a3);
        ushort4 hv, lv;
        hv.x = (uint16_t)h0; hv.y = (uint16_t)h1; hv.z = (uint16_t)h2; hv.w = (uint16_t)h3;
        lv.x = (uint16_t)f2bf(a0 - bf2f(h0)); lv.y = (uint16_t)f2bf(a1 - bf2f(h1));
        lv.z = (uint16_t)f2bf(a2 - bf2f(h2)); lv.w = (uint16_t)f2bf(a3 - bf2f(h3));
        ((ushort4*)(Ah + (size_t)row * KDIM))[idx] = hv;
        ((ushort4*)(Al + (size_t)row * KDIM))[idx] = lv;
    }
}

// ---------------------------------------------------------------------------
// prep_A2: gate(tanh dot) + LN2 stats + affine + split. vp packed (hi|lo<<16).
__global__ __launch_bounds__(256)
void prep_A2(const uint32_t* __restrict__ vp_hl, const float* __restrict__ qa_p,
             const float* __restrict__ g, const float* __restrict__ b,
             short* __restrict__ Ah, short* __restrict__ Al, int chunk_off)
{
    int w = threadIdx.x >> 6, lane = threadIdx.x & 63;
    int row = blockIdx.x * 4 + w;
    int bidx = (chunk_off + row) >> 5;
    const uint4*  hr = (const uint4*)(vp_hl + (size_t)row * KDIM);
    const float4* qr = (const float4*)(qa_p + (size_t)bidx * KDIM);
    float vp[12]; float s = 0.f, ss = 0.f, d = 0.f;
#pragma unroll
    for (int i = 0; i < 3; ++i) {
        uint4  uv = hr[lane + i * 64];
        float4 qv = qr[lane + i * 64];
        float v0 = bf2f((short)(uv.x & 0xffff)) + bf2f((short)(uv.x >> 16));
        float v1 = bf2f((short)(uv.y & 0xffff)) + bf2f((short)(uv.y >> 16));
        float v2 = bf2f((short)(uv.z & 0xffff)) + bf2f((short)(uv.z >> 16));
        float v3 = bf2f((short)(uv.w & 0xffff)) + bf2f((short)(uv.w >> 16));
        vp[i * 4 + 0] = v0; vp[i * 4 + 1] = v1; vp[i * 4 + 2] = v2; vp[i * 4 + 3] = v3;
        s  += v0 + v1 + v2 + v3;
        ss += v0 * v0 + v1 * v1 + v2 * v2 + v3 * v3;
        d  += v0 * qv.x + v1 * qv.y + v2 * qv.z + v3 * qv.w;
    }
    s = wave_sum(s); ss = wave_sum(ss); d = wave_sum(d);
    float gate = tanhf(d);
    float m = s * (1.f / 768.f), var = ss * (1.f / 768.f) - m * m;
    float den = rsqrtf(gate * gate * var + 1e-5f);
    float sa = gate * den, ta = -gate * m * den;
#pragma unroll
    for (int i = 0; i < 3; ++i) {
        int idx = lane + i * 64;
        float4 gv = ((const float4*)g)[idx];
        float4 bv = ((const float4*)b)[idx];
        float a0 = fmaf(fmaf(vp[i * 4 + 0], sa, ta), gv.x, bv.x);
        float a1 = fmaf(fmaf(vp[i * 4 + 1], sa, ta), gv.y, bv.y);
        float a2 = fmaf(fmaf(vp[i * 4 + 2], sa, ta), gv.z, bv.z);
        float a3 = fmaf(fmaf(vp[i * 4 + 3], sa, ta), gv.w, bv.w);
        short h0 = f2bf(a0), h1 = f2bf(a1), h2 = f2bf(a2), h3 = f2bf(a3);
        ushort4 hv, lv;
        hv.x = (uint16_t)h0; hv.y = (uint16_t)h1; hv.z = (uint16_t)h2; hv.w = (uint16_t)h3;
        lv.x = (uint16_t)f2bf(a0 - bf2f(h0)); lv.y = (uint16_t)f2bf(a1 - bf2f(h1));
        lv.z = (uint16_t)f2bf(a2 - bf2f(h2)); lv.w = (uint16_t)f2bf(a3 - bf2f(h3));
        ((ushort4*)(Ah + (size_t)row * KDIM))[idx] = hv;
        ((ushort4*)(Al + (size_t)row * KDIM))[idx] = lv;
    }
}

// ---------------------------------------------------------------------------
// prep_W: transpose + hi/lo split.  W[k][n] f32 -> Bh/Bl[n][k] bf16.
__global__ __launch_bounds__(256)
void prep_W(const float* __restrict__ W, short* __restrict__ Bh, short* __restrict__ Bl, int N)
{
    __shared__ float t[32][33];
    int bx = blockIdx.x, by = blockIdx.y;
    int lx = threadIdx.x & 31, ly = threadIdx.x >> 5;
#pragma unroll
    for (int r = 0; r < 32; r += 8)
        t[ly + r][lx] = W[(size_t)(by * 32 + ly + r) * N + bx * 32 + lx];
    __syncthreads();
#pragma unroll
    for (int r = 0; r < 32; r += 8) {
        float v = t[lx][ly + r];
        short hi = f2bf(v);
        size_t o = (size_t)(bx * 32 + ly + r) * KDIM + by * 32 + lx;
        Bh[o] = hi;
        Bl[o] = f2bf(v - bf2f(hi));
    }
}

// ---------------------------------------------------------------------------
// 8-phase split-bf16 MFMA GEMM.  512 thr / 8 waves (2M x 4N).
// Gray-code quadrant order: P%4 = 0:(mh0,nh0) read A0+B0 | 1:(mh1,nh0) read A1
// | 2:(mh0,nh1) read B1 | 3:(mh1,nh1) no reads.  Operands register-resident.
// LDS row = 128B, chunk c ^= (row&7) swizzle (32-bank spread, verified 0-confl).
#define VM4  asm volatile("s_waitcnt vmcnt(4)" ::: "memory")
#define VM0  asm volatile("s_waitcnt vmcnt(0)" ::: "memory")

#define STAGE(U, TT) do {                                                     \
    const int sT_ = (TT);                                                     \
    const int seg_ = (sT_ >= 24) ? 2 : ((sT_ >= 12) ? 1 : 0);                 \
    const int kp_ = (sT_ - seg_ * 12) << 6;                                   \
    const short* sb_ = ((U) < 2) ? ((seg_ == 1) ? APl : APh)                  \
                                 : ((seg_ == 2) ? BPl : BPh);                 \
    char* db_ = lds + ((sT_) & 1) * BUFSZ;                                    \
    _Pragma("unroll")                                                         \
    for (int j_ = 0; j_ < UL_[(U)]; ++j_)                                     \
        gl_lds16(sb_ + goff[(U)][j_] + kp_, db_ + ldso[(U)][j_]);             \
} while (0)

#define PHASE(P, VMSTMT, ...) do {                                            \
    constexpr int mh_ = (P) & 1, nh_ = ((P) >> 1) & 1;                        \
    const char* Ab_ = lds + (((P) >> 2) & 1) * BUFSZ;                         \
    const char* Bb_ = Ab_ + BREG;                                             \
    if ((P) % 4 == 0) {                                                       \
        _Pragma("unroll")                                                     \
        for (int nf = 0; nf < QN; ++nf) {                                     \
            int sB = wn * (BN / 8) + nf * 16 + lr;                            \
            int so = (lh ^ (sB & 7)) << 4;                                    \
            bv[0][nf][0] = *(const short8v*)(Bb_ + sB * 128 + so);            \
            bv[0][nf][1] = *(const short8v*)(Bb_ + sB * 128 + (so ^ 64));     \
        }                                                                     \
        _Pragma("unroll")                                                     \
        for (int mf = 0; mf < QM; ++mf) {                                     \
            int sA = wm * (BM / 4) + mf * 16 + lr;                            \
            int so = (lh ^ (sA & 7)) << 4;                                    \
            av[0][mf][0] = *(const short8v*)(Ab_ + sA * 128 + so);            \
            av[0][mf][1] = *(const short8v*)(Ab_ + sA * 128 + (so ^ 64));     \
        }                                                                     \
    } else if ((P) % 4 == 1) {                                                \
        _Pragma("unroll")                                                     \
        for (int mf = 0; mf < QM; ++mf) {                                     \
            int sA = (BM / 2) + wm * (BM / 4) + mf * 16 + lr;                 \
            int so = (lh ^ (sA & 7)) << 4;                                    \
            av[1][mf][0] = *(const short8v*)(Ab_ + sA * 128 + so);            \
            av[1][mf][1] = *(const short8v*)(Ab_ + sA * 128 + (so ^ 64));     \
        }                                                                     \
    } else if ((P) % 4 == 2) {                                                \
        _Pragma("unroll")                                                     \
        for (int nf = 0; nf < QN; ++nf) {                                     \
            int sB = (BN / 2) + wn * (BN / 8) + nf * 16 + lr;                 \
            int so = (lh ^ (sB & 7)) << 4;                                    \
            bv[1][nf][0] = *(const short8v*)(Bb_ + sB * 128 + so);            \
            bv[1][nf][1] = *(const short8v*)(Bb_ + sB * 128 + (so ^ 64));     \
        }                                                                     \
    }                                                                         \
    __VA_ARGS__;                                                              \
    VMSTMT;                                                                   \
    __builtin_amdgcn_sched_barrier(0);                                        \
    __builtin_amdgcn_s_barrier();                                             \
    asm volatile("s_waitcnt lgkmcnt(0)" ::: "memory");                        \
    __builtin_amdgcn_sched_barrier(0);                                        \
    __builtin_amdgcn_s_setprio(1);                                            \
    _Pragma("unroll")                                                         \
    for (int mf = 0; mf < QM; ++mf)                                           \
        _Pragma("unroll")                                                     \
        for (int nf = 0; nf < QN; ++nf) {                                     \
            acc[mh_ * QM + mf][nh_ * QN + nf] =                               \
                __builtin_amdgcn_mfma_f32_16x16x32_bf16(av[mh_][mf][0],       \
                    bv[nh_][nf][0], acc[mh_ * QM + mf][nh_ * QN + nf], 0, 0, 0); \
            acc[mh_ * QM + mf][nh_ * QN + nf] =                               \
                __builtin_amdgcn_mfma_f32_16x16x32_bf16(av[mh_][mf][1],       \
                    bv[nh_][nf][1], acc[mh_ * QM + mf][nh_ * QN + nf], 0, 0, 0); \
        }                                                                     \
    __builtin_amdgcn_s_setprio(0);                                            \
    __builtin_amdgcn_sched_barrier(0);                                        \
    __builtin_amdgcn_s_barrier();                                             \
} while (0)

template<int MODE>
__global__ __launch_bounds__(512, 1)
void gemm8(const short* __restrict__ Ah_g, const short* __restrict__ Al_g,
           const short* __restrict__ Bh_g, const short* __restrict__ Bl_g,
           const float* __restrict__ bias, uint32_t* __restrict__ O_hl,
           const float* __restrict__ w2, float* __restrict__ partials,
           int chunk_off)
{
    constexpr int BM = MODE ? 128 : 256;
    constexpr int BN = MODE ? 384 : 256;
    constexpr int QM = MODE ? 2 : 4;          // M frags per quadrant
    constexpr int QN = MODE ? 3 : 2;          // N frags per quadrant
    constexpr int MFR = 2 * QM, NFR = 2 * QN;
    constexpr int BREG  = BM * 128;           // B region byte offset
    constexpr int BUFSZ = (BM + BN) * 128;    // 64 KB per buf
    constexpr int US0[4] = { 0, BM / 2, 0, BN / 2 };      // unit start row
    constexpr int UL_[4] = { BM / 128, BM / 128, BN / 128, BN / 128 };
    extern __shared__ __align__(16) char lds[];

    const int t = threadIdx.x;
    const int w = t >> 6, lane = t & 63;
    const int lr = lane & 15, lh = lane >> 4;
    const int wm = w >> 2, wn = w & 3;        // 2 x 4 wave grid

    const int gx = gridDim.x, nwg = gx * gridDim.y;
    int bidx = blockIdx.y * gx + blockIdx.x;
    int wid = (bidx & 7) * (nwg >> 3) + (bidx >> 3);
    const int bx = wid % gx, by = wid / gx;
    const int row0 = by * BM, col0 = bx * BN;

    const short* APh = Ah_g + (size_t)row0 * KDIM;
    const short* APl = Al_g + (size_t)row0 * KDIM;
    const short* BPh = Bh_g + (size_t)col0 * KDIM;
    const short* BPl = Bl_g + (size_t)col0 * KDIM;

    // stage precompute: identity storage rows; source column pre-swizzled
    // (chunk c holds global k-chunk c ^ (row&7)); LDS dest stays linear.
    size_t goff[4][3];
    int    ldso[4][3];
#pragma unroll
    for (int u = 0; u < 4; ++u)
#pragma unroll
        for (int j = 0; j < 3; ++j) {
            if (j >= UL_[u]) continue;
            int p  = j * 512 + t;
            int sr = US0[u] + (p >> 3);       // storage row (= tile row)
            int c  = p & 7;                   // 16B chunk slot in 128B row
            goff[u][j] = (size_t)sr * KDIM + ((c ^ (sr & 7)) << 3);
            ldso[u][j] = (u < 2 ? 0 : BREG) + US0[u] * 128 + (j * 512 + (t & ~63)) * 16;
        }

    f32x4 acc[MFR][NFR] = {};
    short8v av[2][QM][2];                     // register-resident A halves
    short8v bv[2][QN][2];                     // register-resident B halves

    // prologue: t0 {A0,B0,A1,B1} + t1 {A0,B0}; vmcnt(4) -> t0 landed
    STAGE(0, 0); STAGE(2, 0); STAGE(1, 0); STAGE(3, 0);
    STAGE(0, 1); STAGE(2, 1);
    VM4;
    __builtin_amdgcn_s_barrier();

    for (int i = 0; i < NTILE / 2; ++i) {
        const int  T1 = 2 * i + 1, T2 = 2 * i + 2, T3 = 2 * i + 3;
        const bool nl = (i < NTILE / 2 - 1);
        PHASE(0, (void)0,            STAGE(1, T1));
        PHASE(1, (void)0,            STAGE(3, T1));
        PHASE(2, (void)0,            if (nl) STAGE(0, T2));
        PHASE(3, if (nl) VM4; else VM0, if (nl) STAGE(2, T2));
        PHASE(4, (void)0,            if (nl) STAGE(1, T2));
        PHASE(5, (void)0,            if (nl) STAGE(3, T2));
        PHASE(6, (void)0,            if (nl) STAGE(0, T3));
        PHASE(7, VM4,                if (nl) STAGE(2, T3));
    }

    if (MODE == 0) {
#pragma unroll
        for (int im = 0; im < MFR; ++im)
#pragma unroll
            for (int in = 0; in < NFR; ++in) {
                // im = mh*QM+mf -> row = mh*128 + wm*64 + mf*16 (QM=4)
                // in = nh*QN+nf -> col = nh*128 + wn*32 + nf*16 (QN=2)
                int n = col0 + (in >> 1) * 128 + wn * 32 + (in & 1) * 16 + lr;
                float bvs = bias[n];
#pragma unroll
                for (int q = 0; q < 4; ++q) {
                    int m = row0 + (im >> 2) * 128 + wm * 64 + (im & 3) * 16 + lh * 4 + q;
                    float gv = gelu_erf(acc[im][in][q] + bvs);
                    short hi = f2bf(gv);
                    short lo = f2bf(gv - bf2f(hi));
                    O_hl[(size_t)m * 768 + n] =
                        (uint32_t)(uint16_t)hi | ((uint32_t)(uint16_t)lo << 16);
                }
            }
    } else {
        float rs[MFR][4] = {};
#pragma unroll
        for (int im = 0; im < MFR; ++im)
#pragma unroll
            for (int in = 0; in < NFR; ++in) {
                // in = nh*QN+nf (QN=3) -> col = nh*192 + wn*48 + nf*16
                int n = (in / 3) * 192 + wn * 48 + (in % 3) * 16 + lr;
                float bvs = bias[n], wv = w2[n];
#pragma unroll
                for (int q = 0; q < 4; ++q)
                    rs[im][q] += gelu_erf(acc[im][in][q] + bvs) * wv;
            }
#pragma unroll
        for (int im = 0; im < MFR; ++im)
#pragma unroll
            for (int q = 0; q < 4; ++q) {
                float vv = rs[im][q];
                vv += __shfl_xor(vv, 1); vv += __shfl_xor(vv, 2);
                vv += __shfl_xor(vv, 4); vv += __shfl_xor(vv, 8);
                if (lr == 0) {
                    // im = mh*QM+mf (QM=2) -> row = mh*64 + wm*32 + mf*16
                    int m = chunk_off + row0 + (im >> 1) * 64 + wm * 32 + (im & 1) * 16 + lh * 4 + q;
                    partials[(size_t)wn * 65536 + m] = vv;
                }
            }
    }
}

// ---------------------------------------------------------------------------
// f32 fallback GEMM for the small qa projection.
constexpr int BKF = 16;
__global__ __launch_bounds__(256)
void rowstats(const float* __restrict__ X, float2* __restrict__ st, int M)
{
    int wave = threadIdx.x >> 6, lane = threadIdx.x & 63;
    int row = blockIdx.x * 4 + wave;
    if (row >= M) return;
    const float4* xr = reinterpret_cast<const float4*>(X + (size_t)row * KDIM);
    float s = 0.f, ss = 0.f;
#pragma unroll
    for (int i = 0; i < 3; ++i) {
        float4 v = xr[lane + i * 64];
        s  += v.x + v.y + v.z + v.w;
        ss += v.x * v.x + v.y * v.y + v.z * v.z + v.w * v.w;
    }
    s = wave_sum(s); ss = wave_sum(ss);
    if (lane == 0) {
        float m = s * (1.0f / 768.0f);
        float var = ss * (1.0f / 768.0f) - m * m;
        float rstd = rsqrtf(var + 1e-5f);
        st[row] = make_float2(rstd, -m * rstd);
    }
}

template<int BM, int BN, int TM, int TN>
__global__ __launch_bounds__(256)
void gemm_fused(const float* __restrict__ X, const float2* __restrict__ st,
                const float* __restrict__ gw, const float* __restrict__ gb,
                const float* __restrict__ W, const float* __restrict__ bias,
                float* __restrict__ out, int M, int N)
{
    static_assert((BM / TM) * (BN / TN) == 256, "256 threads");
    __shared__ float As[BKF][BM];
    __shared__ float Bs[BKF][BN];
    const int t = threadIdx.x;
    constexpr int TXN = BN / TN;
    const int tx = t % TXN;
    const int ty = t / TXN;
    const int row0 = blockIdx.y * BM;
    const int col0 = blockIdx.x * BN;
    float acc[TM][TN] = {};
    constexpr int A_IT = BM * BKF / 4 / 256;
    constexpr int B_IT = BKF * BN / 4 / 256;
    for (int k0 = 0; k0 < KDIM; k0 += BKF) {
#pragma unroll
        for (int i = 0; i < A_IT; ++i) {
            int idx = t + i * 256;
            int r = idx >> 2;
            int c = (idx & 3) << 2;
            float4 xv = *reinterpret_cast<const float4*>(X + (size_t)(row0 + r) * KDIM + k0 + c);
            float2 s = st[row0 + r];
            float4 gv = *reinterpret_cast<const float4*>(gw + k0 + c);
            float4 bv = *reinterpret_cast<const float4*>(gb + k0 + c);
            As[c + 0][r] = fmaf(fmaf(xv.x, s.x, s.y), gv.x, bv.x);
            As[c + 1][r] = fmaf(fmaf(xv.y, s.x, s.y), gv.y, bv.y);
            As[c + 2][r] = fmaf(fmaf(xv.z, s.x, s.y), gv.z, bv.z);
            As[c + 3][r] = fmaf(fmaf(xv.w, s.x, s.y), gv.w, bv.w);
        }
#pragma unroll
        for (int i = 0; i < B_IT; ++i) {
            int idx = t + i * 256;
            int r = idx / (BN / 4);
            int c = (idx % (BN / 4)) << 2;
            *reinterpret_cast<float4*>(&Bs[r][c]) =
                *reinterpret_cast<const float4*>(W + (size_t)(k0 + r) * N + col0 + c);
        }
        __syncthreads();
#pragma unroll
        for (int kk = 0; kk < BKF; ++kk) {
            float a[TM], b[TN];
#pragma unroll
            for (int i = 0; i < TM; i += 4)
                *reinterpret_cast<float4*>(&a[i]) = *reinterpret_cast<const float4*>(&As[kk][ty * TM + i]);
#pragma unroll
            for (int j = 0; j < TN; j += 4)
                *reinterpret_cast<float4*>(&b[j]) = *reinterpret_cast<const float4*>(&Bs[kk][tx * TN + j]);
#pragma unroll
            for (int i = 0; i < TM; ++i)
#pragma unroll
                for (int j = 0; j < TN; ++j)
                    acc[i][j] = fmaf(a[i], b[j], acc[i][j]);
        }
        __syncthreads();
    }
#pragma unroll
    for (int i = 0; i < TM; ++i) {
        size_t row = row0 + ty * TM + i;
#pragma unroll
        for (int j = 0; j < TN; j += 4) {
            int col = col0 + tx * TN + j;
            float4 o;
            o.x = gelu_erf(acc[i][j + 0] + bias[col + 0]);
            o.y = gelu_erf(acc[i][j + 1] + bias[col + 1]);
            o.z = gelu_erf(acc[i][j + 2] + bias[col + 2]);
            o.w = gelu_erf(acc[i][j + 3] + bias[col + 3]);
            *reinterpret_cast<float4*>(out + row * N + col) = o;
        }
    }
}

// ---------------------------------------------------------------------------
// head: logits = sum(4 partials)+b2 -> softmax -> smooth -> softmax -> decode.
__global__ __launch_bounds__(64)
void head_kernel(const float* __restrict__ partials, const float* __restrict__ b2,
                 const float* __restrict__ sigma_p, float* __restrict__ out)
{
    int b = blockIdx.x, lane = threadIdx.x;
    __shared__ float ok[36];
    __shared__ float kg[32];
    __shared__ int sel[2];

    if (lane < 36) ok[lane] = 0.f;
    __syncthreads();

    float x = -3.4e38f;
    if (lane < 32) {
        int row = b * 32 + lane;
        x = b2[0];
#pragma unroll
        for (int p = 0; p < 4; ++p) x += partials[(size_t)p * 65536 + row];
    }
    float mx = wave_max(x);
    float e = (lane < 32) ? expf(x - mx) : 0.f;
    float sum = wave_sum(e);
    float ori = e / sum;
    if (lane < 32) {
        out[OFF_ORI + b * 32 + lane] = ori;
        ok[lane + 2] = ori;
    }
    __syncthreads();

    float sg = sigma_p[0];
    float kern[5]; float ks = 0.f;
#pragma unroll
    for (int k = 0; k < 5; ++k) { float xx = (float)(k - 2) / sg; kern[k] = expf(-0.5f * xx * xx); ks += kern[k]; }
    float sm = -3.4e38f;
    if (lane < 32) {
        sm = 0.f;
#pragma unroll
        for (int k = 0; k < 5; ++k) sm += (kern[k] / ks) * ok[lane + k];
    }
    float mx2 = wave_max(sm);
    float e2 = (lane < 32) ? expf(sm - mx2) : 0.f;
    float sum2 = wave_sum(e2);
    float kgv = e2 / sum2;
    if (lane < 32) {
        out[OFF_KG + b * 32 + lane] = kgv;
        kg[lane] = kgv;
    }
    __syncthreads();

    if (lane == 0) {
        int pm = 0; float bv = kg[0];
        for (int i = 1; i < 32; ++i) if (kg[i] > bv) { bv = kg[i]; pm = i; }
        float cum[33]; cum[0] = 0.f;
        for (int i = 0; i < 32; ++i) cum[i + 1] = cum[i] + kg[i];
        float bs = -3.4e38f; int bst = 0, ben = 0;
        const int wsz[3] = {1, 3, 5};
        for (int wi = 0; wi < 3; ++wi) {
            int w = wsz[wi];
            for (int s = 0; s + w <= 32; ++s) {
                if (pm >= s && pm < s + w) {
                    float sc = cum[s + w] - cum[s];
                    if (sc > bs) { bs = sc; bst = s; ben = s + w; }
                }
            }
        }
        out[OFF_MI + b * 2 + 0] = (float)bst;
        out[OFF_MI + b * 2 + 1] = (float)ben;
        out[OFF_ST + b] = (float)bst / 31.0f;
        out[OFF_ET + b] = (float)ben / 31.0f;
        sel[0] = bst; sel[1] = ben;
    }
    __syncthreads();
    if (lane < 32)
        out[OFF_MASK + b * 32 + lane] = (lane >= sel[0] && lane <= sel[1]) ? 1.0f : 0.0f;
}

// ---------------------------------------------------------------------------
extern "C" void kernel_launch(void* const* d_in, const int* in_sizes, int n_in,
                              void* d_out, int out_size, void* d_ws, size_t ws_size,
                              hipStream_t stream)
{
    const float* v      = (const float*)d_in[0];
    const float* qa     = (const float*)d_in[1];
    const float* vp_lng = (const float*)d_in[2];
    const float* vp_lnb = (const float*)d_in[3];
    const float* vp_w   = (const float*)d_in[4];
    const float* vp_b   = (const float*)d_in[5];
    const float* qp_lng = (const float*)d_in[6];
    const float* qp_lnb = (const float*)d_in[7];
    const float* qp_w   = (const float*)d_in[8];
    const float* qp_b   = (const float*)d_in[9];
    const float* g_lng  = (const float*)d_in[10];
    const float* g_lnb  = (const float*)d_in[11];
    const float* g_w1   = (const float*)d_in[12];
    const float* g_b1   = (const float*)d_in[13];
    const float* g_w2   = (const float*)d_in[14];
    const float* g_b2   = (const float*)d_in[15];
    const float* sigma  = (const float*)d_in[16];
    float* outf = (float*)d_out;

    // workspace layout (~213 MB)
    short* A1h = (short*)d_ws;                           // CHUNK*768
    short* A1l = A1h + (size_t)CHUNK * KDIM;
    uint32_t* vp_hl = (uint32_t*)(A1l + (size_t)CHUNK * KDIM);   // CHUNK*768 u32
    short* B1h = (short*)(vp_hl + (size_t)CHUNK * KDIM); // 768*768
    short* B1l = B1h + 768 * KDIM;
    short* B2h = B1l + 768 * KDIM;                       // 384*768
    short* B2l = B2h + 384 * KDIM;
    float* qa_p = (float*)(B2l + 384 * KDIM);            // 2048*768
    float* st_qa = qa_p + 2048 * KDIM;                   // 2048*2
    float* partials = st_qa + 4096;                      // 4*65536

    // qa path (small, f32 vector GEMM)
    rowstats<<<512, 256, 0, stream>>>(qa, (float2*)st_qa, 2048);
    gemm_fused<64, 64, 4, 4><<<dim3(12, 32), 256, 0, stream>>>(
        qa, (const float2*)st_qa, qp_lng, qp_lnb, qp_w, qp_b, qa_p, 2048, 768);

    // weight transpose + split
    prep_W<<<dim3(24, 24), 256, 0, stream>>>(vp_w, B1h, B1l, 768);
    prep_W<<<dim3(12, 24), 256, 0, stream>>>(g_w1, B2h, B2l, 384);

    constexpr int LDS8 = 131072;   // 2 bufs x 64 KB (both modes)

    for (int c = 0; c < 65536; c += CHUNK) {
        prep_A1<<<CHUNK / 4, 256, 0, stream>>>(v + (size_t)c * KDIM, vp_lng, vp_lnb, A1h, A1l);
        // v_p = gelu(A1 @ vp_w^T + vp_b): 256x256 tile, grid (3,128)
        gemm8<0><<<dim3(3, CHUNK / 256), 512, LDS8, stream>>>(
            A1h, A1l, B1h, B1l, vp_b, vp_hl, nullptr, nullptr, 0);
        prep_A2<<<CHUNK / 4, 256, 0, stream>>>(vp_hl, qa_p, g_lng, g_lnb, A1h, A1l, c);
        // fused h@g_w1+gelu+dot(g_w2): 128x384 tile, grid (1,256)
        gemm8<1><<<dim3(1, CHUNK / 128), 512, LDS8, stream>>>(
            A1h, A1l, B2h, B2l, g_b1, nullptr, g_w2, partials, c);
    }

    head_kernel<<<2048, 64, 0, stream>>>(partials, g_b2, sigma, outf);
}

// Round 8
// 661.454 us; speedup vs baseline: 1.2836x; 1.0813x over previous
//
#include <hip/hip_runtime.h>
#include <math.h>
#include <stdint.h>

// ---------------------------------------------------------------------------
// GroundingModule — round 8: 8-phase split-bf16 GEMMs, unified 128x384 tile
// for BOTH gemms (grid 512 = 2 clean CU-rounds for MODE0; was 384 = 1.5).
// Gray-code quadrant order, register-resident operands (24/20 ds_read per
// K-tile), (row&7) chunk-XOR swizzle (verified 0 conflicts), counted vmcnt(4).
// Virtual K = 2304 (AhBh | AlBh | AhBl), 36 K-tiles of 64, 2 tiles/iter.
// ---------------------------------------------------------------------------

#define DEV __device__ __forceinline__

typedef __attribute__((ext_vector_type(8))) short short8v;   // 8 bf16
typedef __attribute__((ext_vector_type(4))) float f32x4;

constexpr int KDIM  = 768;
constexpr int CHUNK = 32768;
constexpr int NTILE = 36;          // virtual K tiles of 64

// output offsets (floats) in return order
constexpr int OFF_KG   = 0;
constexpr int OFF_MI   = 65536;
constexpr int OFF_ST   = 69632;
constexpr int OFF_ET   = 71680;
constexpr int OFF_MASK = 73728;
constexpr int OFF_ORI  = 139264;

DEV float gelu_erf(float x) { return 0.5f * x * (1.0f + erff(x * 0.70710678118654752f)); }
DEV float wave_sum(float v) { for (int o = 32; o; o >>= 1) v += __shfl_xor(v, o); return v; }
DEV float wave_max(float v) { for (int o = 32; o; o >>= 1) v = fmaxf(v, __shfl_xor(v, o)); return v; }

DEV short f2bf(float x) {                       // f32 -> bf16 (RNE)
    uint32_t u = __builtin_bit_cast(uint32_t, x);
    u = u + 0x7fffu + ((u >> 16) & 1u);
    return (short)(u >> 16);
}
DEV float bf2f(short b) {
    uint32_t u = ((uint32_t)(uint16_t)b) << 16;
    return __builtin_bit_cast(float, u);
}

DEV void gl_lds16(const void* g, void* l) {     // async 16B/lane global->LDS
    __builtin_amdgcn_global_load_lds(
        (const __attribute__((address_space(1))) uint32_t*)g,
        (__attribute__((address_space(3))) uint32_t*)l, 16, 0, 0);
}

// ---------------------------------------------------------------------------
// prep_A1: fused rowstats + LN-affine + hi/lo split.  One wave per row.
__global__ __launch_bounds__(256)
void prep_A1(const float* __restrict__ X, const float* __restrict__ g,
             const float* __restrict__ b, short* __restrict__ Ah, short* __restrict__ Al)
{
    int w = threadIdx.x >> 6, lane = threadIdx.x & 63;
    int row = blockIdx.x * 4 + w;
    const float4* xr = (const float4*)(X + (size_t)row * KDIM);
    float4 xv[3]; float s = 0.f, ss = 0.f;
#pragma unroll
    for (int i = 0; i < 3; ++i) {
        xv[i] = xr[lane + i * 64];
        s  += xv[i].x + xv[i].y + xv[i].z + xv[i].w;
        ss += xv[i].x * xv[i].x + xv[i].y * xv[i].y + xv[i].z * xv[i].z + xv[i].w * xv[i].w;
    }
    s = wave_sum(s); ss = wave_sum(ss);
    float m = s * (1.f / 768.f), var = ss * (1.f / 768.f) - m * m;
    float sa = rsqrtf(var + 1e-5f), ta = -m * sa;
#pragma unroll
    for (int i = 0; i < 3; ++i) {
        int idx = lane + i * 64;
        float4 gv = ((const float4*)g)[idx];
        float4 bv = ((const float4*)b)[idx];
        float a0 = fmaf(fmaf(xv[i].x, sa, ta), gv.x, bv.x);
        float a1 = fmaf(fmaf(xv[i].y, sa, ta), gv.y, bv.y);
        float a2 = fmaf(fmaf(xv[i].z, sa, ta), gv.z, bv.z);
        float a3 = fmaf(fmaf(xv[i].w, sa, ta), gv.w, bv.w);
        short h0 = f2bf(a0), h1 = f2bf(a1), h2 = f2bf(a2), h3 = f2bf(a3);
        ushort4 hv, lv;
        hv.x = (uint16_t)h0; hv.y = (uint16_t)h1; hv.z = (uint16_t)h2; hv.w = (uint16_t)h3;
        lv.x = (uint16_t)f2bf(a0 - bf2f(h0)); lv.y = (uint16_t)f2bf(a1 - bf2f(h1));
        lv.z = (uint16_t)f2bf(a2 - bf2f(h2)); lv.w = (uint16_t)f2bf(a3 - bf2f(h3));
        ((ushort4*)(Ah + (size_t)row * KDIM))[idx] = hv;
        ((ushort4*)(Al + (size_t)row * KDIM))[idx] = lv;
    }
}

// ---------------------------------------------------------------------------
// prep_A2: gate(tanh dot) + LN2 stats + affine + split. vp packed (hi|lo<<16).
__global__ __launch_bounds__(256)
void prep_A2(const uint32_t* __restrict__ vp_hl, const float* __restrict__ qa_p,
             const float* __restrict__ g, const float* __restrict__ b,
             short* __restrict__ Ah, short* __restrict__ Al, int chunk_off)
{
    int w = threadIdx.x >> 6, lane = threadIdx.x & 63;
    int row = blockIdx.x * 4 + w;
    int bidx = (chunk_off + row) >> 5;
    const uint4*  hr = (const uint4*)(vp_hl + (size_t)row * KDIM);
    const float4* qr = (const float4*)(qa_p + (size_t)bidx * KDIM);
    float vp[12]; float s = 0.f, ss = 0.f, d = 0.f;
#pragma unroll
    for (int i = 0; i < 3; ++i) {
        uint4  uv = hr[lane + i * 64];
        float4 qv = qr[lane + i * 64];
        float v0 = bf2f((short)(uv.x & 0xffff)) + bf2f((short)(uv.x >> 16));
        float v1 = bf2f((short)(uv.y & 0xffff)) + bf2f((short)(uv.y >> 16));
        float v2 = bf2f((short)(uv.z & 0xffff)) + bf2f((short)(uv.z >> 16));
        float v3 = bf2f((short)(uv.w & 0xffff)) + bf2f((short)(uv.w >> 16));
        vp[i * 4 + 0] = v0; vp[i * 4 + 1] = v1; vp[i * 4 + 2] = v2; vp[i * 4 + 3] = v3;
        s  += v0 + v1 + v2 + v3;
        ss += v0 * v0 + v1 * v1 + v2 * v2 + v3 * v3;
        d  += v0 * qv.x + v1 * qv.y + v2 * qv.z + v3 * qv.w;
    }
    s = wave_sum(s); ss = wave_sum(ss); d = wave_sum(d);
    float gate = tanhf(d);
    float m = s * (1.f / 768.f), var = ss * (1.f / 768.f) - m * m;
    float den = rsqrtf(gate * gate * var + 1e-5f);
    float sa = gate * den, ta = -gate * m * den;
#pragma unroll
    for (int i = 0; i < 3; ++i) {
        int idx = lane + i * 64;
        float4 gv = ((const float4*)g)[idx];
        float4 bv = ((const float4*)b)[idx];
        float a0 = fmaf(fmaf(vp[i * 4 + 0], sa, ta), gv.x, bv.x);
        float a1 = fmaf(fmaf(vp[i * 4 + 1], sa, ta), gv.y, bv.y);
        float a2 = fmaf(fmaf(vp[i * 4 + 2], sa, ta), gv.z, bv.z);
        float a3 = fmaf(fmaf(vp[i * 4 + 3], sa, ta), gv.w, bv.w);
        short h0 = f2bf(a0), h1 = f2bf(a1), h2 = f2bf(a2), h3 = f2bf(a3);
        ushort4 hv, lv;
        hv.x = (uint16_t)h0; hv.y = (uint16_t)h1; hv.z = (uint16_t)h2; hv.w = (uint16_t)h3;
        lv.x = (uint16_t)f2bf(a0 - bf2f(h0)); lv.y = (uint16_t)f2bf(a1 - bf2f(h1));
        lv.z = (uint16_t)f2bf(a2 - bf2f(h2)); lv.w = (uint16_t)f2bf(a3 - bf2f(h3));
        ((ushort4*)(Ah + (size_t)row * KDIM))[idx] = hv;
        ((ushort4*)(Al + (size_t)row * KDIM))[idx] = lv;
    }
}

// ---------------------------------------------------------------------------
// prep_W: transpose + hi/lo split.  W[k][n] f32 -> Bh/Bl[n][k] bf16.
__global__ __launch_bounds__(256)
void prep_W(const float* __restrict__ W, short* __restrict__ Bh, short* __restrict__ Bl, int N)
{
    __shared__ float t[32][33];
    int bx = blockIdx.x, by = blockIdx.y;
    int lx = threadIdx.x & 31, ly = threadIdx.x >> 5;
#pragma unroll
    for (int r = 0; r < 32; r += 8)
        t[ly + r][lx] = W[(size_t)(by * 32 + ly + r) * N + bx * 32 + lx];
    __syncthreads();
#pragma unroll
    for (int r = 0; r < 32; r += 8) {
        float v = t[lx][ly + r];
        short hi = f2bf(v);
        size_t o = (size_t)(bx * 32 + ly + r) * KDIM + by * 32 + lx;
        Bh[o] = hi;
        Bl[o] = f2bf(v - bf2f(hi));
    }
}

// ---------------------------------------------------------------------------
// 8-phase split-bf16 MFMA GEMM.  512 thr / 8 waves (2M x 4N), BM=128 BN=384.
// Gray-code quadrant order: P%4 = 0:(mh0,nh0) read A0+B0 | 1:(mh1,nh0) read A1
// | 2:(mh0,nh1) read B1 | 3:(mh1,nh1) no reads.  Operands register-resident.
// LDS row = 128B, chunk c ^= (row&7) swizzle (32-bank spread, verified 0-confl).
//   MODE 0: out = gelu(.) packed (hi | lo<<16) u32 into 768-wide vp_hl.
//   MODE 1: partial row-dot with w2 -> partials[wn][row].
#define VM4  asm volatile("s_waitcnt vmcnt(4)" ::: "memory")
#define VM0  asm volatile("s_waitcnt vmcnt(0)" ::: "memory")

#define STAGE(U, TT) do {                                                     \
    const int sT_ = (TT);                                                     \
    const int seg_ = (sT_ >= 24) ? 2 : ((sT_ >= 12) ? 1 : 0);                 \
    const int kp_ = (sT_ - seg_ * 12) << 6;                                   \
    const short* sb_ = ((U) < 2) ? ((seg_ == 1) ? APl : APh)                  \
                                 : ((seg_ == 2) ? BPl : BPh);                 \
    char* db_ = lds + ((sT_) & 1) * BUFSZ;                                    \
    _Pragma("unroll")                                                         \
    for (int j_ = 0; j_ < UL_[(U)]; ++j_)                                     \
        gl_lds16(sb_ + goff[(U)][j_] + kp_, db_ + ldso[(U)][j_]);             \
} while (0)

#define PHASE(P, VMSTMT, ...) do {                                            \
    constexpr int mh_ = (P) & 1, nh_ = ((P) >> 1) & 1;                        \
    const char* Ab_ = lds + (((P) >> 2) & 1) * BUFSZ;                         \
    const char* Bb_ = Ab_ + BREG;                                             \
    if ((P) % 4 == 0) {                                                       \
        _Pragma("unroll")                                                     \
        for (int nf = 0; nf < QN; ++nf) {                                     \
            int sB = wn * (BN / 8) + nf * 16 + lr;                            \
            int so = (lh ^ (sB & 7)) << 4;                                    \
            bv[0][nf][0] = *(const short8v*)(Bb_ + sB * 128 + so);            \
            bv[0][nf][1] = *(const short8v*)(Bb_ + sB * 128 + (so ^ 64));     \
        }                                                                     \
        _Pragma("unroll")                                                     \
        for (int mf = 0; mf < QM; ++mf) {                                     \
            int sA = wm * (BM / 4) + mf * 16 + lr;                            \
            int so = (lh ^ (sA & 7)) << 4;                                    \
            av[0][mf][0] = *(const short8v*)(Ab_ + sA * 128 + so);            \
            av[0][mf][1] = *(const short8v*)(Ab_ + sA * 128 + (so ^ 64));     \
        }                                                                     \
    } else if ((P) % 4 == 1) {                                                \
        _Pragma("unroll")                                                     \
        for (int mf = 0; mf < QM; ++mf) {                                     \
            int sA = (BM / 2) + wm * (BM / 4) + mf * 16 + lr;                 \
            int so = (lh ^ (sA & 7)) << 4;                                    \
            av[1][mf][0] = *(const short8v*)(Ab_ + sA * 128 + so);            \
            av[1][mf][1] = *(const short8v*)(Ab_ + sA * 128 + (so ^ 64));     \
        }                                                                     \
    } else if ((P) % 4 == 2) {                                                \
        _Pragma("unroll")                                                     \
        for (int nf = 0; nf < QN; ++nf) {                                     \
            int sB = (BN / 2) + wn * (BN / 8) + nf * 16 + lr;                 \
            int so = (lh ^ (sB & 7)) << 4;                                    \
            bv[1][nf][0] = *(const short8v*)(Bb_ + sB * 128 + so);            \
            bv[1][nf][1] = *(const short8v*)(Bb_ + sB * 128 + (so ^ 64));     \
        }                                                                     \
    }                                                                         \
    __VA_ARGS__;                                                              \
    VMSTMT;                                                                   \
    __builtin_amdgcn_sched_barrier(0);                                        \
    __builtin_amdgcn_s_barrier();                                             \
    asm volatile("s_waitcnt lgkmcnt(0)" ::: "memory");                        \
    __builtin_amdgcn_sched_barrier(0);                                        \
    __builtin_amdgcn_s_setprio(1);                                            \
    _Pragma("unroll")                                                         \
    for (int mf = 0; mf < QM; ++mf)                                           \
        _Pragma("unroll")                                                     \
        for (int nf = 0; nf < QN; ++nf) {                                     \
            acc[mh_ * QM + mf][nh_ * QN + nf] =                               \
                __builtin_amdgcn_mfma_f32_16x16x32_bf16(av[mh_][mf][0],       \
                    bv[nh_][nf][0], acc[mh_ * QM + mf][nh_ * QN + nf], 0, 0, 0); \
            acc[mh_ * QM + mf][nh_ * QN + nf] =                               \
                __builtin_amdgcn_mfma_f32_16x16x32_bf16(av[mh_][mf][1],       \
                    bv[nh_][nf][1], acc[mh_ * QM + mf][nh_ * QN + nf], 0, 0, 0); \
        }                                                                     \
    __builtin_amdgcn_s_setprio(0);                                            \
    __builtin_amdgcn_sched_barrier(0);                                        \
    __builtin_amdgcn_s_barrier();                                             \
} while (0)

template<int MODE>
__global__ __launch_bounds__(512, 1)
void gemm8(const short* __restrict__ Ah_g, const short* __restrict__ Al_g,
           const short* __restrict__ Bh_g, const short* __restrict__ Bl_g,
           const float* __restrict__ bias, uint32_t* __restrict__ O_hl,
           const float* __restrict__ w2, float* __restrict__ partials,
           int chunk_off)
{
    constexpr int BM = 128, BN = 384;
    constexpr int QM = 2;                     // M frags per quadrant
    constexpr int QN = 3;                     // N frags per quadrant
    constexpr int MFR = 2 * QM, NFR = 2 * QN;
    constexpr int BREG  = BM * 128;           // B region byte offset (16 KB)
    constexpr int BUFSZ = (BM + BN) * 128;    // 64 KB per buf
    constexpr int US0[4] = { 0, BM / 2, 0, BN / 2 };      // unit start row
    constexpr int UL_[4] = { BM / 128, BM / 128, BN / 128, BN / 128 };  // 1,1,3,3
    extern __shared__ __align__(16) char lds[];

    const int t = threadIdx.x;
    const int w = t >> 6, lane = t & 63;
    const int lr = lane & 15, lh = lane >> 4;
    const int wm = w >> 2, wn = w & 3;        // 2 x 4 wave grid

    const int gx = gridDim.x, nwg = gx * gridDim.y;
    int bidx = blockIdx.y * gx + blockIdx.x;
    int wid = (bidx & 7) * (nwg >> 3) + (bidx >> 3);
    const int bx = wid % gx, by = wid / gx;
    const int row0 = by * BM, col0 = bx * BN;

    const short* APh = Ah_g + (size_t)row0 * KDIM;
    const short* APl = Al_g + (size_t)row0 * KDIM;
    const short* BPh = Bh_g + (size_t)col0 * KDIM;
    const short* BPl = Bl_g + (size_t)col0 * KDIM;

    // stage precompute: identity storage rows; source column pre-swizzled
    // (chunk c holds global k-chunk c ^ (row&7)); LDS dest stays linear.
    size_t goff[4][3];
    int    ldso[4][3];
#pragma unroll
    for (int u = 0; u < 4; ++u)
#pragma unroll
        for (int j = 0; j < 3; ++j) {
            if (j >= UL_[u]) continue;
            int p  = j * 512 + t;
            int sr = US0[u] + (p >> 3);       // storage row (= tile row)
            int c  = p & 7;                   // 16B chunk slot in 128B row
            goff[u][j] = (size_t)sr * KDIM + ((c ^ (sr & 7)) << 3);
            ldso[u][j] = (u < 2 ? 0 : BREG) + US0[u] * 128 + (j * 512 + (t & ~63)) * 16;
        }

    f32x4 acc[MFR][NFR] = {};
    short8v av[2][QM][2];                     // register-resident A halves
    short8v bv[2][QN][2];                     // register-resident B halves

    // prologue: T0 {A0,B0,A1,B1} + T1 {A0,B0}; VM4 -> all of T0 landed
    STAGE(0, 0); STAGE(2, 0); STAGE(1, 0); STAGE(3, 0);
    STAGE(0, 1); STAGE(2, 1);
    VM4;
    __builtin_amdgcn_s_barrier();

    for (int i = 0; i < NTILE / 2; ++i) {
        const int  T1 = 2 * i + 1, T2 = 2 * i + 2, T3 = 2 * i + 3;
        const bool nl = (i < NTILE / 2 - 1);
        PHASE(0, (void)0,            STAGE(1, T1));
        PHASE(1, (void)0,            STAGE(3, T1));
        PHASE(2, (void)0,            if (nl) STAGE(0, T2));
        PHASE(3, if (nl) VM4; else VM0, if (nl) STAGE(2, T2));
        PHASE(4, (void)0,            if (nl) STAGE(1, T2));
        PHASE(5, (void)0,            if (nl) STAGE(3, T2));
        PHASE(6, (void)0,            if (nl) STAGE(0, T3));
        PHASE(7, VM4,                if (nl) STAGE(2, T3));
    }

    if (MODE == 0) {
#pragma unroll
        for (int im = 0; im < MFR; ++im)
#pragma unroll
            for (int in = 0; in < NFR; ++in) {
                // in = nh*QN+nf (QN=3) -> col = nh*192 + wn*48 + nf*16
                int n = col0 + (in / 3) * 192 + wn * 48 + (in % 3) * 16 + lr;
                float bvs = bias[n];
#pragma unroll
                for (int q = 0; q < 4; ++q) {
                    // im = mh*QM+mf (QM=2) -> row = mh*64 + wm*32 + mf*16
                    int m = row0 + (im >> 1) * 64 + wm * 32 + (im & 1) * 16 + lh * 4 + q;
                    float gv = gelu_erf(acc[im][in][q] + bvs);
                    short hi = f2bf(gv);
                    short lo = f2bf(gv - bf2f(hi));
                    O_hl[(size_t)m * 768 + n] =
                        (uint32_t)(uint16_t)hi | ((uint32_t)(uint16_t)lo << 16);
                }
            }
    } else {
        float rs[MFR][4] = {};
#pragma unroll
        for (int im = 0; im < MFR; ++im)
#pragma unroll
            for (int in = 0; in < NFR; ++in) {
                int n = (in / 3) * 192 + wn * 48 + (in % 3) * 16 + lr;
                float bvs = bias[n], wv = w2[n];
#pragma unroll
                for (int q = 0; q < 4; ++q)
                    rs[im][q] += gelu_erf(acc[im][in][q] + bvs) * wv;
            }
#pragma unroll
        for (int im = 0; im < MFR; ++im)
#pragma unroll
            for (int q = 0; q < 4; ++q) {
                float vv = rs[im][q];
                vv += __shfl_xor(vv, 1); vv += __shfl_xor(vv, 2);
                vv += __shfl_xor(vv, 4); vv += __shfl_xor(vv, 8);
                if (lr == 0) {
                    int m = chunk_off + row0 + (im >> 1) * 64 + wm * 32 + (im & 1) * 16 + lh * 4 + q;
                    partials[(size_t)wn * 65536 + m] = vv;
                }
            }
    }
}

// ---------------------------------------------------------------------------
// f32 fallback GEMM for the small qa projection.
constexpr int BKF = 16;
__global__ __launch_bounds__(256)
void rowstats(const float* __restrict__ X, float2* __restrict__ st, int M)
{
    int wave = threadIdx.x >> 6, lane = threadIdx.x & 63;
    int row = blockIdx.x * 4 + wave;
    if (row >= M) return;
    const float4* xr = reinterpret_cast<const float4*>(X + (size_t)row * KDIM);
    float s = 0.f, ss = 0.f;
#pragma unroll
    for (int i = 0; i < 3; ++i) {
        float4 v = xr[lane + i * 64];
        s  += v.x + v.y + v.z + v.w;
        ss += v.x * v.x + v.y * v.y + v.z * v.z + v.w * v.w;
    }
    s = wave_sum(s); ss = wave_sum(ss);
    if (lane == 0) {
        float m = s * (1.0f / 768.0f);
        float var = ss * (1.0f / 768.0f) - m * m;
        float rstd = rsqrtf(var + 1e-5f);
        st[row] = make_float2(rstd, -m * rstd);
    }
}

template<int BM, int BN, int TM, int TN>
__global__ __launch_bounds__(256)
void gemm_fused(const float* __restrict__ X, const float2* __restrict__ st,
                const float* __restrict__ gw, const float* __restrict__ gb,
                const float* __restrict__ W, const float* __restrict__ bias,
                float* __restrict__ out, int M, int N)
{
    static_assert((BM / TM) * (BN / TN) == 256, "256 threads");
    __shared__ float As[BKF][BM];
    __shared__ float Bs[BKF][BN];
    const int t = threadIdx.x;
    constexpr int TXN = BN / TN;
    const int tx = t % TXN;
    const int ty = t / TXN;
    const int row0 = blockIdx.y * BM;
    const int col0 = blockIdx.x * BN;
    float acc[TM][TN] = {};
    constexpr int A_IT = BM * BKF / 4 / 256;
    constexpr int B_IT = BKF * BN / 4 / 256;
    for (int k0 = 0; k0 < KDIM; k0 += BKF) {
#pragma unroll
        for (int i = 0; i < A_IT; ++i) {
            int idx = t + i * 256;
            int r = idx >> 2;
            int c = (idx & 3) << 2;
            float4 xv = *reinterpret_cast<const float4*>(X + (size_t)(row0 + r) * KDIM + k0 + c);
            float2 s = st[row0 + r];
            float4 gv = *reinterpret_cast<const float4*>(gw + k0 + c);
            float4 bv = *reinterpret_cast<const float4*>(gb + k0 + c);
            As[c + 0][r] = fmaf(fmaf(xv.x, s.x, s.y), gv.x, bv.x);
            As[c + 1][r] = fmaf(fmaf(xv.y, s.x, s.y), gv.y, bv.y);
            As[c + 2][r] = fmaf(fmaf(xv.z, s.x, s.y), gv.z, bv.z);
            As[c + 3][r] = fmaf(fmaf(xv.w, s.x, s.y), gv.w, bv.w);
        }
#pragma unroll
        for (int i = 0; i < B_IT; ++i) {
            int idx = t + i * 256;
            int r = idx / (BN / 4);
            int c = (idx % (BN / 4)) << 2;
            *reinterpret_cast<float4*>(&Bs[r][c]) =
                *reinterpret_cast<const float4*>(W + (size_t)(k0 + r) * N + col0 + c);
        }
        __syncthreads();
#pragma unroll
        for (int kk = 0; kk < BKF; ++kk) {
            float a[TM], b[TN];
#pragma unroll
            for (int i = 0; i < TM; i += 4)
                *reinterpret_cast<float4*>(&a[i]) = *reinterpret_cast<const float4*>(&As[kk][ty * TM + i]);
#pragma unroll
            for (int j = 0; j < TN; j += 4)
                *reinterpret_cast<float4*>(&b[j]) = *reinterpret_cast<const float4*>(&Bs[kk][tx * TN + j]);
#pragma unroll
            for (int i = 0; i < TM; ++i)
#pragma unroll
                for (int j = 0; j < TN; ++j)
                    acc[i][j] = fmaf(a[i], b[j], acc[i][j]);
        }
        __syncthreads();
    }
#pragma unroll
    for (int i = 0; i < TM; ++i) {
        size_t row = row0 + ty * TM + i;
#pragma unroll
        for (int j = 0; j < TN; j += 4) {
            int col = col0 + tx * TN + j;
            float4 o;
            o.x = gelu_erf(acc[i][j + 0] + bias[col + 0]);
            o.y = gelu_erf(acc[i][j + 1] + bias[col + 1]);
            o.z = gelu_erf(acc[i][j + 2] + bias[col + 2]);
            o.w = gelu_erf(acc[i][j + 3] + bias[col + 3]);
            *reinterpret_cast<float4*>(out + row * N + col) = o;
        }
    }
}

// ---------------------------------------------------------------------------
// head: logits = sum(4 partials)+b2 -> softmax -> smooth -> softmax -> decode.
__global__ __launch_bounds__(64)
void head_kernel(const float* __restrict__ partials, const float* __restrict__ b2,
                 const float* __restrict__ sigma_p, float* __restrict__ out)
{
    int b = blockIdx.x, lane = threadIdx.x;
    __shared__ float ok[36];
    __shared__ float kg[32];
    __shared__ int sel[2];

    if (lane < 36) ok[lane] = 0.f;
    __syncthreads();

    float x = -3.4e38f;
    if (lane < 32) {
        int row = b * 32 + lane;
        x = b2[0];
#pragma unroll
        for (int p = 0; p < 4; ++p) x += partials[(size_t)p * 65536 + row];
    }
    float mx = wave_max(x);
    float e = (lane < 32) ? expf(x - mx) : 0.f;
    float sum = wave_sum(e);
    float ori = e / sum;
    if (lane < 32) {
        out[OFF_ORI + b * 32 + lane] = ori;
        ok[lane + 2] = ori;
    }
    __syncthreads();

    float sg = sigma_p[0];
    float kern[5]; float ks = 0.f;
#pragma unroll
    for (int k = 0; k < 5; ++k) { float xx = (float)(k - 2) / sg; kern[k] = expf(-0.5f * xx * xx); ks += kern[k]; }
    float sm = -3.4e38f;
    if (lane < 32) {
        sm = 0.f;
#pragma unroll
        for (int k = 0; k < 5; ++k) sm += (kern[k] / ks) * ok[lane + k];
    }
    float mx2 = wave_max(sm);
    float e2 = (lane < 32) ? expf(sm - mx2) : 0.f;
    float sum2 = wave_sum(e2);
    float kgv = e2 / sum2;
    if (lane < 32) {
        out[OFF_KG + b * 32 + lane] = kgv;
        kg[lane] = kgv;
    }
    __syncthreads();

    if (lane == 0) {
        int pm = 0; float bv = kg[0];
        for (int i = 1; i < 32; ++i) if (kg[i] > bv) { bv = kg[i]; pm = i; }
        float cum[33]; cum[0] = 0.f;
        for (int i = 0; i < 32; ++i) cum[i + 1] = cum[i] + kg[i];
        float bs = -3.4e38f; int bst = 0, ben = 0;
        const int wsz[3] = {1, 3, 5};
        for (int wi = 0; wi < 3; ++wi) {
            int w = wsz[wi];
            for (int s = 0; s + w <= 32; ++s) {
                if (pm >= s && pm < s + w) {
                    float sc = cum[s + w] - cum[s];
                    if (sc > bs) { bs = sc; bst = s; ben = s + w; }
                }
            }
        }
        out[OFF_MI + b * 2 + 0] = (float)bst;
        out[OFF_MI + b * 2 + 1] = (float)ben;
        out[OFF_ST + b] = (float)bst / 31.0f;
        out[OFF_ET + b] = (float)ben / 31.0f;
        sel[0] = bst; sel[1] = ben;
    }
    __syncthreads();
    if (lane < 32)
        out[OFF_MASK + b * 32 + lane] = (lane >= sel[0] && lane <= sel[1]) ? 1.0f : 0.0f;
}

// ---------------------------------------------------------------------------
extern "C" void kernel_launch(void* const* d_in, const int* in_sizes, int n_in,
                              void* d_out, int out_size, void* d_ws, size_t ws_size,
                              hipStream_t stream)
{
    const float* v      = (const float*)d_in[0];
    const float* qa     = (const float*)d_in[1];
    const float* vp_lng = (const float*)d_in[2];
    const float* vp_lnb = (const float*)d_in[3];
    const float* vp_w   = (const float*)d_in[4];
    const float* vp_b   = (const float*)d_in[5];
    const float* qp_lng = (const float*)d_in[6];
    const float* qp_lnb = (const float*)d_in[7];
    const float* qp_w   = (const float*)d_in[8];
    const float* qp_b   = (const float*)d_in[9];
    const float* g_lng  = (const float*)d_in[10];
    const float* g_lnb  = (const float*)d_in[11];
    const float* g_w1   = (const float*)d_in[12];
    const float* g_b1   = (const float*)d_in[13];
    const float* g_w2   = (const float*)d_in[14];
    const float* g_b2   = (const float*)d_in[15];
    const float* sigma  = (const float*)d_in[16];
    float* outf = (float*)d_out;

    // workspace layout (~213 MB)
    short* A1h = (short*)d_ws;                           // CHUNK*768
    short* A1l = A1h + (size_t)CHUNK * KDIM;
    uint32_t* vp_hl = (uint32_t*)(A1l + (size_t)CHUNK * KDIM);   // CHUNK*768 u32
    short* B1h = (short*)(vp_hl + (size_t)CHUNK * KDIM); // 768*768
    short* B1l = B1h + 768 * KDIM;
    short* B2h = B1l + 768 * KDIM;                       // 384*768
    short* B2l = B2h + 384 * KDIM;
    float* qa_p = (float*)(B2l + 384 * KDIM);            // 2048*768
    float* st_qa = qa_p + 2048 * KDIM;                   // 2048*2
    float* partials = st_qa + 4096;                      // 4*65536

    // qa path (small, f32 vector GEMM)
    rowstats<<<512, 256, 0, stream>>>(qa, (float2*)st_qa, 2048);
    gemm_fused<64, 64, 4, 4><<<dim3(12, 32), 256, 0, stream>>>(
        qa, (const float2*)st_qa, qp_lng, qp_lnb, qp_w, qp_b, qa_p, 2048, 768);

    // weight transpose + split
    prep_W<<<dim3(24, 24), 256, 0, stream>>>(vp_w, B1h, B1l, 768);
    prep_W<<<dim3(12, 24), 256, 0, stream>>>(g_w1, B2h, B2l, 384);

    constexpr int LDS8 = 131072;   // 2 bufs x 64 KB (both modes)

    for (int c = 0; c < 65536; c += CHUNK) {
        prep_A1<<<CHUNK / 4, 256, 0, stream>>>(v + (size_t)c * KDIM, vp_lng, vp_lnb, A1h, A1l);
        // v_p = gelu(A1 @ vp_w^T + vp_b): 128x384 tile, grid (2,256)=512 blocks
        gemm8<0><<<dim3(2, CHUNK / 128), 512, LDS8, stream>>>(
            A1h, A1l, B1h, B1l, vp_b, vp_hl, nullptr, nullptr, 0);
        prep_A2<<<CHUNK / 4, 256, 0, stream>>>(vp_hl, qa_p, g_lng, g_lnb, A1h, A1l, c);
        // fused h@g_w1+gelu+dot(g_w2): 128x384 tile, grid (1,256)=256 blocks
        gemm8<1><<<dim3(1, CHUNK / 128), 512, LDS8, stream>>>(
            A1h, A1l, B2h, B2l, g_b1, nullptr, g_w2, partials, c);
    }

    head_kernel<<<2048, 64, 0, stream>>>(partials, g_b2, sigma, outf);
}

// Round 9
// 649.332 us; speedup vs baseline: 1.3075x; 1.0187x over previous
//
#include <hip/hip_runtime.h>
#include <math.h>
#include <stdint.h>

// ---------------------------------------------------------------------------
// GroundingModule — round 9: physical-K split-bf16 GEMM, 3 term-phases per
// k-tile (BK=32): stage {Ah,Al,Bh,Bl} ONCE per k-tile (no redundant staging),
// 24 independent MFMA per phase, register-resident operands (bh reused in P2).
// Counted vmcnt VM(4)/VM(6)/VM(4) guards next phase's groups; never drains.
// 64B LDS rows + slot-XOR swizzle (2-way, free).  BM=128 BN=384, 8 waves.
// ---------------------------------------------------------------------------

#define DEV __device__ __forceinline__

typedef __attribute__((ext_vector_type(8))) short short8v;   // 8 bf16
typedef __attribute__((ext_vector_type(4))) float f32x4;

constexpr int KDIM  = 768;
constexpr int CHUNK = 32768;

// output offsets (floats) in return order
constexpr int OFF_KG   = 0;
constexpr int OFF_MI   = 65536;
constexpr int OFF_ST   = 69632;
constexpr int OFF_ET   = 71680;
constexpr int OFF_MASK = 73728;
constexpr int OFF_ORI  = 139264;

DEV float gelu_erf(float x) { return 0.5f * x * (1.0f + erff(x * 0.70710678118654752f)); }
DEV float wave_sum(float v) { for (int o = 32; o; o >>= 1) v += __shfl_xor(v, o); return v; }
DEV float wave_max(float v) { for (int o = 32; o; o >>= 1) v = fmaxf(v, __shfl_xor(v, o)); return v; }

DEV short f2bf(float x) {                       // f32 -> bf16 (RNE)
    uint32_t u = __builtin_bit_cast(uint32_t, x);
    u = u + 0x7fffu + ((u >> 16) & 1u);
    return (short)(u >> 16);
}
DEV float bf2f(short b) {
    uint32_t u = ((uint32_t)(uint16_t)b) << 16;
    return __builtin_bit_cast(float, u);
}

DEV void gl_lds16(const void* g, void* l) {     // async 16B/lane global->LDS
    __builtin_amdgcn_global_load_lds(
        (const __attribute__((address_space(1))) uint32_t*)g,
        (__attribute__((address_space(3))) uint32_t*)l, 16, 0, 0);
}

// ---------------------------------------------------------------------------
// prep_A1: fused rowstats + LN-affine + hi/lo split.  One wave per row.
__global__ __launch_bounds__(256)
void prep_A1(const float* __restrict__ X, const float* __restrict__ g,
             const float* __restrict__ b, short* __restrict__ Ah, short* __restrict__ Al)
{
    int w = threadIdx.x >> 6, lane = threadIdx.x & 63;
    int row = blockIdx.x * 4 + w;
    const float4* xr = (const float4*)(X + (size_t)row * KDIM);
    float4 xv[3]; float s = 0.f, ss = 0.f;
#pragma unroll
    for (int i = 0; i < 3; ++i) {
        xv[i] = xr[lane + i * 64];
        s  += xv[i].x + xv[i].y + xv[i].z + xv[i].w;
        ss += xv[i].x * xv[i].x + xv[i].y * xv[i].y + xv[i].z * xv[i].z + xv[i].w * xv[i].w;
    }
    s = wave_sum(s); ss = wave_sum(ss);
    float m = s * (1.f / 768.f), var = ss * (1.f / 768.f) - m * m;
    float sa = rsqrtf(var + 1e-5f), ta = -m * sa;
#pragma unroll
    for (int i = 0; i < 3; ++i) {
        int idx = lane + i * 64;
        float4 gv = ((const float4*)g)[idx];
        float4 bv = ((const float4*)b)[idx];
        float a0 = fmaf(fmaf(xv[i].x, sa, ta), gv.x, bv.x);
        float a1 = fmaf(fmaf(xv[i].y, sa, ta), gv.y, bv.y);
        float a2 = fmaf(fmaf(xv[i].z, sa, ta), gv.z, bv.z);
        float a3 = fmaf(fmaf(xv[i].w, sa, ta), gv.w, bv.w);
        short h0 = f2bf(a0), h1 = f2bf(a1), h2 = f2bf(a2), h3 = f2bf(a3);
        ushort4 hv, lv;
        hv.x = (uint16_t)h0; hv.y = (uint16_t)h1; hv.z = (uint16_t)h2; hv.w = (uint16_t)h3;
        lv.x = (uint16_t)f2bf(a0 - bf2f(h0)); lv.y = (uint16_t)f2bf(a1 - bf2f(h1));
        lv.z = (uint16_t)f2bf(a2 - bf2f(h2)); lv.w = (uint16_t)f2bf(a3 - bf2f(h3));
        ((ushort4*)(Ah + (size_t)row * KDIM))[idx] = hv;
        ((ushort4*)(Al + (size_t)row * KDIM))[idx] = lv;
    }
}

// ---------------------------------------------------------------------------
// prep_A2: gate(tanh dot) + LN2 stats + affine + split. vp packed (hi|lo<<16).
__global__ __launch_bounds__(256)
void prep_A2(const uint32_t* __restrict__ vp_hl, const float* __restrict__ qa_p,
             const float* __restrict__ g, const float* __restrict__ b,
             short* __restrict__ Ah, short* __restrict__ Al, int chunk_off)
{
    int w = threadIdx.x >> 6, lane = threadIdx.x & 63;
    int row = blockIdx.x * 4 + w;
    int bidx = (chunk_off + row) >> 5;
    const uint4*  hr = (const uint4*)(vp_hl + (size_t)row * KDIM);
    const float4* qr = (const float4*)(qa_p + (size_t)bidx * KDIM);
    float vp[12]; float s = 0.f, ss = 0.f, d = 0.f;
#pragma unroll
    for (int i = 0; i < 3; ++i) {
        uint4  uv = hr[lane + i * 64];
        float4 qv = qr[lane + i * 64];
        float v0 = bf2f((short)(uv.x & 0xffff)) + bf2f((short)(uv.x >> 16));
        float v1 = bf2f((short)(uv.y & 0xffff)) + bf2f((short)(uv.y >> 16));
        float v2 = bf2f((short)(uv.z & 0xffff)) + bf2f((short)(uv.z >> 16));
        float v3 = bf2f((short)(uv.w & 0xffff)) + bf2f((short)(uv.w >> 16));
        vp[i * 4 + 0] = v0; vp[i * 4 + 1] = v1; vp[i * 4 + 2] = v2; vp[i * 4 + 3] = v3;
        s  += v0 + v1 + v2 + v3;
        ss += v0 * v0 + v1 * v1 + v2 * v2 + v3 * v3;
        d  += v0 * qv.x + v1 * qv.y + v2 * qv.z + v3 * qv.w;
    }
    s = wave_sum(s); ss = wave_sum(ss); d = wave_sum(d);
    float gate = tanhf(d);
    float m = s * (1.f / 768.f), var = ss * (1.f / 768.f) - m * m;
    float den = rsqrtf(gate * gate * var + 1e-5f);
    float sa = gate * den, ta = -gate * m * den;
#pragma unroll
    for (int i = 0; i < 3; ++i) {
        int idx = lane + i * 64;
        float4 gv = ((const float4*)g)[idx];
        float4 bv = ((const float4*)b)[idx];
        float a0 = fmaf(fmaf(vp[i * 4 + 0], sa, ta), gv.x, bv.x);
        float a1 = fmaf(fmaf(vp[i * 4 + 1], sa, ta), gv.y, bv.y);
        float a2 = fmaf(fmaf(vp[i * 4 + 2], sa, ta), gv.z, bv.z);
        float a3 = fmaf(fmaf(vp[i * 4 + 3], sa, ta), gv.w, bv.w);
        short h0 = f2bf(a0), h1 = f2bf(a1), h2 = f2bf(a2), h3 = f2bf(a3);
        ushort4 hv, lv;
        hv.x = (uint16_t)h0; hv.y = (uint16_t)h1; hv.z = (uint16_t)h2; hv.w = (uint16_t)h3;
        lv.x = (uint16_t)f2bf(a0 - bf2f(h0)); lv.y = (uint16_t)f2bf(a1 - bf2f(h1));
        lv.z = (uint16_t)f2bf(a2 - bf2f(h2)); lv.w = (uint16_t)f2bf(a3 - bf2f(h3));
        ((ushort4*)(Ah + (size_t)row * KDIM))[idx] = hv;
        ((ushort4*)(Al + (size_t)row * KDIM))[idx] = lv;
    }
}

// ---------------------------------------------------------------------------
// prep_W: transpose + hi/lo split.  W[k][n] f32 -> Bh/Bl[n][k] bf16.
__global__ __launch_bounds__(256)
void prep_W(const float* __restrict__ W, short* __restrict__ Bh, short* __restrict__ Bl, int N)
{
    __shared__ float t[32][33];
    int bx = blockIdx.x, by = blockIdx.y;
    int lx = threadIdx.x & 31, ly = threadIdx.x >> 5;
#pragma unroll
    for (int r = 0; r < 32; r += 8)
        t[ly + r][lx] = W[(size_t)(by * 32 + ly + r) * N + bx * 32 + lx];
    __syncthreads();
#pragma unroll
    for (int r = 0; r < 32; r += 8) {
        float v = t[lx][ly + r];
        short hi = f2bf(v);
        size_t o = (size_t)(bx * 32 + ly + r) * KDIM + by * 32 + lx;
        Bh[o] = hi;
        Bl[o] = f2bf(v - bf2f(hi));
    }
}

// ---------------------------------------------------------------------------
// Split-bf16 MFMA GEMM, physical-K schedule.  512 thr / 8 waves (2M x 4N),
// BM=128 BN=384, BK=32.  Per k-tile: 3 phases {AhBh, AhBl, AlBh}, 24 MFMA
// each; stage next k-tile's 8x8KB groups 3/3/2 across the phases.
// LDS buf (64KB): Ah@0(8K) Bh@8K(24K) Bl@32K(24K) Al@56K(8K); double-buffered.
// Group order s0..s7 = Ah,Bh0,Bh1,Bh2,Bl0,Bl1,Bl2,Al.
//   MODE 0: out = gelu(.) packed (hi | lo<<16) u32 into 768-wide vp_hl.
//   MODE 1: partial row-dot with w2 -> partials[wn][row].
#define VMW(N_) asm volatile("s_waitcnt vmcnt(" #N_ ")" ::: "memory")

#define STG(G_, KT_) gl_lds16(sp[G_] + (KT_) * 32,                            \
    lds + (((KT_) & 1) ? BUFSZ : 0) + (G_) * 8192 + toff)

#define RDA(dst, BOFF) do {                                                   \
    _Pragma("unroll")                                                         \
    for (int mf = 0; mf < 4; ++mf) {                                          \
        int rA = wm * 64 + mf * 16 + lr;                                      \
        dst[mf] = *(const short8v*)(bb + (BOFF) + rA * 64 +                   \
                                    ((lh ^ ((rA >> 1) & 3)) << 4));           \
    } } while (0)

#define RDB(dst, BOFF) do {                                                   \
    _Pragma("unroll")                                                         \
    for (int nf = 0; nf < 6; ++nf) {                                          \
        int rB = wn * 96 + nf * 16 + lr;                                      \
        dst[nf] = *(const short8v*)(bb + (BOFF) + rB * 64 +                   \
                                    ((lh ^ ((rB >> 1) & 3)) << 4));           \
    } } while (0)

#define SYNCMM(aop, bop) do {                                                 \
    __builtin_amdgcn_sched_barrier(0);                                        \
    __builtin_amdgcn_s_barrier();                                             \
    asm volatile("s_waitcnt lgkmcnt(0)" ::: "memory");                        \
    __builtin_amdgcn_sched_barrier(0);                                        \
    __builtin_amdgcn_s_setprio(1);                                            \
    _Pragma("unroll")                                                         \
    for (int mf = 0; mf < 4; ++mf)                                            \
        _Pragma("unroll")                                                     \
        for (int nf = 0; nf < 6; ++nf)                                        \
            acc[mf][nf] = __builtin_amdgcn_mfma_f32_16x16x32_bf16(            \
                aop[mf], bop[nf], acc[mf][nf], 0, 0, 0);                      \
    __builtin_amdgcn_s_setprio(0);                                            \
    __builtin_amdgcn_sched_barrier(0);                                        \
    __builtin_amdgcn_s_barrier();                                             \
    } while (0)

template<int MODE>
__global__ __launch_bounds__(512, 1)
void gemm8(const short* __restrict__ Ah_g, const short* __restrict__ Al_g,
           const short* __restrict__ Bh_g, const short* __restrict__ Bl_g,
           const float* __restrict__ bias, uint32_t* __restrict__ O_hl,
           const float* __restrict__ w2, float* __restrict__ partials,
           int chunk_off)
{
    constexpr int BM = 128, BN = 384;
    constexpr int BUFSZ = 65536;              // 64 KB per buffer
    extern __shared__ __align__(16) char lds[];

    const int t = threadIdx.x;
    const int w = t >> 6, lane = t & 63;
    const int lr = lane & 15, lh = lane >> 4;
    const int wm = w >> 2, wn = w & 3;        // 2 x 4 wave grid

    const int gx = gridDim.x, nwg = gx * gridDim.y;
    int bidx = blockIdx.y * gx + blockIdx.x;
    int wid = (bidx & 7) * (nwg >> 3) + (bidx >> 3);
    const int bx = wid % gx, by = wid / gx;
    const int row0 = by * BM, col0 = bx * BN;

    // per-thread stage source pointers (k=0), group order Ah,Bh0..2,Bl0..2,Al.
    // thread t covers (row r = t>>2, slot c = t&3); source k-chunk pre-swizzled
    // c ^ ((r>>1)&3) so LDS dest stays linear (dest = group*8K + t*16).
    const int r_ = t >> 2, c_ = t & 3;
    const int swz_ = (c_ ^ ((r_ >> 1) & 3)) << 3;   // element offset in k
    const int toff = t * 16;
    const short* sp[8];
    sp[0] = Ah_g + (size_t)(row0 + r_) * KDIM + swz_;
    sp[1] = Bh_g + (size_t)(col0 + r_)       * KDIM + swz_;
    sp[2] = Bh_g + (size_t)(col0 + 128 + r_) * KDIM + swz_;
    sp[3] = Bh_g + (size_t)(col0 + 256 + r_) * KDIM + swz_;
    sp[4] = Bl_g + (size_t)(col0 + r_)       * KDIM + swz_;
    sp[5] = Bl_g + (size_t)(col0 + 128 + r_) * KDIM + swz_;
    sp[6] = Bl_g + (size_t)(col0 + 256 + r_) * KDIM + swz_;
    sp[7] = Al_g + (size_t)(row0 + r_) * KDIM + swz_;

    f32x4 acc[4][6] = {};
    short8v ah[4], al[4], bh[6], bl[6];

    // prologue: stage all 8 groups of k-tile 0; VM(4) -> s0..s3 landed
    STG(0, 0); STG(1, 0); STG(2, 0); STG(3, 0);
    STG(4, 0); STG(5, 0); STG(6, 0); STG(7, 0);
    VMW(4);
    __builtin_amdgcn_s_barrier();

    for (int kt = 0; kt < 24; ++kt) {
        const char* bb = lds + ((kt & 1) ? BUFSZ : 0);
        const bool nl = (kt < 23);
        // P0: AhBh.  Stage next s0,s1,s2.  VM guards this tile's s4..s6 (Bl).
        RDA(ah, 0); RDB(bh, 8192);
        if (nl) { STG(0, kt + 1); STG(1, kt + 1); STG(2, kt + 1); VMW(4); }
        else    { VMW(1); }
        SYNCMM(ah, bh);
        // P1: AhBl.  Stage next s3,s4,s5.  VM guards this tile's s7 (Al).
        RDB(bl, 32768);
        if (nl) { STG(3, kt + 1); STG(4, kt + 1); STG(5, kt + 1); VMW(6); }
        else    { VMW(0); }
        SYNCMM(ah, bl);
        // P2: AlBh.  Stage next s6,s7.  VM guards NEXT tile's s0..s3.
        RDA(al, 57344);
        if (nl) { STG(6, kt + 1); STG(7, kt + 1); VMW(4); }
        SYNCMM(al, bh);
    }

    if (MODE == 0) {
#pragma unroll
        for (int mf = 0; mf < 4; ++mf)
#pragma unroll
            for (int nf = 0; nf < 6; ++nf) {
                int n = col0 + wn * 96 + nf * 16 + lr;
                float bvs = bias[n];
#pragma unroll
                for (int q = 0; q < 4; ++q) {
                    int m = row0 + wm * 64 + mf * 16 + lh * 4 + q;
                    float gv = gelu_erf(acc[mf][nf][q] + bvs);
                    short hi = f2bf(gv);
                    short lo = f2bf(gv - bf2f(hi));
                    O_hl[(size_t)m * 768 + n] =
                        (uint32_t)(uint16_t)hi | ((uint32_t)(uint16_t)lo << 16);
                }
            }
    } else {
        float rs[4][4] = {};
#pragma unroll
        for (int mf = 0; mf < 4; ++mf)
#pragma unroll
            for (int nf = 0; nf < 6; ++nf) {
                int n = col0 + wn * 96 + nf * 16 + lr;
                float bvs = bias[n], wv = w2[n];
#pragma unroll
                for (int q = 0; q < 4; ++q)
                    rs[mf][q] += gelu_erf(acc[mf][nf][q] + bvs) * wv;
            }
#pragma unroll
        for (int mf = 0; mf < 4; ++mf)
#pragma unroll
            for (int q = 0; q < 4; ++q) {
                float vv = rs[mf][q];
                vv += __shfl_xor(vv, 1); vv += __shfl_xor(vv, 2);
                vv += __shfl_xor(vv, 4); vv += __shfl_xor(vv, 8);
                if (lr == 0) {
                    int m = chunk_off + row0 + wm * 64 + mf * 16 + lh * 4 + q;
                    partials[(size_t)wn * 65536 + m] = vv;
                }
            }
    }
}

// ---------------------------------------------------------------------------
// f32 fallback GEMM for the small qa projection.
constexpr int BKF = 16;
__global__ __launch_bounds__(256)
void rowstats(const float* __restrict__ X, float2* __restrict__ st, int M)
{
    int wave = threadIdx.x >> 6, lane = threadIdx.x & 63;
    int row = blockIdx.x * 4 + wave;
    if (row >= M) return;
    const float4* xr = reinterpret_cast<const float4*>(X + (size_t)row * KDIM);
    float s = 0.f, ss = 0.f;
#pragma unroll
    for (int i = 0; i < 3; ++i) {
        float4 v = xr[lane + i * 64];
        s  += v.x + v.y + v.z + v.w;
        ss += v.x * v.x + v.y * v.y + v.z * v.z + v.w * v.w;
    }
    s = wave_sum(s); ss = wave_sum(ss);
    if (lane == 0) {
        float m = s * (1.0f / 768.0f);
        float var = ss * (1.0f / 768.0f) - m * m;
        float rstd = rsqrtf(var + 1e-5f);
        st[row] = make_float2(rstd, -m * rstd);
    }
}

template<int BM, int BN, int TM, int TN>
__global__ __launch_bounds__(256)
void gemm_fused(const float* __restrict__ X, const float2* __restrict__ st,
                const float* __restrict__ gw, const float* __restrict__ gb,
                const float* __restrict__ W, const float* __restrict__ bias,
                float* __restrict__ out, int M, int N)
{
    static_assert((BM / TM) * (BN / TN) == 256, "256 threads");
    __shared__ float As[BKF][BM];
    __shared__ float Bs[BKF][BN];
    const int t = threadIdx.x;
    constexpr int TXN = BN / TN;
    const int tx = t % TXN;
    const int ty = t / TXN;
    const int row0 = blockIdx.y * BM;
    const int col0 = blockIdx.x * BN;
    float acc[TM][TN] = {};
    constexpr int A_IT = BM * BKF / 4 / 256;
    constexpr int B_IT = BKF * BN / 4 / 256;
    for (int k0 = 0; k0 < KDIM; k0 += BKF) {
#pragma unroll
        for (int i = 0; i < A_IT; ++i) {
            int idx = t + i * 256;
            int r = idx >> 2;
            int c = (idx & 3) << 2;
            float4 xv = *reinterpret_cast<const float4*>(X + (size_t)(row0 + r) * KDIM + k0 + c);
            float2 s = st[row0 + r];
            float4 gv = *reinterpret_cast<const float4*>(gw + k0 + c);
            float4 bv = *reinterpret_cast<const float4*>(gb + k0 + c);
            As[c + 0][r] = fmaf(fmaf(xv.x, s.x, s.y), gv.x, bv.x);
            As[c + 1][r] = fmaf(fmaf(xv.y, s.x, s.y), gv.y, bv.y);
            As[c + 2][r] = fmaf(fmaf(xv.z, s.x, s.y), gv.z, bv.z);
            As[c + 3][r] = fmaf(fmaf(xv.w, s.x, s.y), gv.w, bv.w);
        }
#pragma unroll
        for (int i = 0; i < B_IT; ++i) {
            int idx = t + i * 256;
            int r = idx / (BN / 4);
            int c = (idx % (BN / 4)) << 2;
            *reinterpret_cast<float4*>(&Bs[r][c]) =
                *reinterpret_cast<const float4*>(W + (size_t)(k0 + r) * N + col0 + c);
        }
        __syncthreads();
#pragma unroll
        for (int kk = 0; kk < BKF; ++kk) {
            float a[TM], b[TN];
#pragma unroll
            for (int i = 0; i < TM; i += 4)
                *reinterpret_cast<float4*>(&a[i]) = *reinterpret_cast<const float4*>(&As[kk][ty * TM + i]);
#pragma unroll
            for (int j = 0; j < TN; j += 4)
                *reinterpret_cast<float4*>(&b[j]) = *reinterpret_cast<const float4*>(&Bs[kk][tx * TN + j]);
#pragma unroll
            for (int i = 0; i < TM; ++i)
#pragma unroll
                for (int j = 0; j < TN; ++j)
                    acc[i][j] = fmaf(a[i], b[j], acc[i][j]);
        }
        __syncthreads();
    }
#pragma unroll
    for (int i = 0; i < TM; ++i) {
        size_t row = row0 + ty * TM + i;
#pragma unroll
        for (int j = 0; j < TN; j += 4) {
            int col = col0 + tx * TN + j;
            float4 o;
            o.x = gelu_erf(acc[i][j + 0] + bias[col + 0]);
            o.y = gelu_erf(acc[i][j + 1] + bias[col + 1]);
            o.z = gelu_erf(acc[i][j + 2] + bias[col + 2]);
            o.w = gelu_erf(acc[i][j + 3] + bias[col + 3]);
            *reinterpret_cast<float4*>(out + row * N + col) = o;
        }
    }
}

// ---------------------------------------------------------------------------
// head: logits = sum(4 partials)+b2 -> softmax -> smooth -> softmax -> decode.
__global__ __launch_bounds__(64)
void head_kernel(const float* __restrict__ partials, const float* __restrict__ b2,
                 const float* __restrict__ sigma_p, float* __restrict__ out)
{
    int b = blockIdx.x, lane = threadIdx.x;
    __shared__ float ok[36];
    __shared__ float kg[32];
    __shared__ int sel[2];

    if (lane < 36) ok[lane] = 0.f;
    __syncthreads();

    float x = -3.4e38f;
    if (lane < 32) {
        int row = b * 32 + lane;
        x = b2[0];
#pragma unroll
        for (int p = 0; p < 4; ++p) x += partials[(size_t)p * 65536 + row];
    }
    float mx = wave_max(x);
    float e = (lane < 32) ? expf(x - mx) : 0.f;
    float sum = wave_sum(e);
    float ori = e / sum;
    if (lane < 32) {
        out[OFF_ORI + b * 32 + lane] = ori;
        ok[lane + 2] = ori;
    }
    __syncthreads();

    float sg = sigma_p[0];
    float kern[5]; float ks = 0.f;
#pragma unroll
    for (int k = 0; k < 5; ++k) { float xx = (float)(k - 2) / sg; kern[k] = expf(-0.5f * xx * xx); ks += kern[k]; }
    float sm = -3.4e38f;
    if (lane < 32) {
        sm = 0.f;
#pragma unroll
        for (int k = 0; k < 5; ++k) sm += (kern[k] / ks) * ok[lane + k];
    }
    float mx2 = wave_max(sm);
    float e2 = (lane < 32) ? expf(sm - mx2) : 0.f;
    float sum2 = wave_sum(e2);
    float kgv = e2 / sum2;
    if (lane < 32) {
        out[OFF_KG + b * 32 + lane] = kgv;
        kg[lane] = kgv;
    }
    __syncthreads();

    if (lane == 0) {
        int pm = 0; float bv = kg[0];
        for (int i = 1; i < 32; ++i) if (kg[i] > bv) { bv = kg[i]; pm = i; }
        float cum[33]; cum[0] = 0.f;
        for (int i = 0; i < 32; ++i) cum[i + 1] = cum[i] + kg[i];
        float bs = -3.4e38f; int bst = 0, ben = 0;
        const int wsz[3] = {1, 3, 5};
        for (int wi = 0; wi < 3; ++wi) {
            int w = wsz[wi];
            for (int s = 0; s + w <= 32; ++s) {
                if (pm >= s && pm < s + w) {
                    float sc = cum[s + w] - cum[s];
                    if (sc > bs) { bs = sc; bst = s; ben = s + w; }
                }
            }
        }
        out[OFF_MI + b * 2 + 0] = (float)bst;
        out[OFF_MI + b * 2 + 1] = (float)ben;
        out[OFF_ST + b] = (float)bst / 31.0f;
        out[OFF_ET + b] = (float)ben / 31.0f;
        sel[0] = bst; sel[1] = ben;
    }
    __syncthreads();
    if (lane < 32)
        out[OFF_MASK + b * 32 + lane] = (lane >= sel[0] && lane <= sel[1]) ? 1.0f : 0.0f;
}

// ---------------------------------------------------------------------------
extern "C" void kernel_launch(void* const* d_in, const int* in_sizes, int n_in,
                              void* d_out, int out_size, void* d_ws, size_t ws_size,
                              hipStream_t stream)
{
    const float* v      = (const float*)d_in[0];
    const float* qa     = (const float*)d_in[1];
    const float* vp_lng = (const float*)d_in[2];
    const float* vp_lnb = (const float*)d_in[3];
    const float* vp_w   = (const float*)d_in[4];
    const float* vp_b   = (const float*)d_in[5];
    const float* qp_lng = (const float*)d_in[6];
    const float* qp_lnb = (const float*)d_in[7];
    const float* qp_w   = (const float*)d_in[8];
    const float* qp_b   = (const float*)d_in[9];
    const float* g_lng  = (const float*)d_in[10];
    const float* g_lnb  = (const float*)d_in[11];
    const float* g_w1   = (const float*)d_in[12];
    const float* g_b1   = (const float*)d_in[13];
    const float* g_w2   = (const float*)d_in[14];
    const float* g_b2   = (const float*)d_in[15];
    const float* sigma  = (const float*)d_in[16];
    float* outf = (float*)d_out;

    // workspace layout (~213 MB)
    short* A1h = (short*)d_ws;                           // CHUNK*768
    short* A1l = A1h + (size_t)CHUNK * KDIM;
    uint32_t* vp_hl = (uint32_t*)(A1l + (size_t)CHUNK * KDIM);   // CHUNK*768 u32
    short* B1h = (short*)(vp_hl + (size_t)CHUNK * KDIM); // 768*768
    short* B1l = B1h + 768 * KDIM;
    short* B2h = B1l + 768 * KDIM;                       // 384*768
    short* B2l = B2h + 384 * KDIM;
    float* qa_p = (float*)(B2l + 384 * KDIM);            // 2048*768
    float* st_qa = qa_p + 2048 * KDIM;                   // 2048*2
    float* partials = st_qa + 4096;                      // 4*65536

    // qa path (small, f32 vector GEMM)
    rowstats<<<512, 256, 0, stream>>>(qa, (float2*)st_qa, 2048);
    gemm_fused<64, 64, 4, 4><<<dim3(12, 32), 256, 0, stream>>>(
        qa, (const float2*)st_qa, qp_lng, qp_lnb, qp_w, qp_b, qa_p, 2048, 768);

    // weight transpose + split
    prep_W<<<dim3(24, 24), 256, 0, stream>>>(vp_w, B1h, B1l, 768);
    prep_W<<<dim3(12, 24), 256, 0, stream>>>(g_w1, B2h, B2l, 384);

    constexpr int LDS8 = 131072;   // 2 bufs x 64 KB

    for (int c = 0; c < 65536; c += CHUNK) {
        prep_A1<<<CHUNK / 4, 256, 0, stream>>>(v + (size_t)c * KDIM, vp_lng, vp_lnb, A1h, A1l);
        // v_p = gelu(A1 @ vp_w^T + vp_b): 128x384 tile, grid (2,256)=512 blocks
        gemm8<0><<<dim3(2, CHUNK / 128), 512, LDS8, stream>>>(
            A1h, A1l, B1h, B1l, vp_b, vp_hl, nullptr, nullptr, 0);
        prep_A2<<<CHUNK / 4, 256, 0, stream>>>(vp_hl, qa_p, g_lng, g_lnb, A1h, A1l, c);
        // fused h@g_w1+gelu+dot(g_w2): 128x384 tile, grid (1,256)=256 blocks
        gemm8<1><<<dim3(1, CHUNK / 128), 512, LDS8, stream>>>(
            A1h, A1l, B2h, B2l, g_b1, nullptr, g_w2, partials, c);
    }

    head_kernel<<<2048, 64, 0, stream>>>(partials, g_b2, sigma, outf);
}

// Round 10
// 610.085 us; speedup vs baseline: 1.3916x; 1.0643x over previous
//
#include <hip/hip_runtime.h>
#include <math.h>
#include <stdint.h>

// ---------------------------------------------------------------------------
// GroundingModule — round 10: 2-blocks-per-CU split-bf16 GEMM.
// 256 thr / 4 waves (2x2), tile 128x128, LDS 64KB (2 x 32KB dbuf) -> two
// independent barrier groups per CU: block A's barrier/vmcnt stalls hide
// under block B's MFMA.  Physical-K stage-once 3-term schedule from round 9
// (units halved to 4KB): P0 AhBh / P1 AhBl / P2 AlBh, 16 MFMA each;
// counted vmcnt VM(4)/VM(6)/VM(4); 64B rows + slot-XOR swizzle (0 conflicts).
// ---------------------------------------------------------------------------

#define DEV __device__ __forceinline__

typedef __attribute__((ext_vector_type(8))) short short8v;   // 8 bf16
typedef __attribute__((ext_vector_type(4))) float f32x4;

constexpr int KDIM  = 768;
constexpr int CHUNK = 32768;

// output offsets (floats) in return order
constexpr int OFF_KG   = 0;
constexpr int OFF_MI   = 65536;
constexpr int OFF_ST   = 69632;
constexpr int OFF_ET   = 71680;
constexpr int OFF_MASK = 73728;
constexpr int OFF_ORI  = 139264;

DEV float gelu_erf(float x) { return 0.5f * x * (1.0f + erff(x * 0.70710678118654752f)); }
DEV float wave_sum(float v) { for (int o = 32; o; o >>= 1) v += __shfl_xor(v, o); return v; }
DEV float wave_max(float v) { for (int o = 32; o; o >>= 1) v = fmaxf(v, __shfl_xor(v, o)); return v; }

DEV short f2bf(float x) {                       // f32 -> bf16 (RNE)
    uint32_t u = __builtin_bit_cast(uint32_t, x);
    u = u + 0x7fffu + ((u >> 16) & 1u);
    return (short)(u >> 16);
}
DEV float bf2f(short b) {
    uint32_t u = ((uint32_t)(uint16_t)b) << 16;
    return __builtin_bit_cast(float, u);
}

DEV void gl_lds16(const void* g, void* l) {     // async 16B/lane global->LDS
    __builtin_amdgcn_global_load_lds(
        (const __attribute__((address_space(1))) uint32_t*)g,
        (__attribute__((address_space(3))) uint32_t*)l, 16, 0, 0);
}

// ---------------------------------------------------------------------------
// prep_A1: fused rowstats + LN-affine + hi/lo split.  One wave per row.
__global__ __launch_bounds__(256)
void prep_A1(const float* __restrict__ X, const float* __restrict__ g,
             const float* __restrict__ b, short* __restrict__ Ah, short* __restrict__ Al)
{
    int w = threadIdx.x >> 6, lane = threadIdx.x & 63;
    int row = blockIdx.x * 4 + w;
    const float4* xr = (const float4*)(X + (size_t)row * KDIM);
    float4 xv[3]; float s = 0.f, ss = 0.f;
#pragma unroll
    for (int i = 0; i < 3; ++i) {
        xv[i] = xr[lane + i * 64];
        s  += xv[i].x + xv[i].y + xv[i].z + xv[i].w;
        ss += xv[i].x * xv[i].x + xv[i].y * xv[i].y + xv[i].z * xv[i].z + xv[i].w * xv[i].w;
    }
    s = wave_sum(s); ss = wave_sum(ss);
    float m = s * (1.f / 768.f), var = ss * (1.f / 768.f) - m * m;
    float sa = rsqrtf(var + 1e-5f), ta = -m * sa;
#pragma unroll
    for (int i = 0; i < 3; ++i) {
        int idx = lane + i * 64;
        float4 gv = ((const float4*)g)[idx];
        float4 bv = ((const float4*)b)[idx];
        float a0 = fmaf(fmaf(xv[i].x, sa, ta), gv.x, bv.x);
        float a1 = fmaf(fmaf(xv[i].y, sa, ta), gv.y, bv.y);
        float a2 = fmaf(fmaf(xv[i].z, sa, ta), gv.z, bv.z);
        float a3 = fmaf(fmaf(xv[i].w, sa, ta), gv.w, bv.w);
        short h0 = f2bf(a0), h1 = f2bf(a1), h2 = f2bf(a2), h3 = f2bf(a3);
        ushort4 hv, lv;
        hv.x = (uint16_t)h0; hv.y = (uint16_t)h1; hv.z = (uint16_t)h2; hv.w = (uint16_t)h3;
        lv.x = (uint16_t)f2bf(a0 - bf2f(h0)); lv.y = (uint16_t)f2bf(a1 - bf2f(h1));
        lv.z = (uint16_t)f2bf(a2 - bf2f(h2)); lv.w = (uint16_t)f2bf(a3 - bf2f(h3));
        ((ushort4*)(Ah + (size_t)row * KDIM))[idx] = hv;
        ((ushort4*)(Al + (size_t)row * KDIM))[idx] = lv;
    }
}

// ---------------------------------------------------------------------------
// prep_A2: gate(tanh dot) + LN2 stats + affine + split. vp packed (hi|lo<<16).
__global__ __launch_bounds__(256)
void prep_A2(const uint32_t* __restrict__ vp_hl, const float* __restrict__ qa_p,
             const float* __restrict__ g, const float* __restrict__ b,
             short* __restrict__ Ah, short* __restrict__ Al, int chunk_off)
{
    int w = threadIdx.x >> 6, lane = threadIdx.x & 63;
    int row = blockIdx.x * 4 + w;
    int bidx = (chunk_off + row) >> 5;
    const uint4*  hr = (const uint4*)(vp_hl + (size_t)row * KDIM);
    const float4* qr = (const float4*)(qa_p + (size_t)bidx * KDIM);
    float vp[12]; float s = 0.f, ss = 0.f, d = 0.f;
#pragma unroll
    for (int i = 0; i < 3; ++i) {
        uint4  uv = hr[lane + i * 64];
        float4 qv = qr[lane + i * 64];
        float v0 = bf2f((short)(uv.x & 0xffff)) + bf2f((short)(uv.x >> 16));
        float v1 = bf2f((short)(uv.y & 0xffff)) + bf2f((short)(uv.y >> 16));
        float v2 = bf2f((short)(uv.z & 0xffff)) + bf2f((short)(uv.z >> 16));
        float v3 = bf2f((short)(uv.w & 0xffff)) + bf2f((short)(uv.w >> 16));
        vp[i * 4 + 0] = v0; vp[i * 4 + 1] = v1; vp[i * 4 + 2] = v2; vp[i * 4 + 3] = v3;
        s  += v0 + v1 + v2 + v3;
        ss += v0 * v0 + v1 * v1 + v2 * v2 + v3 * v3;
        d  += v0 * qv.x + v1 * qv.y + v2 * qv.z + v3 * qv.w;
    }
    s = wave_sum(s); ss = wave_sum(ss); d = wave_sum(d);
    float gate = tanhf(d);
    float m = s * (1.f / 768.f), var = ss * (1.f / 768.f) - m * m;
    float den = rsqrtf(gate * gate * var + 1e-5f);
    float sa = gate * den, ta = -gate * m * den;
#pragma unroll
    for (int i = 0; i < 3; ++i) {
        int idx = lane + i * 64;
        float4 gv = ((const float4*)g)[idx];
        float4 bv = ((const float4*)b)[idx];
        float a0 = fmaf(fmaf(vp[i * 4 + 0], sa, ta), gv.x, bv.x);
        float a1 = fmaf(fmaf(vp[i * 4 + 1], sa, ta), gv.y, bv.y);
        float a2 = fmaf(fmaf(vp[i * 4 + 2], sa, ta), gv.z, bv.z);
        float a3 = fmaf(fmaf(vp[i * 4 + 3], sa, ta), gv.w, bv.w);
        short h0 = f2bf(a0), h1 = f2bf(a1), h2 = f2bf(a2), h3 = f2bf(a3);
        ushort4 hv, lv;
        hv.x = (uint16_t)h0; hv.y = (uint16_t)h1; hv.z = (uint16_t)h2; hv.w = (uint16_t)h3;
        lv.x = (uint16_t)f2bf(a0 - bf2f(h0)); lv.y = (uint16_t)f2bf(a1 - bf2f(h1));
        lv.z = (uint16_t)f2bf(a2 - bf2f(h2)); lv.w = (uint16_t)f2bf(a3 - bf2f(h3));
        ((ushort4*)(Ah + (size_t)row * KDIM))[idx] = hv;
        ((ushort4*)(Al + (size_t)row * KDIM))[idx] = lv;
    }
}

// ---------------------------------------------------------------------------
// prep_W: transpose + hi/lo split.  W[k][n] f32 -> Bh/Bl[n][k] bf16.
__global__ __launch_bounds__(256)
void prep_W(const float* __restrict__ W, short* __restrict__ Bh, short* __restrict__ Bl, int N)
{
    __shared__ float t[32][33];
    int bx = blockIdx.x, by = blockIdx.y;
    int lx = threadIdx.x & 31, ly = threadIdx.x >> 5;
#pragma unroll
    for (int r = 0; r < 32; r += 8)
        t[ly + r][lx] = W[(size_t)(by * 32 + ly + r) * N + bx * 32 + lx];
    __syncthreads();
#pragma unroll
    for (int r = 0; r < 32; r += 8) {
        float v = t[lx][ly + r];
        short hi = f2bf(v);
        size_t o = (size_t)(bx * 32 + ly + r) * KDIM + by * 32 + lx;
        Bh[o] = hi;
        Bl[o] = f2bf(v - bf2f(hi));
    }
}

// ---------------------------------------------------------------------------
// Split-bf16 MFMA GEMM, 2 blocks/CU.  256 thr / 4 waves (2M x 2N), BM=BN=128,
// BK=32.  Per k-tile: 3 phases {AhBh, AhBl, AlBh}, 16 MFMA each; stage next
// k-tile's 8x4KB units 3/3/2 across the phases.
// LDS buf (32KB): Ah@0(8K) Bh@8K(8K) Bl@16K(8K) Al@24K(8K); double-buffered.
// Unit order u0..u7 = Ah0,Ah1,Bh0 | Bh1,Bl0,Bl1 | Al0,Al1.
//   MODE 0: out = gelu(.) packed (hi | lo<<16) u32 into 768-wide vp_hl.
//   MODE 1: partial row-dot with w2 -> partials[bx*2+wn][row].
#define VMW(N_) asm volatile("s_waitcnt vmcnt(" #N_ ")" ::: "memory")

#define STG(G_, KT_) gl_lds16(sp[G_] + (KT_) * 32,                            \
    lds + (((KT_) & 1) ? BUFSZ : 0) + (G_) * 4096 + toff)

#define RDA(dst, BOFF) do {                                                   \
    _Pragma("unroll")                                                         \
    for (int mf = 0; mf < 4; ++mf) {                                          \
        int rA = wm * 64 + mf * 16 + lr;                                      \
        dst[mf] = *(const short8v*)(bb + (BOFF) + rA * 64 +                   \
                                    ((lh ^ ((rA >> 1) & 3)) << 4));           \
    } } while (0)

#define RDB(dst, BOFF) do {                                                   \
    _Pragma("unroll")                                                         \
    for (int nf = 0; nf < 4; ++nf) {                                          \
        int rB = wn * 64 + nf * 16 + lr;                                      \
        dst[nf] = *(const short8v*)(bb + (BOFF) + rB * 64 +                   \
                                    ((lh ^ ((rB >> 1) & 3)) << 4));           \
    } } while (0)

#define SYNCMM(aop, bop) do {                                                 \
    __builtin_amdgcn_sched_barrier(0);                                        \
    __builtin_amdgcn_s_barrier();                                             \
    asm volatile("s_waitcnt lgkmcnt(0)" ::: "memory");                        \
    __builtin_amdgcn_sched_barrier(0);                                        \
    __builtin_amdgcn_s_setprio(1);                                            \
    _Pragma("unroll")                                                         \
    for (int mf = 0; mf < 4; ++mf)                                            \
        _Pragma("unroll")                                                     \
        for (int nf = 0; nf < 4; ++nf)                                        \
            acc[mf][nf] = __builtin_amdgcn_mfma_f32_16x16x32_bf16(            \
                aop[mf], bop[nf], acc[mf][nf], 0, 0, 0);                      \
    __builtin_amdgcn_s_setprio(0);                                            \
    __builtin_amdgcn_sched_barrier(0);                                        \
    __builtin_amdgcn_s_barrier();                                             \
    } while (0)

template<int MODE>
__global__ __launch_bounds__(256, 2)
void gemm8(const short* __restrict__ Ah_g, const short* __restrict__ Al_g,
           const short* __restrict__ Bh_g, const short* __restrict__ Bl_g,
           const float* __restrict__ bias, uint32_t* __restrict__ O_hl,
           const float* __restrict__ w2, float* __restrict__ partials,
           int chunk_off)
{
    constexpr int BUFSZ = 32768;              // 32 KB per buffer
    extern __shared__ __align__(16) char lds[];

    const int t = threadIdx.x;
    const int w = t >> 6, lane = t & 63;
    const int lr = lane & 15, lh = lane >> 4;
    const int wm = w >> 1, wn = w & 1;        // 2 x 2 wave grid

    const int gx = gridDim.x, nwg = gx * gridDim.y;
    int bidx = blockIdx.y * gx + blockIdx.x;
    int wid = (bidx & 7) * (nwg >> 3) + (bidx >> 3);
    const int bx = wid % gx, by = wid / gx;
    const int row0 = by * 128, col0 = bx * 128;

    // per-thread stage source pointers (k=0); unit order Ah0,Ah1,Bh0,Bh1,
    // Bl0,Bl1,Al0,Al1.  thread t covers (row r_ = t>>2, slot c_ = t&3) within
    // a 64-row unit; source k-chunk pre-swizzled c ^ ((r>>1)&3) so the LDS
    // destination stays linear (dest = unit*4K + t*16).
    const int r_ = t >> 2, c_ = t & 3;
    const int swz_ = (c_ ^ ((r_ >> 1) & 3)) << 3;   // element offset in k
    const int toff = t * 16;
    const short* sp[8];
    sp[0] = Ah_g + (size_t)(row0 + r_)      * KDIM + swz_;
    sp[1] = Ah_g + (size_t)(row0 + 64 + r_) * KDIM + swz_;
    sp[2] = Bh_g + (size_t)(col0 + r_)      * KDIM + swz_;
    sp[3] = Bh_g + (size_t)(col0 + 64 + r_) * KDIM + swz_;
    sp[4] = Bl_g + (size_t)(col0 + r_)      * KDIM + swz_;
    sp[5] = Bl_g + (size_t)(col0 + 64 + r_) * KDIM + swz_;
    sp[6] = Al_g + (size_t)(row0 + r_)      * KDIM + swz_;
    sp[7] = Al_g + (size_t)(row0 + 64 + r_) * KDIM + swz_;

    f32x4 acc[4][4] = {};
    short8v ah[4], al[4], bh[4], bl[4];

    // prologue: stage all 8 units of k-tile 0; VM(4) -> u0..u3 (Ah+Bh) landed
    STG(0, 0); STG(1, 0); STG(2, 0); STG(3, 0);
    STG(4, 0); STG(5, 0); STG(6, 0); STG(7, 0);
    VMW(4);
    __builtin_amdgcn_s_barrier();

    for (int kt = 0; kt < 24; ++kt) {
        const char* bb = lds + ((kt & 1) ? BUFSZ : 0);
        const bool nl = (kt < 23);
        // P0: AhBh.  Stage next u0,u1,u2.  Wait covers this tile's Bl units.
        RDA(ah, 0); RDB(bh, 8192);
        if (nl) { STG(0, kt + 1); STG(1, kt + 1); STG(2, kt + 1); VMW(4); }
        else    { VMW(2); }
        SYNCMM(ah, bh);
        // P1: AhBl.  Stage next u3,u4,u5.  Wait covers this tile's Al units.
        RDB(bl, 16384);
        if (nl) { STG(3, kt + 1); STG(4, kt + 1); STG(5, kt + 1); VMW(6); }
        else    { VMW(0); }
        SYNCMM(ah, bl);
        // P2: AlBh.  Stage next u6,u7.  Wait covers NEXT tile's Ah+Bh units.
        RDA(al, 24576);
        if (nl) { STG(6, kt + 1); STG(7, kt + 1); VMW(4); }
        SYNCMM(al, bh);
    }

    if (MODE == 0) {
#pragma unroll
        for (int mf = 0; mf < 4; ++mf)
#pragma unroll
            for (int nf = 0; nf < 4; ++nf) {
                int n = col0 + wn * 64 + nf * 16 + lr;
                float bvs = bias[n];
#pragma unroll
                for (int q = 0; q < 4; ++q) {
                    int m = row0 + wm * 64 + mf * 16 + lh * 4 + q;
                    float gv = gelu_erf(acc[mf][nf][q] + bvs);
                    short hi = f2bf(gv);
                    short lo = f2bf(gv - bf2f(hi));
                    O_hl[(size_t)m * 768 + n] =
                        (uint32_t)(uint16_t)hi | ((uint32_t)(uint16_t)lo << 16);
                }
            }
    } else {
        float rs[4][4] = {};
#pragma unroll
        for (int mf = 0; mf < 4; ++mf)
#pragma unroll
            for (int nf = 0; nf < 4; ++nf) {
                int n = col0 + wn * 64 + nf * 16 + lr;
                float bvs = bias[n], wv = w2[n];
#pragma unroll
                for (int q = 0; q < 4; ++q)
                    rs[mf][q] += gelu_erf(acc[mf][nf][q] + bvs) * wv;
            }
#pragma unroll
        for (int mf = 0; mf < 4; ++mf)
#pragma unroll
            for (int q = 0; q < 4; ++q) {
                float vv = rs[mf][q];
                vv += __shfl_xor(vv, 1); vv += __shfl_xor(vv, 2);
                vv += __shfl_xor(vv, 4); vv += __shfl_xor(vv, 8);
                if (lr == 0) {
                    int m = chunk_off + row0 + wm * 64 + mf * 16 + lh * 4 + q;
                    partials[(size_t)(bx * 2 + wn) * 65536 + m] = vv;
                }
            }
    }
}

// ---------------------------------------------------------------------------
// f32 fallback GEMM for the small qa projection.
constexpr int BKF = 16;
__global__ __launch_bounds__(256)
void rowstats(const float* __restrict__ X, float2* __restrict__ st, int M)
{
    int wave = threadIdx.x >> 6, lane = threadIdx.x & 63;
    int row = blockIdx.x * 4 + wave;
    if (row >= M) return;
    const float4* xr = reinterpret_cast<const float4*>(X + (size_t)row * KDIM);
    float s = 0.f, ss = 0.f;
#pragma unroll
    for (int i = 0; i < 3; ++i) {
        float4 v = xr[lane + i * 64];
        s  += v.x + v.y + v.z + v.w;
        ss += v.x * v.x + v.y * v.y + v.z * v.z + v.w * v.w;
    }
    s = wave_sum(s); ss = wave_sum(ss);
    if (lane == 0) {
        float m = s * (1.0f / 768.0f);
        float var = ss * (1.0f / 768.0f) - m * m;
        float rstd = rsqrtf(var + 1e-5f);
        st[row] = make_float2(rstd, -m * rstd);
    }
}

template<int BM, int BN, int TM, int TN>
__global__ __launch_bounds__(256)
void gemm_fused(const float* __restrict__ X, const float2* __restrict__ st,
                const float* __restrict__ gw, const float* __restrict__ gb,
                const float* __restrict__ W, const float* __restrict__ bias,
                float* __restrict__ out, int M, int N)
{
    static_assert((BM / TM) * (BN / TN) == 256, "256 threads");
    __shared__ float As[BKF][BM];
    __shared__ float Bs[BKF][BN];
    const int t = threadIdx.x;
    constexpr int TXN = BN / TN;
    const int tx = t % TXN;
    const int ty = t / TXN;
    const int row0 = blockIdx.y * BM;
    const int col0 = blockIdx.x * BN;
    float acc[TM][TN] = {};
    constexpr int A_IT = BM * BKF / 4 / 256;
    constexpr int B_IT = BKF * BN / 4 / 256;
    for (int k0 = 0; k0 < KDIM; k0 += BKF) {
#pragma unroll
        for (int i = 0; i < A_IT; ++i) {
            int idx = t + i * 256;
            int r = idx >> 2;
            int c = (idx & 3) << 2;
            float4 xv = *reinterpret_cast<const float4*>(X + (size_t)(row0 + r) * KDIM + k0 + c);
            float2 s = st[row0 + r];
            float4 gv = *reinterpret_cast<const float4*>(gw + k0 + c);
            float4 bv = *reinterpret_cast<const float4*>(gb + k0 + c);
            As[c + 0][r] = fmaf(fmaf(xv.x, s.x, s.y), gv.x, bv.x);
            As[c + 1][r] = fmaf(fmaf(xv.y, s.x, s.y), gv.y, bv.y);
            As[c + 2][r] = fmaf(fmaf(xv.z, s.x, s.y), gv.z, bv.z);
            As[c + 3][r] = fmaf(fmaf(xv.w, s.x, s.y), gv.w, bv.w);
        }
#pragma unroll
        for (int i = 0; i < B_IT; ++i) {
            int idx = t + i * 256;
            int r = idx / (BN / 4);
            int c = (idx % (BN / 4)) << 2;
            *reinterpret_cast<float4*>(&Bs[r][c]) =
                *reinterpret_cast<const float4*>(W + (size_t)(k0 + r) * N + col0 + c);
        }
        __syncthreads();
#pragma unroll
        for (int kk = 0; kk < BKF; ++kk) {
            float a[TM], b[TN];
#pragma unroll
            for (int i = 0; i < TM; i += 4)
                *reinterpret_cast<float4*>(&a[i]) = *reinterpret_cast<const float4*>(&As[kk][ty * TM + i]);
#pragma unroll
            for (int j = 0; j < TN; j += 4)
                *reinterpret_cast<float4*>(&b[j]) = *reinterpret_cast<const float4*>(&Bs[kk][tx * TN + j]);
#pragma unroll
            for (int i = 0; i < TM; ++i)
#pragma unroll
                for (int j = 0; j < TN; ++j)
                    acc[i][j] = fmaf(a[i], b[j], acc[i][j]);
        }
        __syncthreads();
    }
#pragma unroll
    for (int i = 0; i < TM; ++i) {
        size_t row = row0 + ty * TM + i;
#pragma unroll
        for (int j = 0; j < TN; j += 4) {
            int col = col0 + tx * TN + j;
            float4 o;
            o.x = gelu_erf(acc[i][j + 0] + bias[col + 0]);
            o.y = gelu_erf(acc[i][j + 1] + bias[col + 1]);
            o.z = gelu_erf(acc[i][j + 2] + bias[col + 2]);
            o.w = gelu_erf(acc[i][j + 3] + bias[col + 3]);
            *reinterpret_cast<float4*>(out + row * N + col) = o;
        }
    }
}

// ---------------------------------------------------------------------------
// head: logits = sum(6 partials)+b2 -> softmax -> smooth -> softmax -> decode.
__global__ __launch_bounds__(64)
void head_kernel(const float* __restrict__ partials, const float* __restrict__ b2,
                 const float* __restrict__ sigma_p, float* __restrict__ out)
{
    int b = blockIdx.x, lane = threadIdx.x;
    __shared__ float ok[36];
    __shared__ float kg[32];
    __shared__ int sel[2];

    if (lane < 36) ok[lane] = 0.f;
    __syncthreads();

    float x = -3.4e38f;
    if (lane < 32) {
        int row = b * 32 + lane;
        x = b2[0];
#pragma unroll
        for (int p = 0; p < 6; ++p) x += partials[(size_t)p * 65536 + row];
    }
    float mx = wave_max(x);
    float e = (lane < 32) ? expf(x - mx) : 0.f;
    float sum = wave_sum(e);
    float ori = e / sum;
    if (lane < 32) {
        out[OFF_ORI + b * 32 + lane] = ori;
        ok[lane + 2] = ori;
    }
    __syncthreads();

    float sg = sigma_p[0];
    float kern[5]; float ks = 0.f;
#pragma unroll
    for (int k = 0; k < 5; ++k) { float xx = (float)(k - 2) / sg; kern[k] = expf(-0.5f * xx * xx); ks += kern[k]; }
    float sm = -3.4e38f;
    if (lane < 32) {
        sm = 0.f;
#pragma unroll
        for (int k = 0; k < 5; ++k) sm += (kern[k] / ks) * ok[lane + k];
    }
    float mx2 = wave_max(sm);
    float e2 = (lane < 32) ? expf(sm - mx2) : 0.f;
    float sum2 = wave_sum(e2);
    float kgv = e2 / sum2;
    if (lane < 32) {
        out[OFF_KG + b * 32 + lane] = kgv;
        kg[lane] = kgv;
    }
    __syncthreads();

    if (lane == 0) {
        int pm = 0; float bv = kg[0];
        for (int i = 1; i < 32; ++i) if (kg[i] > bv) { bv = kg[i]; pm = i; }
        float cum[33]; cum[0] = 0.f;
        for (int i = 0; i < 32; ++i) cum[i + 1] = cum[i] + kg[i];
        float bs = -3.4e38f; int bst = 0, ben = 0;
        const int wsz[3] = {1, 3, 5};
        for (int wi = 0; wi < 3; ++wi) {
            int w = wsz[wi];
            for (int s = 0; s + w <= 32; ++s) {
                if (pm >= s && pm < s + w) {
                    float sc = cum[s + w] - cum[s];
                    if (sc > bs) { bs = sc; bst = s; ben = s + w; }
                }
            }
        }
        out[OFF_MI + b * 2 + 0] = (float)bst;
        out[OFF_MI + b * 2 + 1] = (float)ben;
        out[OFF_ST + b] = (float)bst / 31.0f;
        out[OFF_ET + b] = (float)ben / 31.0f;
        sel[0] = bst; sel[1] = ben;
    }
    __syncthreads();
    if (lane < 32)
        out[OFF_MASK + b * 32 + lane] = (lane >= sel[0] && lane <= sel[1]) ? 1.0f : 0.0f;
}

// ---------------------------------------------------------------------------
extern "C" void kernel_launch(void* const* d_in, const int* in_sizes, int n_in,
                              void* d_out, int out_size, void* d_ws, size_t ws_size,
                              hipStream_t stream)
{
    const float* v      = (const float*)d_in[0];
    const float* qa     = (const float*)d_in[1];
    const float* vp_lng = (const float*)d_in[2];
    const float* vp_lnb = (const float*)d_in[3];
    const float* vp_w   = (const float*)d_in[4];
    const float* vp_b   = (const float*)d_in[5];
    const float* qp_lng = (const float*)d_in[6];
    const float* qp_lnb = (const float*)d_in[7];
    const float* qp_w   = (const float*)d_in[8];
    const float* qp_b   = (const float*)d_in[9];
    const float* g_lng  = (const float*)d_in[10];
    const float* g_lnb  = (const float*)d_in[11];
    const float* g_w1   = (const float*)d_in[12];
    const float* g_b1   = (const float*)d_in[13];
    const float* g_w2   = (const float*)d_in[14];
    const float* g_b2   = (const float*)d_in[15];
    const float* sigma  = (const float*)d_in[16];
    float* outf = (float*)d_out;

    // workspace layout (~213 MB)
    short* A1h = (short*)d_ws;                           // CHUNK*768
    short* A1l = A1h + (size_t)CHUNK * KDIM;
    uint32_t* vp_hl = (uint32_t*)(A1l + (size_t)CHUNK * KDIM);   // CHUNK*768 u32
    short* B1h = (short*)(vp_hl + (size_t)CHUNK * KDIM); // 768*768
    short* B1l = B1h + 768 * KDIM;
    short* B2h = B1l + 768 * KDIM;                       // 384*768
    short* B2l = B2h + 384 * KDIM;
    float* qa_p = (float*)(B2l + 384 * KDIM);            // 2048*768
    float* st_qa = qa_p + 2048 * KDIM;                   // 2048*2
    float* partials = st_qa + 4096;                      // 6*65536

    // qa path (small, f32 vector GEMM)
    rowstats<<<512, 256, 0, stream>>>(qa, (float2*)st_qa, 2048);
    gemm_fused<64, 64, 4, 4><<<dim3(12, 32), 256, 0, stream>>>(
        qa, (const float2*)st_qa, qp_lng, qp_lnb, qp_w, qp_b, qa_p, 2048, 768);

    // weight transpose + split
    prep_W<<<dim3(24, 24), 256, 0, stream>>>(vp_w, B1h, B1l, 768);
    prep_W<<<dim3(12, 24), 256, 0, stream>>>(g_w1, B2h, B2l, 384);

    constexpr int LDS8 = 65536;   // 2 bufs x 32 KB -> 2 blocks/CU

    for (int c = 0; c < 65536; c += CHUNK) {
        prep_A1<<<CHUNK / 4, 256, 0, stream>>>(v + (size_t)c * KDIM, vp_lng, vp_lnb, A1h, A1l);
        // v_p = gelu(A1 @ vp_w^T + vp_b): 128x128 tile, grid (6,256)=1536 blocks
        gemm8<0><<<dim3(6, CHUNK / 128), 256, LDS8, stream>>>(
            A1h, A1l, B1h, B1l, vp_b, vp_hl, nullptr, nullptr, 0);
        prep_A2<<<CHUNK / 4, 256, 0, stream>>>(vp_hl, qa_p, g_lng, g_lnb, A1h, A1l, c);
        // fused h@g_w1+gelu+dot(g_w2): 128x128 tile, grid (3,256)=768 blocks
        gemm8<1><<<dim3(3, CHUNK / 128), 256, LDS8, stream>>>(
            A1h, A1l, B2h, B2l, g_b1, nullptr, g_w2, partials, c);
    }

    head_kernel<<<2048, 64, 0, stream>>>(partials, g_b2, sigma, outf);
}

// Round 11
// 562.497 us; speedup vs baseline: 1.5094x; 1.0846x over previous
//
#include <hip/hip_runtime.h>
#include <math.h>
#include <stdint.h>

// ---------------------------------------------------------------------------
// GroundingModule — round 11: round-10 structure + cheap epilogue.
//   - branchless A&S-7.1.26 erf (rcp+exp HW instrs, ~18 ops, err<=1.5e-7)
//     replaces divergent libm erff in all GEMM epilogues.
//   - MODE0 v_p split: truncated hi (1 AND) + RNE lo of remainder (pair
//     accuracy unchanged, 2^-17); packed hi|lo -> 1-op unpack in prep_A2.
// GEMM core unchanged: 2 blocks/CU, 256 thr / 4 waves (2x2), 128x128 tile,
// 3-phase stage-once split-bf16 schedule, counted vmcnt, slot-XOR swizzle.
// ---------------------------------------------------------------------------

#define DEV __device__ __forceinline__

typedef __attribute__((ext_vector_type(8))) short short8v;   // 8 bf16
typedef __attribute__((ext_vector_type(4))) float f32x4;

constexpr int KDIM  = 768;
constexpr int CHUNK = 32768;

// output offsets (floats) in return order
constexpr int OFF_KG   = 0;
constexpr int OFF_MI   = 65536;
constexpr int OFF_ST   = 69632;
constexpr int OFF_ET   = 71680;
constexpr int OFF_MASK = 73728;
constexpr int OFF_ORI  = 139264;

DEV float wave_sum(float v) { for (int o = 32; o; o >>= 1) v += __shfl_xor(v, o); return v; }
DEV float wave_max(float v) { for (int o = 32; o; o >>= 1) v = fmaxf(v, __shfl_xor(v, o)); return v; }

// branchless gelu: 0.5x(1+erf(x/sqrt2)), erf via A&S 7.1.26 (|err|<=1.5e-7)
DEV float gelu_fast(float x) {
    float z = x * 0.70710678118654752f;
    float s = fabsf(z);
    float t = __builtin_amdgcn_rcpf(fmaf(0.3275911f, s, 1.0f));
    float p = t * fmaf(t, fmaf(t, fmaf(t, fmaf(t, 1.061405429f, -1.453152027f),
                                       1.421413741f), -0.284496736f), 0.254829592f);
    float e = __expf(-s * s);
    float er = copysignf(1.0f - p * e, z);
    return 0.5f * x * (1.0f + er);
}

DEV short f2bf(float x) {                       // f32 -> bf16 (RNE)
    uint32_t u = __builtin_bit_cast(uint32_t, x);
    u = u + 0x7fffu + ((u >> 16) & 1u);
    return (short)(u >> 16);
}
DEV float bf2f(short b) {
    uint32_t u = ((uint32_t)(uint16_t)b) << 16;
    return __builtin_bit_cast(float, u);
}
DEV float asf(uint32_t u) { return __builtin_bit_cast(float, u); }

DEV void gl_lds16(const void* g, void* l) {     // async 16B/lane global->LDS
    __builtin_amdgcn_global_load_lds(
        (const __attribute__((address_space(1))) uint32_t*)g,
        (__attribute__((address_space(3))) uint32_t*)l, 16, 0, 0);
}

// ---------------------------------------------------------------------------
// prep_A1: fused rowstats + LN-affine + hi/lo split.  One wave per row.
__global__ __launch_bounds__(256)
void prep_A1(const float* __restrict__ X, const float* __restrict__ g,
             const float* __restrict__ b, short* __restrict__ Ah, short* __restrict__ Al)
{
    int w = threadIdx.x >> 6, lane = threadIdx.x & 63;
    int row = blockIdx.x * 4 + w;
    const float4* xr = (const float4*)(X + (size_t)row * KDIM);
    float4 xv[3]; float s = 0.f, ss = 0.f;
#pragma unroll
    for (int i = 0; i < 3; ++i) {
        xv[i] = xr[lane + i * 64];
        s  += xv[i].x + xv[i].y + xv[i].z + xv[i].w;
        ss += xv[i].x * xv[i].x + xv[i].y * xv[i].y + xv[i].z * xv[i].z + xv[i].w * xv[i].w;
    }
    s = wave_sum(s); ss = wave_sum(ss);
    float m = s * (1.f / 768.f), var = ss * (1.f / 768.f) - m * m;
    float sa = rsqrtf(var + 1e-5f), ta = -m * sa;
#pragma unroll
    for (int i = 0; i < 3; ++i) {
        int idx = lane + i * 64;
        float4 gv = ((const float4*)g)[idx];
        float4 bv = ((const float4*)b)[idx];
        float a0 = fmaf(fmaf(xv[i].x, sa, ta), gv.x, bv.x);
        float a1 = fmaf(fmaf(xv[i].y, sa, ta), gv.y, bv.y);
        float a2 = fmaf(fmaf(xv[i].z, sa, ta), gv.z, bv.z);
        float a3 = fmaf(fmaf(xv[i].w, sa, ta), gv.w, bv.w);
        short h0 = f2bf(a0), h1 = f2bf(a1), h2 = f2bf(a2), h3 = f2bf(a3);
        ushort4 hv, lv;
        hv.x = (uint16_t)h0; hv.y = (uint16_t)h1; hv.z = (uint16_t)h2; hv.w = (uint16_t)h3;
        lv.x = (uint16_t)f2bf(a0 - bf2f(h0)); lv.y = (uint16_t)f2bf(a1 - bf2f(h1));
        lv.z = (uint16_t)f2bf(a2 - bf2f(h2)); lv.w = (uint16_t)f2bf(a3 - bf2f(h3));
        ((ushort4*)(Ah + (size_t)row * KDIM))[idx] = hv;
        ((ushort4*)(Al + (size_t)row * KDIM))[idx] = lv;
    }
}

// ---------------------------------------------------------------------------
// prep_A2: gate(tanh dot) + LN2 stats + affine + split.
// vp packed: hi bits in TOP half, lo bf16 in LOW half (round-11 layout).
__global__ __launch_bounds__(256)
void prep_A2(const uint32_t* __restrict__ vp_hl, const float* __restrict__ qa_p,
             const float* __restrict__ g, const float* __restrict__ b,
             short* __restrict__ Ah, short* __restrict__ Al, int chunk_off)
{
    int w = threadIdx.x >> 6, lane = threadIdx.x & 63;
    int row = blockIdx.x * 4 + w;
    int bidx = (chunk_off + row) >> 5;
    const uint4*  hr = (const uint4*)(vp_hl + (size_t)row * KDIM);
    const float4* qr = (const float4*)(qa_p + (size_t)bidx * KDIM);
    float vp[12]; float s = 0.f, ss = 0.f, d = 0.f;
#pragma unroll
    for (int i = 0; i < 3; ++i) {
        uint4  uv = hr[lane + i * 64];
        float4 qv = qr[lane + i * 64];
        float v0 = asf(uv.x & 0xffff0000u) + asf(uv.x << 16);
        float v1 = asf(uv.y & 0xffff0000u) + asf(uv.y << 16);
        float v2 = asf(uv.z & 0xffff0000u) + asf(uv.z << 16);
        float v3 = asf(uv.w & 0xffff0000u) + asf(uv.w << 16);
        vp[i * 4 + 0] = v0; vp[i * 4 + 1] = v1; vp[i * 4 + 2] = v2; vp[i * 4 + 3] = v3;
        s  += v0 + v1 + v2 + v3;
        ss += v0 * v0 + v1 * v1 + v2 * v2 + v3 * v3;
        d  += v0 * qv.x + v1 * qv.y + v2 * qv.z + v3 * qv.w;
    }
    s = wave_sum(s); ss = wave_sum(ss); d = wave_sum(d);
    float gate = tanhf(d);
    float m = s * (1.f / 768.f), var = ss * (1.f / 768.f) - m * m;
    float den = rsqrtf(gate * gate * var + 1e-5f);
    float sa = gate * den, ta = -gate * m * den;
#pragma unroll
    for (int i = 0; i < 3; ++i) {
        int idx = lane + i * 64;
        float4 gv = ((const float4*)g)[idx];
        float4 bv = ((const float4*)b)[idx];
        float a0 = fmaf(fmaf(vp[i * 4 + 0], sa, ta), gv.x, bv.x);
        float a1 = fmaf(fmaf(vp[i * 4 + 1], sa, ta), gv.y, bv.y);
        float a2 = fmaf(fmaf(vp[i * 4 + 2], sa, ta), gv.z, bv.z);
        float a3 = fmaf(fmaf(vp[i * 4 + 3], sa, ta), gv.w, bv.w);
        short h0 = f2bf(a0), h1 = f2bf(a1), h2 = f2bf(a2), h3 = f2bf(a3);
        ushort4 hv, lv;
        hv.x = (uint16_t)h0; hv.y = (uint16_t)h1; hv.z = (uint16_t)h2; hv.w = (uint16_t)h3;
        lv.x = (uint16_t)f2bf(a0 - bf2f(h0)); lv.y = (uint16_t)f2bf(a1 - bf2f(h1));
        lv.z = (uint16_t)f2bf(a2 - bf2f(h2)); lv.w = (uint16_t)f2bf(a3 - bf2f(h3));
        ((ushort4*)(Ah + (size_t)row * KDIM))[idx] = hv;
        ((ushort4*)(Al + (size_t)row * KDIM))[idx] = lv;
    }
}

// ---------------------------------------------------------------------------
// prep_W: transpose + hi/lo split.  W[k][n] f32 -> Bh/Bl[n][k] bf16.
__global__ __launch_bounds__(256)
void prep_W(const float* __restrict__ W, short* __restrict__ Bh, short* __restrict__ Bl, int N)
{
    __shared__ float t[32][33];
    int bx = blockIdx.x, by = blockIdx.y;
    int lx = threadIdx.x & 31, ly = threadIdx.x >> 5;
#pragma unroll
    for (int r = 0; r < 32; r += 8)
        t[ly + r][lx] = W[(size_t)(by * 32 + ly + r) * N + bx * 32 + lx];
    __syncthreads();
#pragma unroll
    for (int r = 0; r < 32; r += 8) {
        float v = t[lx][ly + r];
        short hi = f2bf(v);
        size_t o = (size_t)(bx * 32 + ly + r) * KDIM + by * 32 + lx;
        Bh[o] = hi;
        Bl[o] = f2bf(v - bf2f(hi));
    }
}

// ---------------------------------------------------------------------------
// Split-bf16 MFMA GEMM, 2 blocks/CU.  256 thr / 4 waves (2M x 2N), BM=BN=128,
// BK=32.  Per k-tile: 3 phases {AhBh, AhBl, AlBh}, 16 MFMA each; stage next
// k-tile's 8x4KB units 3/3/2 across the phases.
// LDS buf (32KB): Ah@0(8K) Bh@8K(8K) Bl@16K(8K) Al@24K(8K); double-buffered.
//   MODE 0: out = gelu(.) packed (hi-bits | lo-bf16) u32 into 768-wide vp_hl.
//   MODE 1: partial row-dot with w2 -> partials[bx*2+wn][row].
#define VMW(N_) asm volatile("s_waitcnt vmcnt(" #N_ ")" ::: "memory")

#define STG(G_, KT_) gl_lds16(sp[G_] + (KT_) * 32,                            \
    lds + (((KT_) & 1) ? BUFSZ : 0) + (G_) * 4096 + toff)

#define RDA(dst, BOFF) do {                                                   \
    _Pragma("unroll")                                                         \
    for (int mf = 0; mf < 4; ++mf) {                                          \
        int rA = wm * 64 + mf * 16 + lr;                                      \
        dst[mf] = *(const short8v*)(bb + (BOFF) + rA * 64 +                   \
                                    ((lh ^ ((rA >> 1) & 3)) << 4));           \
    } } while (0)

#define RDB(dst, BOFF) do {                                                   \
    _Pragma("unroll")                                                         \
    for (int nf = 0; nf < 4; ++nf) {                                          \
        int rB = wn * 64 + nf * 16 + lr;                                      \
        dst[nf] = *(const short8v*)(bb + (BOFF) + rB * 64 +                   \
                                    ((lh ^ ((rB >> 1) & 3)) << 4));           \
    } } while (0)

#define SYNCMM(aop, bop) do {                                                 \
    __builtin_amdgcn_sched_barrier(0);                                        \
    __builtin_amdgcn_s_barrier();                                             \
    asm volatile("s_waitcnt lgkmcnt(0)" ::: "memory");                        \
    __builtin_amdgcn_sched_barrier(0);                                        \
    __builtin_amdgcn_s_setprio(1);                                            \
    _Pragma("unroll")                                                         \
    for (int mf = 0; mf < 4; ++mf)                                            \
        _Pragma("unroll")                                                     \
        for (int nf = 0; nf < 4; ++nf)                                        \
            acc[mf][nf] = __builtin_amdgcn_mfma_f32_16x16x32_bf16(            \
                aop[mf], bop[nf], acc[mf][nf], 0, 0, 0);                      \
    __builtin_amdgcn_s_setprio(0);                                            \
    __builtin_amdgcn_sched_barrier(0);                                        \
    __builtin_amdgcn_s_barrier();                                             \
    } while (0)

template<int MODE>
__global__ __launch_bounds__(256, 2)
void gemm8(const short* __restrict__ Ah_g, const short* __restrict__ Al_g,
           const short* __restrict__ Bh_g, const short* __restrict__ Bl_g,
           const float* __restrict__ bias, uint32_t* __restrict__ O_hl,
           const float* __restrict__ w2, float* __restrict__ partials,
           int chunk_off)
{
    constexpr int BUFSZ = 32768;              // 32 KB per buffer
    extern __shared__ __align__(16) char lds[];

    const int t = threadIdx.x;
    const int w = t >> 6, lane = t & 63;
    const int lr = lane & 15, lh = lane >> 4;
    const int wm = w >> 1, wn = w & 1;        // 2 x 2 wave grid

    const int gx = gridDim.x, nwg = gx * gridDim.y;
    int bidx = blockIdx.y * gx + blockIdx.x;
    int wid = (bidx & 7) * (nwg >> 3) + (bidx >> 3);
    const int bx = wid % gx, by = wid / gx;
    const int row0 = by * 128, col0 = bx * 128;

    // per-thread stage source pointers (k=0); unit order Ah0,Ah1,Bh0,Bh1,
    // Bl0,Bl1,Al0,Al1.  thread t covers (row r_ = t>>2, slot c_ = t&3) within
    // a 64-row unit; source k-chunk pre-swizzled c ^ ((r>>1)&3) so the LDS
    // destination stays linear (dest = unit*4K + t*16).
    const int r_ = t >> 2, c_ = t & 3;
    const int swz_ = (c_ ^ ((r_ >> 1) & 3)) << 3;   // element offset in k
    const int toff = t * 16;
    const short* sp[8];
    sp[0] = Ah_g + (size_t)(row0 + r_)      * KDIM + swz_;
    sp[1] = Ah_g + (size_t)(row0 + 64 + r_) * KDIM + swz_;
    sp[2] = Bh_g + (size_t)(col0 + r_)      * KDIM + swz_;
    sp[3] = Bh_g + (size_t)(col0 + 64 + r_) * KDIM + swz_;
    sp[4] = Bl_g + (size_t)(col0 + r_)      * KDIM + swz_;
    sp[5] = Bl_g + (size_t)(col0 + 64 + r_) * KDIM + swz_;
    sp[6] = Al_g + (size_t)(row0 + r_)      * KDIM + swz_;
    sp[7] = Al_g + (size_t)(row0 + 64 + r_) * KDIM + swz_;

    f32x4 acc[4][4] = {};
    short8v ah[4], al[4], bh[4], bl[4];

    // prologue: stage all 8 units of k-tile 0; VM(4) -> u0..u3 (Ah+Bh) landed
    STG(0, 0); STG(1, 0); STG(2, 0); STG(3, 0);
    STG(4, 0); STG(5, 0); STG(6, 0); STG(7, 0);
    VMW(4);
    __builtin_amdgcn_s_barrier();

    for (int kt = 0; kt < 24; ++kt) {
        const char* bb = lds + ((kt & 1) ? BUFSZ : 0);
        const bool nl = (kt < 23);
        // P0: AhBh.  Stage next u0,u1,u2.  Wait covers this tile's Bl units.
        RDA(ah, 0); RDB(bh, 8192);
        if (nl) { STG(0, kt + 1); STG(1, kt + 1); STG(2, kt + 1); VMW(4); }
        else    { VMW(2); }
        SYNCMM(ah, bh);
        // P1: AhBl.  Stage next u3,u4,u5.  Wait covers this tile's Al units.
        RDB(bl, 16384);
        if (nl) { STG(3, kt + 1); STG(4, kt + 1); STG(5, kt + 1); VMW(6); }
        else    { VMW(0); }
        SYNCMM(ah, bl);
        // P2: AlBh.  Stage next u6,u7.  Wait covers NEXT tile's Ah+Bh units.
        RDA(al, 24576);
        if (nl) { STG(6, kt + 1); STG(7, kt + 1); VMW(4); }
        SYNCMM(al, bh);
    }

    if (MODE == 0) {
#pragma unroll
        for (int mf = 0; mf < 4; ++mf)
#pragma unroll
            for (int nf = 0; nf < 4; ++nf) {
                int n = col0 + wn * 64 + nf * 16 + lr;
                float bvs = bias[n];
#pragma unroll
                for (int q = 0; q < 4; ++q) {
                    int m = row0 + wm * 64 + mf * 16 + lh * 4 + q;
                    float gv = gelu_fast(acc[mf][nf][q] + bvs);
                    uint32_t u  = __builtin_bit_cast(uint32_t, gv);
                    uint32_t hb = u & 0xffff0000u;            // truncated hi
                    float rem   = gv - asf(hb);               // exact remainder
                    O_hl[(size_t)m * 768 + n] =
                        hb | (uint32_t)(uint16_t)f2bf(rem);   // hi TOP | lo LOW
                }
            }
    } else {
        float rs[4][4] = {};
#pragma unroll
        for (int mf = 0; mf < 4; ++mf)
#pragma unroll
            for (int nf = 0; nf < 4; ++nf) {
                int n = col0 + wn * 64 + nf * 16 + lr;
                float bvs = bias[n], wv = w2[n];
#pragma unroll
                for (int q = 0; q < 4; ++q)
                    rs[mf][q] += gelu_fast(acc[mf][nf][q] + bvs) * wv;
            }
#pragma unroll
        for (int mf = 0; mf < 4; ++mf)
#pragma unroll
            for (int q = 0; q < 4; ++q) {
                float vv = rs[mf][q];
                vv += __shfl_xor(vv, 1); vv += __shfl_xor(vv, 2);
                vv += __shfl_xor(vv, 4); vv += __shfl_xor(vv, 8);
                if (lr == 0) {
                    int m = chunk_off + row0 + wm * 64 + mf * 16 + lh * 4 + q;
                    partials[(size_t)(bx * 2 + wn) * 65536 + m] = vv;
                }
            }
    }
}

// ---------------------------------------------------------------------------
// f32 fallback GEMM for the small qa projection.
constexpr int BKF = 16;
__global__ __launch_bounds__(256)
void rowstats(const float* __restrict__ X, float2* __restrict__ st, int M)
{
    int wave = threadIdx.x >> 6, lane = threadIdx.x & 63;
    int row = blockIdx.x * 4 + wave;
    if (row >= M) return;
    const float4* xr = reinterpret_cast<const float4*>(X + (size_t)row * KDIM);
    float s = 0.f, ss = 0.f;
#pragma unroll
    for (int i = 0; i < 3; ++i) {
        float4 v = xr[lane + i * 64];
        s  += v.x + v.y + v.z + v.w;
        ss += v.x * v.x + v.y * v.y + v.z * v.z + v.w * v.w;
    }
    s = wave_sum(s); ss = wave_sum(ss);
    if (lane == 0) {
        float m = s * (1.0f / 768.0f);
        float var = ss * (1.0f / 768.0f) - m * m;
        float rstd = rsqrtf(var + 1e-5f);
        st[row] = make_float2(rstd, -m * rstd);
    }
}

template<int BM, int BN, int TM, int TN>
__global__ __launch_bounds__(256)
void gemm_fused(const float* __restrict__ X, const float2* __restrict__ st,
                const float* __restrict__ gw, const float* __restrict__ gb,
                const float* __restrict__ W, const float* __restrict__ bias,
                float* __restrict__ out, int M, int N)
{
    static_assert((BM / TM) * (BN / TN) == 256, "256 threads");
    __shared__ float As[BKF][BM];
    __shared__ float Bs[BKF][BN];
    const int t = threadIdx.x;
    constexpr int TXN = BN / TN;
    const int tx = t % TXN;
    const int ty = t / TXN;
    const int row0 = blockIdx.y * BM;
    const int col0 = blockIdx.x * BN;
    float acc[TM][TN] = {};
    constexpr int A_IT = BM * BKF / 4 / 256;
    constexpr int B_IT = BKF * BN / 4 / 256;
    for (int k0 = 0; k0 < KDIM; k0 += BKF) {
#pragma unroll
        for (int i = 0; i < A_IT; ++i) {
            int idx = t + i * 256;
            int r = idx >> 2;
            int c = (idx & 3) << 2;
            float4 xv = *reinterpret_cast<const float4*>(X + (size_t)(row0 + r) * KDIM + k0 + c);
            float2 s = st[row0 + r];
            float4 gv = *reinterpret_cast<const float4*>(gw + k0 + c);
            float4 bv = *reinterpret_cast<const float4*>(gb + k0 + c);
            As[c + 0][r] = fmaf(fmaf(xv.x, s.x, s.y), gv.x, bv.x);
            As[c + 1][r] = fmaf(fmaf(xv.y, s.x, s.y), gv.y, bv.y);
            As[c + 2][r] = fmaf(fmaf(xv.z, s.x, s.y), gv.z, bv.z);
            As[c + 3][r] = fmaf(fmaf(xv.w, s.x, s.y), gv.w, bv.w);
        }
#pragma unroll
        for (int i = 0; i < B_IT; ++i) {
            int idx = t + i * 256;
            int r = idx / (BN / 4);
            int c = (idx % (BN / 4)) << 2;
            *reinterpret_cast<float4*>(&Bs[r][c]) =
                *reinterpret_cast<const float4*>(W + (size_t)(k0 + r) * N + col0 + c);
        }
        __syncthreads();
#pragma unroll
        for (int kk = 0; kk < BKF; ++kk) {
            float a[TM], b[TN];
#pragma unroll
            for (int i = 0; i < TM; i += 4)
                *reinterpret_cast<float4*>(&a[i]) = *reinterpret_cast<const float4*>(&As[kk][ty * TM + i]);
#pragma unroll
            for (int j = 0; j < TN; j += 4)
                *reinterpret_cast<float4*>(&b[j]) = *reinterpret_cast<const float4*>(&Bs[kk][tx * TN + j]);
#pragma unroll
            for (int i = 0; i < TM; ++i)
#pragma unroll
                for (int j = 0; j < TN; ++j)
                    acc[i][j] = fmaf(a[i], b[j], acc[i][j]);
        }
        __syncthreads();
    }
#pragma unroll
    for (int i = 0; i < TM; ++i) {
        size_t row = row0 + ty * TM + i;
#pragma unroll
        for (int j = 0; j < TN; j += 4) {
            int col = col0 + tx * TN + j;
            float4 o;
            o.x = gelu_fast(acc[i][j + 0] + bias[col + 0]);
            o.y = gelu_fast(acc[i][j + 1] + bias[col + 1]);
            o.z = gelu_fast(acc[i][j + 2] + bias[col + 2]);
            o.w = gelu_fast(acc[i][j + 3] + bias[col + 3]);
            *reinterpret_cast<float4*>(out + row * N + col) = o;
        }
    }
}

// ---------------------------------------------------------------------------
// head: logits = sum(6 partials)+b2 -> softmax -> smooth -> softmax -> decode.
__global__ __launch_bounds__(64)
void head_kernel(const float* __restrict__ partials, const float* __restrict__ b2,
                 const float* __restrict__ sigma_p, float* __restrict__ out)
{
    int b = blockIdx.x, lane = threadIdx.x;
    __shared__ float ok[36];
    __shared__ float kg[32];
    __shared__ int sel[2];

    if (lane < 36) ok[lane] = 0.f;
    __syncthreads();

    float x = -3.4e38f;
    if (lane < 32) {
        int row = b * 32 + lane;
        x = b2[0];
#pragma unroll
        for (int p = 0; p < 6; ++p) x += partials[(size_t)p * 65536 + row];
    }
    float mx = wave_max(x);
    float e = (lane < 32) ? expf(x - mx) : 0.f;
    float sum = wave_sum(e);
    float ori = e / sum;
    if (lane < 32) {
        out[OFF_ORI + b * 32 + lane] = ori;
        ok[lane + 2] = ori;
    }
    __syncthreads();

    float sg = sigma_p[0];
    float kern[5]; float ks = 0.f;
#pragma unroll
    for (int k = 0; k < 5; ++k) { float xx = (float)(k - 2) / sg; kern[k] = expf(-0.5f * xx * xx); ks += kern[k]; }
    float sm = -3.4e38f;
    if (lane < 32) {
        sm = 0.f;
#pragma unroll
        for (int k = 0; k < 5; ++k) sm += (kern[k] / ks) * ok[lane + k];
    }
    float mx2 = wave_max(sm);
    float e2 = (lane < 32) ? expf(sm - mx2) : 0.f;
    float sum2 = wave_sum(e2);
    float kgv = e2 / sum2;
    if (lane < 32) {
        out[OFF_KG + b * 32 + lane] = kgv;
        kg[lane] = kgv;
    }
    __syncthreads();

    if (lane == 0) {
        int pm = 0; float bv = kg[0];
        for (int i = 1; i < 32; ++i) if (kg[i] > bv) { bv = kg[i]; pm = i; }
        float cum[33]; cum[0] = 0.f;
        for (int i = 0; i < 32; ++i) cum[i + 1] = cum[i] + kg[i];
        float bs = -3.4e38f; int bst = 0, ben = 0;
        const int wsz[3] = {1, 3, 5};
        for (int wi = 0; wi < 3; ++wi) {
            int w = wsz[wi];
            for (int s = 0; s + w <= 32; ++s) {
                if (pm >= s && pm < s + w) {
                    float sc = cum[s + w] - cum[s];
                    if (sc > bs) { bs = sc; bst = s; ben = s + w; }
                }
            }
        }
        out[OFF_MI + b * 2 + 0] = (float)bst;
        out[OFF_MI + b * 2 + 1] = (float)ben;
        out[OFF_ST + b] = (float)bst / 31.0f;
        out[OFF_ET + b] = (float)ben / 31.0f;
        sel[0] = bst; sel[1] = ben;
    }
    __syncthreads();
    if (lane < 32)
        out[OFF_MASK + b * 32 + lane] = (lane >= sel[0] && lane <= sel[1]) ? 1.0f : 0.0f;
}

// ---------------------------------------------------------------------------
extern "C" void kernel_launch(void* const* d_in, const int* in_sizes, int n_in,
                              void* d_out, int out_size, void* d_ws, size_t ws_size,
                              hipStream_t stream)
{
    const float* v      = (const float*)d_in[0];
    const float* qa     = (const float*)d_in[1];
    const float* vp_lng = (const float*)d_in[2];
    const float* vp_lnb = (const float*)d_in[3];
    const float* vp_w   = (const float*)d_in[4];
    const float* vp_b   = (const float*)d_in[5];
    const float* qp_lng = (const float*)d_in[6];
    const float* qp_lnb = (const float*)d_in[7];
    const float* qp_w   = (const float*)d_in[8];
    const float* qp_b   = (const float*)d_in[9];
    const float* g_lng  = (const float*)d_in[10];
    const float* g_lnb  = (const float*)d_in[11];
    const float* g_w1   = (const float*)d_in[12];
    const float* g_b1   = (const float*)d_in[13];
    const float* g_w2   = (const float*)d_in[14];
    const float* g_b2   = (const float*)d_in[15];
    const float* sigma  = (const float*)d_in[16];
    float* outf = (float*)d_out;

    // workspace layout (~213 MB)
    short* A1h = (short*)d_ws;                           // CHUNK*768
    short* A1l = A1h + (size_t)CHUNK * KDIM;
    uint32_t* vp_hl = (uint32_t*)(A1l + (size_t)CHUNK * KDIM);   // CHUNK*768 u32
    short* B1h = (short*)(vp_hl + (size_t)CHUNK * KDIM); // 768*768
    short* B1l = B1h + 768 * KDIM;
    short* B2h = B1l + 768 * KDIM;                       // 384*768
    short* B2l = B2h + 384 * KDIM;
    float* qa_p = (float*)(B2l + 384 * KDIM);            // 2048*768
    float* st_qa = qa_p + 2048 * KDIM;                   // 2048*2
    float* partials = st_qa + 4096;                      // 6*65536

    // qa path (small, f32 vector GEMM)
    rowstats<<<512, 256, 0, stream>>>(qa, (float2*)st_qa, 2048);
    gemm_fused<64, 64, 4, 4><<<dim3(12, 32), 256, 0, stream>>>(
        qa, (const float2*)st_qa, qp_lng, qp_lnb, qp_w, qp_b, qa_p, 2048, 768);

    // weight transpose + split
    prep_W<<<dim3(24, 24), 256, 0, stream>>>(vp_w, B1h, B1l, 768);
    prep_W<<<dim3(12, 24), 256, 0, stream>>>(g_w1, B2h, B2l, 384);

    constexpr int LDS8 = 65536;   // 2 bufs x 32 KB -> 2 blocks/CU

    for (int c = 0; c < 65536; c += CHUNK) {
        prep_A1<<<CHUNK / 4, 256, 0, stream>>>(v + (size_t)c * KDIM, vp_lng, vp_lnb, A1h, A1l);
        // v_p = gelu(A1 @ vp_w^T + vp_b): 128x128 tile, grid (6,256)=1536 blocks
        gemm8<0><<<dim3(6, CHUNK / 128), 256, LDS8, stream>>>(
            A1h, A1l, B1h, B1l, vp_b, vp_hl, nullptr, nullptr, 0);
        prep_A2<<<CHUNK / 4, 256, 0, stream>>>(vp_hl, qa_p, g_lng, g_lnb, A1h, A1l, c);
        // fused h@g_w1+gelu+dot(g_w2): 128x128 tile, grid (3,256)=768 blocks
        gemm8<1><<<dim3(3, CHUNK / 128), 256, LDS8, stream>>>(
            A1h, A1l, B2h, B2l, g_b1, nullptr, g_w2, partials, c);
    }

    head_kernel<<<2048, 64, 0, stream>>>(partials, g_b2, sigma, outf);
}